// Round 1
// baseline (2407.394 us; speedup 1.0000x reference)
//
#include <hip/hip_runtime.h>
#include <math.h>

#define B_   2
#define N_   1024
#define DIM_ 512
#define H_   8
#define DH_  64
#define PD_  4

static constexpr float SCALAR_SCALE = 0.08838834764831845f; // (2*64)^-0.5
static constexpr float POINT_SCALE  = 0.16666666666666666f; // (2*4*4.5)^-0.5
static constexpr float EPS_         = 1e-8f;

// ---------------------------------------------------------------------------
// Generic fp32 tiled GEMM: C[M,N] = A[M,K] @ W[K,N] (+ bias[N] if bias!=null)
// 64x64 tile, 256 threads, 4x4 microtile. Guards on N (for N=96 case).
// ---------------------------------------------------------------------------
#define BM 64
#define BN 64
#define BK 16
__global__ __launch_bounds__(256) void gemm_kernel(
    const float* __restrict__ A, const float* __restrict__ W,
    const float* __restrict__ bias, float* __restrict__ C,
    int M, int N, int K) {
  __shared__ float As[BK][BM + 1];
  __shared__ float Bs[BK][BN + 1];
  const int tid = threadIdx.x;
  const int tx = tid % 16, ty = tid / 16;
  const int row0 = blockIdx.y * BM, col0 = blockIdx.x * BN;
  float acc[4][4] = {};
  for (int k0 = 0; k0 < K; k0 += BK) {
    // Load A tile (BM x BK), store transposed
    for (int i = tid; i < BM * BK; i += 256) {
      int m = i / BK, k = i % BK;
      As[k][m] = A[(size_t)(row0 + m) * K + k0 + k];
    }
    // Load W tile (BK x BN)
    for (int i = tid; i < BK * BN; i += 256) {
      int k = i / BN, n = i % BN;
      int c = col0 + n;
      Bs[k][n] = (c < N) ? W[(size_t)(k0 + k) * N + c] : 0.0f;
    }
    __syncthreads();
#pragma unroll
    for (int k = 0; k < BK; ++k) {
      float a[4], b[4];
#pragma unroll
      for (int u = 0; u < 4; ++u) a[u] = As[k][ty * 4 + u];
#pragma unroll
      for (int v = 0; v < 4; ++v) b[v] = Bs[k][tx * 4 + v];
#pragma unroll
      for (int u = 0; u < 4; ++u)
#pragma unroll
        for (int v = 0; v < 4; ++v) acc[u][v] += a[u] * b[v];
    }
    __syncthreads();
  }
#pragma unroll
  for (int u = 0; u < 4; ++u)
#pragma unroll
    for (int v = 0; v < 4; ++v) {
      int r = row0 + ty * 4 + u, c = col0 + tx * 4 + v;
      if (c < N) {
        float val = acc[u][v] + (bias ? bias[c] : 0.0f);
        C[(size_t)r * N + c] = val;
      }
    }
}

// ---------------------------------------------------------------------------
// Rotate points to global frame: out[c] = sum_r R[c][r]*p[r] + t[c]
// p layout: (B*N, H, PD, 3) flat; R: (B*N, 3, 3); t: (B*N, 3)
// idx enumerates (b*N+n)*H*PD + h*PD + d
// ---------------------------------------------------------------------------
__global__ __launch_bounds__(256) void rotate_fwd_kernel(
    const float* __restrict__ p, const float* __restrict__ R,
    const float* __restrict__ t, float* __restrict__ out, int total) {
  int idx = blockIdx.x * blockDim.x + threadIdx.x;
  if (idx >= total) return;
  int bn = idx / (H_ * PD_);
  const float* Rv = R + (size_t)bn * 9;
  const float* tv = t + (size_t)bn * 3;
  float p0 = p[idx * 3 + 0], p1 = p[idx * 3 + 1], p2 = p[idx * 3 + 2];
  out[idx * 3 + 0] = Rv[0] * p0 + Rv[1] * p1 + Rv[2] * p2 + tv[0];
  out[idx * 3 + 1] = Rv[3] * p0 + Rv[4] * p1 + Rv[5] * p2 + tv[1];
  out[idx * 3 + 2] = Rv[6] * p0 + Rv[7] * p1 + Rv[8] * p2 + tv[2];
}

// Sum of squares over (PD*3) per (b,n,h): sq[(b*N+n)*H + h]
__global__ __launch_bounds__(256) void sumsq_kernel(
    const float* __restrict__ p, float* __restrict__ sq, int total) {
  int idx = blockIdx.x * blockDim.x + threadIdx.x;
  if (idx >= total) return;
  const float* pp = p + (size_t)idx * (PD_ * 3);
  float s = 0.0f;
#pragma unroll
  for (int e = 0; e < PD_ * 3; ++e) s += pp[e] * pp[e];
  sq[idx] = s;
}

// ---------------------------------------------------------------------------
// Attention: one block per (i, h, b). 256 threads.
// Computes logits[j] (j=0..1023), softmax, then PV for 64 scalar dims
// (written directly to feats) and 12 point dims (written to rp buffer).
// ---------------------------------------------------------------------------
__global__ __launch_bounds__(256) void attn_kernel(
    const float* __restrict__ qs, const float* __restrict__ ks,
    const float* __restrict__ vs, const float* __restrict__ qp,
    const float* __restrict__ kp, const float* __restrict__ vp,
    const float* __restrict__ q2, const float* __restrict__ k2,
    const float* __restrict__ point_weights,
    float* __restrict__ feats, float* __restrict__ rp_out) {
  const int i = blockIdx.x, h = blockIdx.y, b = blockIdx.z;
  const int tid = threadIdx.x;

  __shared__ float logits[N_];
  __shared__ float qrow[DH_ + PD_ * 3];
  __shared__ float red[256];

  // Stage q row
  if (tid < DH_) qrow[tid] = qs[((size_t)(b * N_ + i) * H_ + h) * DH_ + tid];
  else if (tid < DH_ + PD_ * 3)
    qrow[tid] = qp[((size_t)(b * N_ + i) * H_ + h) * (PD_ * 3) + (tid - DH_)];
  __syncthreads();

  const float pw = log1pf(expf(point_weights[h]));
  const float coef = 0.5f * POINT_SCALE * pw;
  const float q2v = q2[(size_t)(b * N_ + i) * H_ + h];

  // Phase 1: logits
  for (int j = tid; j < N_; j += 256) {
    const float* krow = ks + ((size_t)(b * N_ + j) * H_ + h) * DH_;
    float s = 0.0f;
#pragma unroll
    for (int d = 0; d < DH_; ++d) s += qrow[d] * krow[d];
    s *= SCALAR_SCALE;
    const float* kprow = kp + ((size_t)(b * N_ + j) * H_ + h) * (PD_ * 3);
    float qk = 0.0f;
#pragma unroll
    for (int e = 0; e < PD_ * 3; ++e) qk += qrow[DH_ + e] * kprow[e];
    float dist = q2v + k2[(size_t)(b * N_ + j) * H_ + h] - 2.0f * qk;
    logits[j] = s - coef * dist;
  }
  __syncthreads();

  // Softmax: max
  float m = -INFINITY;
  for (int j = tid; j < N_; j += 256) m = fmaxf(m, logits[j]);
  red[tid] = m;
  __syncthreads();
  for (int s = 128; s > 0; s >>= 1) {
    if (tid < s) red[tid] = fmaxf(red[tid], red[tid + s]);
    __syncthreads();
  }
  const float mx = red[0];
  __syncthreads();
  // exp + sum
  float sum = 0.0f;
  for (int j = tid; j < N_; j += 256) {
    float e = expf(logits[j] - mx);
    logits[j] = e;
    sum += e;
  }
  red[tid] = sum;
  __syncthreads();
  for (int s = 128; s > 0; s >>= 1) {
    if (tid < s) red[tid] += red[tid + s];
    __syncthreads();
  }
  const float inv_denom = 1.0f / red[0];
  __syncthreads();

  // Phase 2: scalar PV. tid = part*64 + d; part covers 256 j's.
  {
    const int d = tid & 63, part = tid >> 6;
    float acc = 0.0f;
    const int j0 = part * 256;
    for (int j = j0; j < j0 + 256; ++j)
      acc += logits[j] * vs[((size_t)(b * N_ + j) * H_ + h) * DH_ + d];
    red[tid] = acc;
    __syncthreads();
    if (tid < 64) {
      float v = red[tid] + red[tid + 64] + red[tid + 128] + red[tid + 192];
      feats[(size_t)(b * N_ + i) * 640 + h * DH_ + tid] = v * inv_denom;
    }
    __syncthreads();
  }

  // Phase 3: point PV. 192 threads: tid = part*12 + e; part covers 64 j's.
  {
    float acc = 0.0f;
    if (tid < 192) {
      const int e = tid % 12, part = tid / 12;
      const int j0 = part * 64;
      for (int j = j0; j < j0 + 64; ++j)
        acc += logits[j] * vp[((size_t)(b * N_ + j) * H_ + h) * (PD_ * 3) + e];
    }
    red[tid] = acc;
    __syncthreads();
    if (tid < 12) {
      float v = 0.0f;
#pragma unroll
      for (int p = 0; p < 16; ++p) v += red[p * 12 + tid];
      rp_out[((size_t)(b * N_ + i) * H_ + h) * (PD_ * 3) + tid] = v * inv_denom;
    }
  }
}

// ---------------------------------------------------------------------------
// Post: rotate back to local frame (R^T, after removing translation),
// compute norm, fill feats[512:640].
// idx enumerates (b*N+n)*H*PD + h*PD + d
// ---------------------------------------------------------------------------
__global__ __launch_bounds__(256) void post_kernel(
    const float* __restrict__ rp, const float* __restrict__ R,
    const float* __restrict__ t, float* __restrict__ feats, int total) {
  int idx = blockIdx.x * blockDim.x + threadIdx.x;
  if (idx >= total) return;
  int bn = idx / (H_ * PD_);
  int hd = idx % (H_ * PD_);
  int h = hd / PD_, d = hd % PD_;
  const float* Rv = R + (size_t)bn * 9;
  const float* tv = t + (size_t)bn * 3;
  float p0 = rp[idx * 3 + 0] - tv[0];
  float p1 = rp[idx * 3 + 1] - tv[1];
  float p2 = rp[idx * 3 + 2] - tv[2];
  // out[c] = sum_r R[r][c] * p[r]
  float o0 = Rv[0] * p0 + Rv[3] * p1 + Rv[6] * p2;
  float o1 = Rv[1] * p0 + Rv[4] * p1 + Rv[7] * p2;
  float o2 = Rv[2] * p0 + Rv[5] * p1 + Rv[8] * p2;
  float nrm = sqrtf(o0 * o0 + o1 * o1 + o2 * o2 + EPS_);
  float* f = feats + (size_t)bn * 640;
  f[512 + h * 12 + d * 3 + 0] = o0;
  f[512 + h * 12 + d * 3 + 1] = o1;
  f[512 + h * 12 + d * 3 + 2] = o2;
  f[608 + h * 4 + d] = nrm;
}

// ---------------------------------------------------------------------------
extern "C" void kernel_launch(void* const* d_in, const int* in_sizes, int n_in,
                              void* d_out, int out_size, void* d_ws, size_t ws_size,
                              hipStream_t stream) {
  const float* tgt    = (const float*)d_in[0];
  const float* memory = (const float*)d_in[1];
  const float* q_cent = (const float*)d_in[2];
  const float* q_vec  = (const float*)d_in[3];
  const float* k_cent = (const float*)d_in[4];
  const float* k_vec  = (const float*)d_in[5];
  const float* Wq_s   = (const float*)d_in[6];
  const float* Wk_s   = (const float*)d_in[7];
  const float* Wv_s   = (const float*)d_in[8];
  const float* Wq_p   = (const float*)d_in[9];
  const float* Wk_p   = (const float*)d_in[10];
  const float* Wv_p   = (const float*)d_in[11];
  const float* pw     = (const float*)d_in[12];
  const float* Wo     = (const float*)d_in[13];
  const float* bo     = (const float*)d_in[14];
  float* out = (float*)d_out;

  const int M = B_ * N_;            // 2048
  const int SD = H_ * DH_;          // 512
  const int PDIM = H_ * PD_ * 3;    // 96

  // Workspace carve-up (floats)
  float* ws = (float*)d_ws;
  size_t off = 0;
  float* qs     = ws + off; off += (size_t)M * SD;     // 1,048,576
  float* ks     = ws + off; off += (size_t)M * SD;
  float* vs     = ws + off; off += (size_t)M * SD;
  float* qp_raw = ws + off; off += (size_t)M * PDIM;   // 196,608
  float* kp_raw = ws + off; off += (size_t)M * PDIM;
  float* vp_raw = ws + off; off += (size_t)M * PDIM;
  float* qp_rot = ws + off; off += (size_t)M * PDIM;
  float* kp_rot = ws + off; off += (size_t)M * PDIM;
  float* vp_rot = ws + off; off += (size_t)M * PDIM;
  float* q2     = ws + off; off += (size_t)M * H_;     // 16,384
  float* k2     = ws + off; off += (size_t)M * H_;
  float* rp     = ws + off; off += (size_t)M * PDIM;
  float* feats  = ws + off; off += (size_t)M * 640;    // 1,310,720

  dim3 blk(256);

  // Projections
  gemm_kernel<<<dim3(SD / BN, M / BM), blk, 0, stream>>>(tgt,    Wq_s, nullptr, qs, M, SD, DIM_);
  gemm_kernel<<<dim3(SD / BN, M / BM), blk, 0, stream>>>(memory, Wk_s, nullptr, ks, M, SD, DIM_);
  gemm_kernel<<<dim3(SD / BN, M / BM), blk, 0, stream>>>(memory, Wv_s, nullptr, vs, M, SD, DIM_);
  gemm_kernel<<<dim3((PDIM + BN - 1) / BN, M / BM), blk, 0, stream>>>(tgt,    Wq_p, nullptr, qp_raw, M, PDIM, DIM_);
  gemm_kernel<<<dim3((PDIM + BN - 1) / BN, M / BM), blk, 0, stream>>>(memory, Wk_p, nullptr, kp_raw, M, PDIM, DIM_);
  gemm_kernel<<<dim3((PDIM + BN - 1) / BN, M / BM), blk, 0, stream>>>(memory, Wv_p, nullptr, vp_raw, M, PDIM, DIM_);

  // Rotate to global frame
  const int npts = M * H_ * PD_;  // 65536
  rotate_fwd_kernel<<<npts / 256, blk, 0, stream>>>(qp_raw, q_vec, q_cent, qp_rot, npts);
  rotate_fwd_kernel<<<npts / 256, blk, 0, stream>>>(kp_raw, k_vec, k_cent, kp_rot, npts);
  rotate_fwd_kernel<<<npts / 256, blk, 0, stream>>>(vp_raw, k_vec, k_cent, vp_rot, npts);

  // |q|^2, |k|^2 per (b,n,h)
  const int nbh = M * H_;  // 16384
  sumsq_kernel<<<nbh / 256, blk, 0, stream>>>(qp_rot, q2, nbh);
  sumsq_kernel<<<nbh / 256, blk, 0, stream>>>(kp_rot, k2, nbh);

  // Attention
  attn_kernel<<<dim3(N_, H_, B_), blk, 0, stream>>>(
      qs, ks, vs, qp_rot, kp_rot, vp_rot, q2, k2, pw, feats, rp);

  // Rotate back + norm + feats tail
  post_kernel<<<npts / 256, blk, 0, stream>>>(rp, q_vec, q_cent, feats, npts);

  // Output projection
  gemm_kernel<<<dim3(SD / BN, M / BM), blk, 0, stream>>>(feats, Wo, bo, out, M, SD, 640);
}

// Round 2
// 650.193 us; speedup vs baseline: 3.7026x; 3.7026x over previous
//
#include <hip/hip_runtime.h>
#include <math.h>

#define B_   2
#define N_   1024
#define DIM_ 512
#define H_   8
#define DH_  64
#define PD_  4

static constexpr float SCALAR_SCALE = 0.08838834764831845f; // (2*64)^-0.5
static constexpr float POINT_SCALE  = 0.16666666666666666f; // (2*4*4.5)^-0.5
static constexpr float EPS_         = 1e-8f;

typedef __attribute__((ext_vector_type(8))) short short8;
typedef __attribute__((ext_vector_type(4))) float f32x4;

__device__ __forceinline__ short f2bf(float x) {
  union { float f; unsigned u; } c; c.f = x;
  unsigned r = c.u + 0x7FFFu + ((c.u >> 16) & 1u);
  return (short)(r >> 16);
}

// ---------------------------------------------------------------------------
// Generic fp32 tiled GEMM: C[M,N] = A[M,K] @ W[K,N] (+ bias[N] if bias!=null)
// ---------------------------------------------------------------------------
#define BM 64
#define BN 64
#define BK 16
__global__ __launch_bounds__(256) void gemm_kernel(
    const float* __restrict__ A, const float* __restrict__ W,
    const float* __restrict__ bias, float* __restrict__ C,
    int M, int N, int K) {
  __shared__ float As[BK][BM + 1];
  __shared__ float Bs[BK][BN + 1];
  const int tid = threadIdx.x;
  const int tx = tid % 16, ty = tid / 16;
  const int row0 = blockIdx.y * BM, col0 = blockIdx.x * BN;
  float acc[4][4] = {};
  for (int k0 = 0; k0 < K; k0 += BK) {
    for (int i = tid; i < BM * BK; i += 256) {
      int m = i / BK, k = i % BK;
      As[k][m] = A[(size_t)(row0 + m) * K + k0 + k];
    }
    for (int i = tid; i < BK * BN; i += 256) {
      int k = i / BN, n = i % BN;
      int c = col0 + n;
      Bs[k][n] = (c < N) ? W[(size_t)(k0 + k) * N + c] : 0.0f;
    }
    __syncthreads();
#pragma unroll
    for (int k = 0; k < BK; ++k) {
      float a[4], b[4];
#pragma unroll
      for (int u = 0; u < 4; ++u) a[u] = As[k][ty * 4 + u];
#pragma unroll
      for (int v = 0; v < 4; ++v) b[v] = Bs[k][tx * 4 + v];
#pragma unroll
      for (int u = 0; u < 4; ++u)
#pragma unroll
        for (int v = 0; v < 4; ++v) acc[u][v] += a[u] * b[v];
    }
    __syncthreads();
  }
#pragma unroll
  for (int u = 0; u < 4; ++u)
#pragma unroll
    for (int v = 0; v < 4; ++v) {
      int r = row0 + ty * 4 + u, c = col0 + tx * 4 + v;
      if (c < N) C[(size_t)r * N + c] = acc[u][v] + (bias ? bias[c] : 0.0f);
    }
}

// ---------------------------------------------------------------------------
// In-place rotate to global frame: out[c] = sum_r R[c][r]*p[r] + t[c]
// ---------------------------------------------------------------------------
__global__ __launch_bounds__(256) void rotate_fwd_kernel(
    float* __restrict__ p, const float* __restrict__ R,
    const float* __restrict__ t, int total) {
  int idx = blockIdx.x * blockDim.x + threadIdx.x;
  if (idx >= total) return;
  int bn = idx / (H_ * PD_);
  const float* Rv = R + (size_t)bn * 9;
  const float* tv = t + (size_t)bn * 3;
  float p0 = p[idx * 3 + 0], p1 = p[idx * 3 + 1], p2 = p[idx * 3 + 2];
  p[idx * 3 + 0] = Rv[0] * p0 + Rv[1] * p1 + Rv[2] * p2 + tv[0];
  p[idx * 3 + 1] = Rv[3] * p0 + Rv[4] * p1 + Rv[5] * p2 + tv[1];
  p[idx * 3 + 2] = Rv[6] * p0 + Rv[7] * p1 + Rv[8] * p2 + tv[2];
}

// ---------------------------------------------------------------------------
// Build augmented Q in bf16: Qaug[b][h][n][96]
//   d<64: qs*SS ; 64..75: qp_rot*2*coef_h ; 76: 1.0 ; else 0
// ---------------------------------------------------------------------------
__global__ __launch_bounds__(256) void build_qaug_kernel(
    const float* __restrict__ qs, const float* __restrict__ qp,
    const float* __restrict__ point_weights, short* __restrict__ Qaug) {
  int idx = blockIdx.x * 256 + threadIdx.x;  // ((b*H+h)*N+n)*96 + d
  int d = idx % 96;
  int n = (idx / 96) % N_;
  int h = (idx / (96 * N_)) % H_;
  int b = idx / (96 * N_ * H_);
  int bn = b * N_ + n;
  float val;
  if (d < 64) {
    val = qs[(size_t)bn * 512 + h * 64 + d] * SCALAR_SCALE;
  } else if (d < 76) {
    float pwh = log1pf(expf(point_weights[h]));
    float coef = 0.5f * POINT_SCALE * pwh;
    val = qp[(size_t)bn * 96 + h * 12 + (d - 64)] * (2.0f * coef);
  } else if (d == 76) {
    val = 1.0f;
  } else {
    val = 0.0f;
  }
  Qaug[idx] = f2bf(val);
}

// Kaug: d<64: ks ; 64..75: kp_rot ; 76: -coef_h*|kp_rot|^2 ; else 0
__global__ __launch_bounds__(256) void build_kaug_kernel(
    const float* __restrict__ ks, const float* __restrict__ kp,
    const float* __restrict__ point_weights, short* __restrict__ Kaug) {
  int idx = blockIdx.x * 256 + threadIdx.x;
  int d = idx % 96;
  int n = (idx / 96) % N_;
  int h = (idx / (96 * N_)) % H_;
  int b = idx / (96 * N_ * H_);
  int bn = b * N_ + n;
  float val;
  if (d < 64) {
    val = ks[(size_t)bn * 512 + h * 64 + d];
  } else if (d < 76) {
    val = kp[(size_t)bn * 96 + h * 12 + (d - 64)];
  } else if (d == 76) {
    float pwh = log1pf(expf(point_weights[h]));
    float coef = 0.5f * POINT_SCALE * pwh;
    const float* kk = kp + (size_t)bn * 96 + h * 12;
    float s = 0.0f;
#pragma unroll
    for (int e = 0; e < 12; ++e) s += kk[e] * kk[e];
    val = -coef * s;
  } else {
    val = 0.0f;
  }
  Kaug[idx] = f2bf(val);
}

// ---------------------------------------------------------------------------
// Build transposed augmented V in bf16: Vt[b][h][80][N]
//   d<64: vs ; 64..75: vp_rot ; 76..79: 0
// One block per (64 n-rows, h, b); LDS transpose for coalescing both sides.
// ---------------------------------------------------------------------------
__global__ __launch_bounds__(256) void build_vt_kernel(
    const float* __restrict__ vs, const float* __restrict__ vp,
    short* __restrict__ Vt) {
  const int n0 = blockIdx.x * 64, h = blockIdx.y, b = blockIdx.z;
  const int tid = threadIdx.x;
  __shared__ float buf[64][85];
#pragma unroll
  for (int i = 0; i < 16; ++i) {
    int nl = i * 4 + (tid >> 6), d = tid & 63;
    buf[nl][d] = vs[(size_t)(b * N_ + n0 + nl) * 512 + h * 64 + d];
  }
#pragma unroll
  for (int i = 0; i < 3; ++i) {
    int idx = i * 256 + tid;
    int nl = idx / 12, dd = idx % 12;
    buf[nl][64 + dd] = vp[(size_t)(b * N_ + n0 + nl) * 96 + h * 12 + dd];
  }
  { int nl = tid >> 2, dd = 76 + (tid & 3); buf[nl][dd] = 0.0f; }
  __syncthreads();
#pragma unroll
  for (int i = 0; i < 20; ++i) {
    int d = i * 4 + (tid >> 6), nl = tid & 63;
    Vt[((size_t)(b * H_ + h) * 80 + d) * N_ + n0 + nl] = f2bf(buf[nl][d]);
  }
}

// ---------------------------------------------------------------------------
// Fused MFMA flash attention.
// Grid (N/64, H, B), 256 threads. Wave w owns q-rows it*64+w*16 .. +15.
// Qaug/Kaug: [bh][n][96] bf16 ; Vt: [bh][80][N] bf16.
// mfma_f32_16x16x32_bf16: A[row=l&15][k=(l>>4)*8+e], B[k=(l>>4)*8+e][col=l&15],
// C[row=(l>>4)*4+r][col=l&15].
// ---------------------------------------------------------------------------
__global__ __launch_bounds__(256) void flash_attn_kernel(
    const short* __restrict__ Qaug, const short* __restrict__ Kaug,
    const short* __restrict__ Vt, float* __restrict__ feats,
    float* __restrict__ rp_out) {
  const int it = blockIdx.x, h = blockIdx.y, b = blockIdx.z;
  const int bh = b * H_ + h;
  const int tid = threadIdx.x;
  const int wave = tid >> 6, lane = tid & 63;
  const int lg = lane >> 4, lr = lane & 15;

  __shared__ short K_lds[64][104];     // rows j, 96 used (pad 104: 2-way max)
  __shared__ short V_lds[80][72];      // rows d, 64 used (pad 72)
  __shared__ short P_lds[4][16][72];   // per-wave P tile, rows q, 64 used

  // Q fragments (persistent): 3 K-steps of 32
  short8 aQ[3];
  {
    const short* qrow = Qaug + ((size_t)bh * N_ + it * 64 + wave * 16 + lr) * 96;
#pragma unroll
    for (int s = 0; s < 3; ++s)
      aQ[s] = *(const short8*)(qrow + s * 32 + lg * 8);
  }

  f32x4 O[5];
  float m_run[4], l_run[4];
#pragma unroll
  for (int v = 0; v < 5; ++v)
#pragma unroll
    for (int r = 0; r < 4; ++r) O[v][r] = 0.0f;
#pragma unroll
  for (int r = 0; r < 4; ++r) { m_run[r] = -3.0e38f; l_run[r] = 0.0f; }

  for (int t = 0; t < N_ / 64; ++t) {
    const int j0 = t * 64;
    // stage K tile: 64 rows x 12 segs of 16B
#pragma unroll
    for (int c = 0; c < 3; ++c) {
      int idx = c * 256 + tid;
      int row = idx / 12, seg = idx % 12;
      *(short8*)(&K_lds[row][seg * 8]) =
          *(const short8*)(Kaug + ((size_t)bh * N_ + j0 + row) * 96 + seg * 8);
    }
    // stage V tile: 80 rows x 8 segs of 16B
#pragma unroll
    for (int c = 0; c < 3; ++c) {
      int idx = c * 256 + tid;
      if (idx < 640) {
        int row = idx / 8, seg = idx % 8;
        *(short8*)(&V_lds[row][seg * 8]) =
            *(const short8*)(Vt + ((size_t)bh * 80 + row) * N_ + j0 + seg * 8);
      }
    }
    __syncthreads();

    // S = Qaug @ Kaug^T : 4 j-frags x 3 k-steps
    f32x4 S[4];
#pragma unroll
    for (int f = 0; f < 4; ++f)
#pragma unroll
      for (int r = 0; r < 4; ++r) S[f][r] = 0.0f;
#pragma unroll
    for (int s = 0; s < 3; ++s) {
#pragma unroll
      for (int f = 0; f < 4; ++f) {
        short8 bK = *(const short8*)(&K_lds[f * 16 + lr][s * 32 + lg * 8]);
        S[f] = __builtin_amdgcn_mfma_f32_16x16x32_bf16(aQ[s], bK, S[f], 0, 0, 0);
      }
    }

    // online softmax (rows = lg*4 + r)
    float tmax[4];
#pragma unroll
    for (int r = 0; r < 4; ++r)
      tmax[r] = fmaxf(fmaxf(S[0][r], S[1][r]), fmaxf(S[2][r], S[3][r]));
#pragma unroll
    for (int mask = 1; mask < 16; mask <<= 1)
#pragma unroll
      for (int r = 0; r < 4; ++r)
        tmax[r] = fmaxf(tmax[r], __shfl_xor(tmax[r], mask, 16));
    float alpha[4];
#pragma unroll
    for (int r = 0; r < 4; ++r) {
      float mnew = fmaxf(m_run[r], tmax[r]);
      alpha[r] = __expf(m_run[r] - mnew);
      m_run[r] = mnew;
    }
#pragma unroll
    for (int f = 0; f < 4; ++f)
#pragma unroll
      for (int r = 0; r < 4; ++r) S[f][r] = __expf(S[f][r] - m_run[r]);
    float rsum[4];
#pragma unroll
    for (int r = 0; r < 4; ++r) rsum[r] = S[0][r] + S[1][r] + S[2][r] + S[3][r];
#pragma unroll
    for (int mask = 1; mask < 16; mask <<= 1)
#pragma unroll
      for (int r = 0; r < 4; ++r) rsum[r] += __shfl_xor(rsum[r], mask, 16);
#pragma unroll
    for (int r = 0; r < 4; ++r) l_run[r] = l_run[r] * alpha[r] + rsum[r];
#pragma unroll
    for (int v = 0; v < 5; ++v)
#pragma unroll
      for (int r = 0; r < 4; ++r) O[v][r] *= alpha[r];

    // P -> LDS (bf16), C-layout -> A-layout fixup through LDS
#pragma unroll
    for (int f = 0; f < 4; ++f)
#pragma unroll
      for (int r = 0; r < 4; ++r)
        P_lds[wave][lg * 4 + r][f * 16 + lr] = f2bf(S[f][r]);

    // O += P @ V : 2 k-steps over j, 5 d-frags
#pragma unroll
    for (int s2 = 0; s2 < 2; ++s2) {
      short8 aP = *(const short8*)(&P_lds[wave][lr][s2 * 32 + lg * 8]);
#pragma unroll
      for (int v = 0; v < 5; ++v) {
        short8 bV = *(const short8*)(&V_lds[v * 16 + lr][s2 * 32 + lg * 8]);
        O[v] = __builtin_amdgcn_mfma_f32_16x16x32_bf16(aP, bV, O[v], 0, 0, 0);
      }
    }
    __syncthreads();
  }

  // epilogue: O /= l ; scatter to feats (d<64) and rp (64<=d<76)
  const int i0 = it * 64 + wave * 16 + lg * 4;
  float inv[4];
#pragma unroll
  for (int r = 0; r < 4; ++r) inv[r] = 1.0f / l_run[r];
#pragma unroll
  for (int v = 0; v < 5; ++v) {
    const int d = v * 16 + lr;
#pragma unroll
    for (int r = 0; r < 4; ++r) {
      float val = O[v][r] * inv[r];
      int row = i0 + r;
      if (d < 64)
        feats[(size_t)(b * N_ + row) * 640 + h * 64 + d] = val;
      else if (d < 76)
        rp_out[((size_t)(b * N_ + row) * H_ + h) * 12 + (d - 64)] = val;
    }
  }
}

// ---------------------------------------------------------------------------
// Post: rotate back to local frame, norm, fill feats[512:640].
// ---------------------------------------------------------------------------
__global__ __launch_bounds__(256) void post_kernel(
    const float* __restrict__ rp, const float* __restrict__ R,
    const float* __restrict__ t, float* __restrict__ feats, int total) {
  int idx = blockIdx.x * blockDim.x + threadIdx.x;
  if (idx >= total) return;
  int bn = idx / (H_ * PD_);
  int hd = idx % (H_ * PD_);
  int h = hd / PD_, d = hd % PD_;
  const float* Rv = R + (size_t)bn * 9;
  const float* tv = t + (size_t)bn * 3;
  float p0 = rp[idx * 3 + 0] - tv[0];
  float p1 = rp[idx * 3 + 1] - tv[1];
  float p2 = rp[idx * 3 + 2] - tv[2];
  float o0 = Rv[0] * p0 + Rv[3] * p1 + Rv[6] * p2;
  float o1 = Rv[1] * p0 + Rv[4] * p1 + Rv[7] * p2;
  float o2 = Rv[2] * p0 + Rv[5] * p1 + Rv[8] * p2;
  float nrm = sqrtf(o0 * o0 + o1 * o1 + o2 * o2 + EPS_);
  float* f = feats + (size_t)bn * 640;
  f[512 + h * 12 + d * 3 + 0] = o0;
  f[512 + h * 12 + d * 3 + 1] = o1;
  f[512 + h * 12 + d * 3 + 2] = o2;
  f[608 + h * 4 + d] = nrm;
}

// ---------------------------------------------------------------------------
extern "C" void kernel_launch(void* const* d_in, const int* in_sizes, int n_in,
                              void* d_out, int out_size, void* d_ws, size_t ws_size,
                              hipStream_t stream) {
  const float* tgt    = (const float*)d_in[0];
  const float* memory = (const float*)d_in[1];
  const float* q_cent = (const float*)d_in[2];
  const float* q_vec  = (const float*)d_in[3];
  const float* k_cent = (const float*)d_in[4];
  const float* k_vec  = (const float*)d_in[5];
  const float* Wq_s   = (const float*)d_in[6];
  const float* Wk_s   = (const float*)d_in[7];
  const float* Wv_s   = (const float*)d_in[8];
  const float* Wq_p   = (const float*)d_in[9];
  const float* Wk_p   = (const float*)d_in[10];
  const float* Wv_p   = (const float*)d_in[11];
  const float* pw     = (const float*)d_in[12];
  const float* Wo     = (const float*)d_in[13];
  const float* bo     = (const float*)d_in[14];
  float* out = (float*)d_out;

  const int M = B_ * N_;          // 2048
  const int SD = H_ * DH_;        // 512
  const int PDIM = H_ * PD_ * 3;  // 96

  // Workspace carve-up
  float* ws = (float*)d_ws;
  size_t off = 0;
  float* qs    = ws + off; off += (size_t)M * SD;
  float* ks    = ws + off; off += (size_t)M * SD;
  float* vs    = ws + off; off += (size_t)M * SD;
  float* qp    = ws + off; off += (size_t)M * PDIM;
  float* kp    = ws + off; off += (size_t)M * PDIM;
  float* vp    = ws + off; off += (size_t)M * PDIM;
  float* rp    = ws + off; off += (size_t)M * PDIM;
  float* feats = ws + off; off += (size_t)M * 640;
  short* Qaug  = (short*)(ws + off); off += (size_t)M * H_ * 96 / 2;
  short* Kaug  = (short*)(ws + off); off += (size_t)M * H_ * 96 / 2;
  short* Vt    = (short*)(ws + off); off += (size_t)M * H_ * 80 / 2;

  dim3 blk(256);

  // Projections (fp32 tiled GEMM)
  gemm_kernel<<<dim3(SD / BN, M / BM), blk, 0, stream>>>(tgt,    Wq_s, nullptr, qs, M, SD, DIM_);
  gemm_kernel<<<dim3(SD / BN, M / BM), blk, 0, stream>>>(memory, Wk_s, nullptr, ks, M, SD, DIM_);
  gemm_kernel<<<dim3(SD / BN, M / BM), blk, 0, stream>>>(memory, Wv_s, nullptr, vs, M, SD, DIM_);
  gemm_kernel<<<dim3((PDIM + BN - 1) / BN, M / BM), blk, 0, stream>>>(tgt,    Wq_p, nullptr, qp, M, PDIM, DIM_);
  gemm_kernel<<<dim3((PDIM + BN - 1) / BN, M / BM), blk, 0, stream>>>(memory, Wk_p, nullptr, kp, M, PDIM, DIM_);
  gemm_kernel<<<dim3((PDIM + BN - 1) / BN, M / BM), blk, 0, stream>>>(memory, Wv_p, nullptr, vp, M, PDIM, DIM_);

  // Rotate to global frame (in place)
  const int npts = M * H_ * PD_;  // 65536
  rotate_fwd_kernel<<<npts / 256, blk, 0, stream>>>(qp, q_vec, q_cent, npts);
  rotate_fwd_kernel<<<npts / 256, blk, 0, stream>>>(kp, k_vec, k_cent, npts);
  rotate_fwd_kernel<<<npts / 256, blk, 0, stream>>>(vp, k_vec, k_cent, npts);

  // Build augmented bf16 Q/K/V^T
  const int naug = B_ * H_ * N_ * 96;  // 1,572,864
  build_qaug_kernel<<<naug / 256, blk, 0, stream>>>(qs, qp, pw, Qaug);
  build_kaug_kernel<<<naug / 256, blk, 0, stream>>>(ks, kp, pw, Kaug);
  build_vt_kernel<<<dim3(N_ / 64, H_, B_), blk, 0, stream>>>(vs, vp, Vt);

  // Fused flash attention
  flash_attn_kernel<<<dim3(N_ / 64, H_, B_), blk, 0, stream>>>(
      Qaug, Kaug, Vt, feats, rp);

  // Rotate back + norm + feats tail
  post_kernel<<<npts / 256, blk, 0, stream>>>(rp, q_vec, q_cent, feats, npts);

  // Output projection
  gemm_kernel<<<dim3(SD / BN, M / BM), blk, 0, stream>>>(feats, Wo, bo, out, M, SD, 640);
}

// Round 3
// 114.510 us; speedup vs baseline: 21.0234x; 5.6780x over previous
//
#include <hip/hip_runtime.h>
#include <math.h>

#define B_   2
#define N_   1024
#define DIM_ 512
#define H_   8
#define DH_  64
#define PD_  4

static constexpr float SCALAR_SCALE = 0.08838834764831845f; // (2*64)^-0.5
static constexpr float POINT_SCALE  = 0.16666666666666666f; // (2*4*4.5)^-0.5
static constexpr float EPS_         = 1e-8f;

typedef __attribute__((ext_vector_type(8))) short short8;
typedef __attribute__((ext_vector_type(4))) float f32x4;

__device__ __forceinline__ short f2bf(float x) {
  union { float f; unsigned u; } c; c.f = x;
  unsigned r = c.u + 0x7FFFu + ((c.u >> 16) & 1u);
  return (short)(r >> 16);
}

// ---------------------------------------------------------------------------
// Convert tgt+memory (2048x512 fp32 each) to bf16. 8 elems/thread.
// ---------------------------------------------------------------------------
__global__ __launch_bounds__(256) void convert_inputs_kernel(
    const float* __restrict__ tgt, const float* __restrict__ memory,
    short* __restrict__ Atgt, short* __restrict__ Amem) {
  const int tot8 = 2048 * 512 / 8;  // 131072
  int idx = blockIdx.x * 256 + threadIdx.x;
  const float* src;
  short* dst;
  int o;
  if (idx < tot8) { src = tgt; dst = Atgt; o = idx; }
  else            { src = memory; dst = Amem; o = idx - tot8; }
  float4 lo = ((const float4*)src)[o * 2];
  float4 hi = ((const float4*)src)[o * 2 + 1];
  short8 v;
  v[0] = f2bf(lo.x); v[1] = f2bf(lo.y); v[2] = f2bf(lo.z); v[3] = f2bf(lo.w);
  v[4] = f2bf(hi.x); v[5] = f2bf(hi.y); v[6] = f2bf(hi.z); v[7] = f2bf(hi.w);
  ((short8*)dst)[o] = v;
}

// ---------------------------------------------------------------------------
// Pack weights into transposed bf16 buffers (row = output col, K-contiguous):
//   Wt_tgt[640][512]: n<512 Wq_s*SS | 512..607 Wq_p | pad 0
//   Wt_mem[1280][512]: Wk_s | Wv_s | Wk_p | Wv_p | pad 0
//   Wot[512][640]: Wo^T
// Each thread: 8 consecutive k for one n (coalesced 16B store).
// ---------------------------------------------------------------------------
__global__ __launch_bounds__(256) void pack_weights_kernel(
    const float* __restrict__ Wq_s, const float* __restrict__ Wq_p,
    const float* __restrict__ Wk_s, const float* __restrict__ Wv_s,
    const float* __restrict__ Wk_p, const float* __restrict__ Wv_p,
    const float* __restrict__ Wo,
    short* __restrict__ Wt_tgt, short* __restrict__ Wt_mem,
    short* __restrict__ Wot) {
  const int SA = 640 * 64, SB = 1280 * 64, SC = 512 * 80;
  int idx = blockIdx.x * 256 + threadIdx.x;
  float v[8];
  if (idx < SA) {
    int n = idx / 64, k0 = (idx % 64) * 8;
#pragma unroll
    for (int e = 0; e < 8; ++e) {
      int k = k0 + e;
      if (n < 512)      v[e] = Wq_s[(size_t)k * 512 + n] * SCALAR_SCALE;
      else if (n < 608) v[e] = Wq_p[(size_t)k * 96 + (n - 512)];
      else              v[e] = 0.0f;
    }
    short8 o;
#pragma unroll
    for (int e = 0; e < 8; ++e) o[e] = f2bf(v[e]);
    *(short8*)(Wt_tgt + (size_t)n * 512 + k0) = o;
  } else if (idx < SA + SB) {
    int j = idx - SA;
    int n = j / 64, k0 = (j % 64) * 8;
#pragma unroll
    for (int e = 0; e < 8; ++e) {
      int k = k0 + e;
      if (n < 512)       v[e] = Wk_s[(size_t)k * 512 + n];
      else if (n < 1024) v[e] = Wv_s[(size_t)k * 512 + (n - 512)];
      else if (n < 1120) v[e] = Wk_p[(size_t)k * 96 + (n - 1024)];
      else if (n < 1216) v[e] = Wv_p[(size_t)k * 96 + (n - 1120)];
      else               v[e] = 0.0f;
    }
    short8 o;
#pragma unroll
    for (int e = 0; e < 8; ++e) o[e] = f2bf(v[e]);
    *(short8*)(Wt_mem + (size_t)n * 512 + k0) = o;
  } else if (idx < SA + SB + SC) {
    int j = idx - SA - SB;
    int n = j / 80, k0 = (j % 80) * 8;
#pragma unroll
    for (int e = 0; e < 8; ++e) v[e] = Wo[(size_t)(k0 + e) * 512 + n];
    short8 o;
#pragma unroll
    for (int e = 0; e < 8; ++e) o[e] = f2bf(v[e]);
    *(short8*)(Wot + (size_t)n * 640 + k0) = o;
  }
}

// ---------------------------------------------------------------------------
// bf16 MFMA GEMM: C[M][ldc] fp32 = A[M][K] @ Bt[Npad][K]^T (+bias)
// Grid (Npad/64, M/64), 256 threads = 4 waves (2x2), each wave 32x32.
// Reg-staged LDS, padded stride 72 (<=2-way bank conflicts).
// ---------------------------------------------------------------------------
__global__ __launch_bounds__(256) void gemm64_kernel(
    const short* __restrict__ A, const short* __restrict__ Bt,
    const float* __restrict__ bias, float* __restrict__ C,
    int K, int ldc) {
  const int row0 = blockIdx.y * 64, col0 = blockIdx.x * 64;
  const int tid = threadIdx.x, wave = tid >> 6, lane = tid & 63;
  const int wr = wave >> 1, wc = wave & 1;
  const int lg = lane >> 4, lr = lane & 15;
  const int l8 = lane >> 3, l7 = lane & 7;

  __shared__ short Al[64][72];
  __shared__ short Bl[64][72];

  f32x4 acc[2][2];
#pragma unroll
  for (int m = 0; m < 2; ++m)
#pragma unroll
    for (int n = 0; n < 2; ++n)
#pragma unroll
      for (int r = 0; r < 4; ++r) acc[m][n][r] = 0.0f;

  for (int kt = 0; kt < K; kt += 64) {
    short8 areg[2], breg[2];
#pragma unroll
    for (int i = 0; i < 2; ++i) {
      int r = wave * 16 + i * 8 + l8;
      areg[i] = *(const short8*)(A + (size_t)(row0 + r) * K + kt + l7 * 8);
      breg[i] = *(const short8*)(Bt + (size_t)(col0 + r) * K + kt + l7 * 8);
    }
    __syncthreads();
#pragma unroll
    for (int i = 0; i < 2; ++i) {
      int r = wave * 16 + i * 8 + l8;
      *(short8*)(&Al[r][l7 * 8]) = areg[i];
      *(short8*)(&Bl[r][l7 * 8]) = breg[i];
    }
    __syncthreads();
#pragma unroll
    for (int ks = 0; ks < 2; ++ks) {
      short8 aA[2], bB[2];
#pragma unroll
      for (int m = 0; m < 2; ++m)
        aA[m] = *(const short8*)(&Al[wr * 32 + m * 16 + lr][ks * 32 + lg * 8]);
#pragma unroll
      for (int n = 0; n < 2; ++n)
        bB[n] = *(const short8*)(&Bl[wc * 32 + n * 16 + lr][ks * 32 + lg * 8]);
#pragma unroll
      for (int m = 0; m < 2; ++m)
#pragma unroll
        for (int n = 0; n < 2; ++n)
          acc[m][n] = __builtin_amdgcn_mfma_f32_16x16x32_bf16(aA[m], bB[n], acc[m][n], 0, 0, 0);
    }
  }

#pragma unroll
  for (int m = 0; m < 2; ++m)
#pragma unroll
    for (int n = 0; n < 2; ++n)
#pragma unroll
      for (int r = 0; r < 4; ++r) {
        int row = row0 + wr * 32 + m * 16 + lg * 4 + r;
        int col = col0 + wc * 32 + n * 16 + lr;
        float val = acc[m][n][r] + (bias ? bias[col] : 0.0f);
        C[(size_t)row * ldc + col] = val;
      }
}

// ---------------------------------------------------------------------------
// Rotate all three point sets to global frame, in place inside fused buffers.
// seg 0: qp in Ptgt (cols 512+), seg 1: kp in Pmem (1024+), seg 2: vp (1120+)
// ---------------------------------------------------------------------------
__global__ __launch_bounds__(256) void rotate_all_kernel(
    float* __restrict__ Ptgt, float* __restrict__ Pmem,
    const float* __restrict__ qv, const float* __restrict__ qc,
    const float* __restrict__ kv, const float* __restrict__ kc) {
  int idx = blockIdx.x * 256 + threadIdx.x;
  int seg = idx >> 16;          // 65536 points per segment
  int p = idx & 65535;
  int bn = p >> 5;              // 32 points (H*PD) per bn
  int e = p & 31;
  float* base;
  const float* R;
  const float* t;
  if (seg == 0)      { base = Ptgt + (size_t)bn * 640 + 512;  R = qv; t = qc; }
  else if (seg == 1) { base = Pmem + (size_t)bn * 1280 + 1024; R = kv; t = kc; }
  else               { base = Pmem + (size_t)bn * 1280 + 1120; R = kv; t = kc; }
  const float* Rv = R + (size_t)bn * 9;
  const float* tv = t + (size_t)bn * 3;
  float* pp = base + e * 3;
  float p0 = pp[0], p1 = pp[1], p2 = pp[2];
  pp[0] = Rv[0] * p0 + Rv[1] * p1 + Rv[2] * p2 + tv[0];
  pp[1] = Rv[3] * p0 + Rv[4] * p1 + Rv[5] * p2 + tv[1];
  pp[2] = Rv[6] * p0 + Rv[7] * p1 + Rv[8] * p2 + tv[2];
}

// ---------------------------------------------------------------------------
// Build augmented Q and K (bf16): [b][h][n][96]
// blockIdx.y: 0 = Q (from Ptgt), 1 = K (from Pmem)
// ---------------------------------------------------------------------------
__global__ __launch_bounds__(256) void build_qkaug_kernel(
    const float* __restrict__ Ptgt, const float* __restrict__ Pmem,
    const float* __restrict__ point_weights,
    short* __restrict__ Qaug, short* __restrict__ Kaug) {
  int idx = blockIdx.x * 256 + threadIdx.x;
  int d = idx % 96;
  int n = (idx / 96) % N_;
  int h = (idx / (96 * N_)) % H_;
  int b = idx / (96 * N_ * H_);
  int bn = b * N_ + n;
  float pwh = log1pf(expf(point_weights[h]));
  float coef = 0.5f * POINT_SCALE * pwh;
  float val;
  if (blockIdx.y == 0) {
    if (d < 64)      val = Ptgt[(size_t)bn * 640 + h * 64 + d];        // pre-scaled
    else if (d < 76) val = Ptgt[(size_t)bn * 640 + 512 + h * 12 + (d - 64)] * (2.0f * coef);
    else if (d == 76) val = 1.0f;
    else             val = 0.0f;
    Qaug[idx] = f2bf(val);
  } else {
    if (d < 64)      val = Pmem[(size_t)bn * 1280 + h * 64 + d];
    else if (d < 76) val = Pmem[(size_t)bn * 1280 + 1024 + h * 12 + (d - 64)];
    else if (d == 76) {
      const float* kk = Pmem + (size_t)bn * 1280 + 1024 + h * 12;
      float s = 0.0f;
#pragma unroll
      for (int e = 0; e < 12; ++e) s += kk[e] * kk[e];
      val = -coef * s;
    } else val = 0.0f;
    Kaug[idx] = f2bf(val);
  }
}

// ---------------------------------------------------------------------------
// Build transposed augmented V (bf16): Vt[b][h][80][N]
// ---------------------------------------------------------------------------
__global__ __launch_bounds__(256) void build_vt_kernel(
    const float* __restrict__ Pmem, short* __restrict__ Vt) {
  const int n0 = blockIdx.x * 64, h = blockIdx.y, b = blockIdx.z;
  const int tid = threadIdx.x;
  __shared__ float buf[64][85];
#pragma unroll
  for (int i = 0; i < 16; ++i) {
    int nl = i * 4 + (tid >> 6), d = tid & 63;
    buf[nl][d] = Pmem[(size_t)(b * N_ + n0 + nl) * 1280 + 512 + h * 64 + d];
  }
#pragma unroll
  for (int i = 0; i < 3; ++i) {
    int idx = i * 256 + tid;
    int nl = idx / 12, dd = idx % 12;
    buf[nl][64 + dd] = Pmem[(size_t)(b * N_ + n0 + nl) * 1280 + 1120 + h * 12 + dd];
  }
  { int nl = tid >> 2, dd = 76 + (tid & 3); buf[nl][dd] = 0.0f; }
  __syncthreads();
#pragma unroll
  for (int i = 0; i < 20; ++i) {
    int d = i * 4 + (tid >> 6), nl = tid & 63;
    Vt[((size_t)(b * H_ + h) * 80 + d) * N_ + n0 + nl] = f2bf(buf[nl][d]);
  }
}

// ---------------------------------------------------------------------------
// Fused MFMA flash attention (as R1), feats now bf16.
// ---------------------------------------------------------------------------
__global__ __launch_bounds__(256) void flash_attn_kernel(
    const short* __restrict__ Qaug, const short* __restrict__ Kaug,
    const short* __restrict__ Vt, short* __restrict__ featsB,
    float* __restrict__ rp_out) {
  const int it = blockIdx.x, h = blockIdx.y, b = blockIdx.z;
  const int bh = b * H_ + h;
  const int tid = threadIdx.x;
  const int wave = tid >> 6, lane = tid & 63;
  const int lg = lane >> 4, lr = lane & 15;

  __shared__ short K_lds[64][104];
  __shared__ short V_lds[80][72];
  __shared__ short P_lds[4][16][72];

  short8 aQ[3];
  {
    const short* qrow = Qaug + ((size_t)bh * N_ + it * 64 + wave * 16 + lr) * 96;
#pragma unroll
    for (int s = 0; s < 3; ++s)
      aQ[s] = *(const short8*)(qrow + s * 32 + lg * 8);
  }

  f32x4 O[5];
  float m_run[4], l_run[4];
#pragma unroll
  for (int v = 0; v < 5; ++v)
#pragma unroll
    for (int r = 0; r < 4; ++r) O[v][r] = 0.0f;
#pragma unroll
  for (int r = 0; r < 4; ++r) { m_run[r] = -3.0e38f; l_run[r] = 0.0f; }

  for (int t = 0; t < N_ / 64; ++t) {
    const int j0 = t * 64;
#pragma unroll
    for (int c = 0; c < 3; ++c) {
      int idx = c * 256 + tid;
      int row = idx / 12, seg = idx % 12;
      *(short8*)(&K_lds[row][seg * 8]) =
          *(const short8*)(Kaug + ((size_t)bh * N_ + j0 + row) * 96 + seg * 8);
    }
#pragma unroll
    for (int c = 0; c < 3; ++c) {
      int idx = c * 256 + tid;
      if (idx < 640) {
        int row = idx / 8, seg = idx % 8;
        *(short8*)(&V_lds[row][seg * 8]) =
            *(const short8*)(Vt + ((size_t)bh * 80 + row) * N_ + j0 + seg * 8);
      }
    }
    __syncthreads();

    f32x4 S[4];
#pragma unroll
    for (int f = 0; f < 4; ++f)
#pragma unroll
      for (int r = 0; r < 4; ++r) S[f][r] = 0.0f;
#pragma unroll
    for (int s = 0; s < 3; ++s) {
#pragma unroll
      for (int f = 0; f < 4; ++f) {
        short8 bK = *(const short8*)(&K_lds[f * 16 + lr][s * 32 + lg * 8]);
        S[f] = __builtin_amdgcn_mfma_f32_16x16x32_bf16(aQ[s], bK, S[f], 0, 0, 0);
      }
    }

    float tmax[4];
#pragma unroll
    for (int r = 0; r < 4; ++r)
      tmax[r] = fmaxf(fmaxf(S[0][r], S[1][r]), fmaxf(S[2][r], S[3][r]));
#pragma unroll
    for (int mask = 1; mask < 16; mask <<= 1)
#pragma unroll
      for (int r = 0; r < 4; ++r)
        tmax[r] = fmaxf(tmax[r], __shfl_xor(tmax[r], mask, 16));
    float alpha[4];
#pragma unroll
    for (int r = 0; r < 4; ++r) {
      float mnew = fmaxf(m_run[r], tmax[r]);
      alpha[r] = __expf(m_run[r] - mnew);
      m_run[r] = mnew;
    }
#pragma unroll
    for (int f = 0; f < 4; ++f)
#pragma unroll
      for (int r = 0; r < 4; ++r) S[f][r] = __expf(S[f][r] - m_run[r]);
    float rsum[4];
#pragma unroll
    for (int r = 0; r < 4; ++r) rsum[r] = S[0][r] + S[1][r] + S[2][r] + S[3][r];
#pragma unroll
    for (int mask = 1; mask < 16; mask <<= 1)
#pragma unroll
      for (int r = 0; r < 4; ++r) rsum[r] += __shfl_xor(rsum[r], mask, 16);
#pragma unroll
    for (int r = 0; r < 4; ++r) l_run[r] = l_run[r] * alpha[r] + rsum[r];
#pragma unroll
    for (int v = 0; v < 5; ++v)
#pragma unroll
      for (int r = 0; r < 4; ++r) O[v][r] *= alpha[r];

#pragma unroll
    for (int f = 0; f < 4; ++f)
#pragma unroll
      for (int r = 0; r < 4; ++r)
        P_lds[wave][lg * 4 + r][f * 16 + lr] = f2bf(S[f][r]);

#pragma unroll
    for (int s2 = 0; s2 < 2; ++s2) {
      short8 aP = *(const short8*)(&P_lds[wave][lr][s2 * 32 + lg * 8]);
#pragma unroll
      for (int v = 0; v < 5; ++v) {
        short8 bV = *(const short8*)(&V_lds[v * 16 + lr][s2 * 32 + lg * 8]);
        O[v] = __builtin_amdgcn_mfma_f32_16x16x32_bf16(aP, bV, O[v], 0, 0, 0);
      }
    }
    __syncthreads();
  }

  const int i0 = it * 64 + wave * 16 + lg * 4;
  float inv[4];
#pragma unroll
  for (int r = 0; r < 4; ++r) inv[r] = 1.0f / l_run[r];
#pragma unroll
  for (int v = 0; v < 5; ++v) {
    const int d = v * 16 + lr;
#pragma unroll
    for (int r = 0; r < 4; ++r) {
      float val = O[v][r] * inv[r];
      int row = i0 + r;
      if (d < 64)
        featsB[(size_t)(b * N_ + row) * 640 + h * 64 + d] = f2bf(val);
      else if (d < 76)
        rp_out[((size_t)(b * N_ + row) * H_ + h) * 12 + (d - 64)] = val;
    }
  }
}

// ---------------------------------------------------------------------------
// Post: rotate back, norm, fill featsB[512:640] (bf16).
// ---------------------------------------------------------------------------
__global__ __launch_bounds__(256) void post_kernel(
    const float* __restrict__ rp, const float* __restrict__ R,
    const float* __restrict__ t, short* __restrict__ featsB, int total) {
  int idx = blockIdx.x * blockDim.x + threadIdx.x;
  if (idx >= total) return;
  int bn = idx / (H_ * PD_);
  int hd = idx % (H_ * PD_);
  int h = hd / PD_, d = hd % PD_;
  const float* Rv = R + (size_t)bn * 9;
  const float* tv = t + (size_t)bn * 3;
  float p0 = rp[idx * 3 + 0] - tv[0];
  float p1 = rp[idx * 3 + 1] - tv[1];
  float p2 = rp[idx * 3 + 2] - tv[2];
  float o0 = Rv[0] * p0 + Rv[3] * p1 + Rv[6] * p2;
  float o1 = Rv[1] * p0 + Rv[4] * p1 + Rv[7] * p2;
  float o2 = Rv[2] * p0 + Rv[5] * p1 + Rv[8] * p2;
  float nrm = sqrtf(o0 * o0 + o1 * o1 + o2 * o2 + EPS_);
  short* f = featsB + (size_t)bn * 640;
  f[512 + h * 12 + d * 3 + 0] = f2bf(o0);
  f[512 + h * 12 + d * 3 + 1] = f2bf(o1);
  f[512 + h * 12 + d * 3 + 2] = f2bf(o2);
  f[608 + h * 4 + d] = f2bf(nrm);
}

// ---------------------------------------------------------------------------
extern "C" void kernel_launch(void* const* d_in, const int* in_sizes, int n_in,
                              void* d_out, int out_size, void* d_ws, size_t ws_size,
                              hipStream_t stream) {
  const float* tgt    = (const float*)d_in[0];
  const float* memory = (const float*)d_in[1];
  const float* q_cent = (const float*)d_in[2];
  const float* q_vec  = (const float*)d_in[3];
  const float* k_cent = (const float*)d_in[4];
  const float* k_vec  = (const float*)d_in[5];
  const float* Wq_s   = (const float*)d_in[6];
  const float* Wk_s   = (const float*)d_in[7];
  const float* Wv_s   = (const float*)d_in[8];
  const float* Wq_p   = (const float*)d_in[9];
  const float* Wk_p   = (const float*)d_in[10];
  const float* Wv_p   = (const float*)d_in[11];
  const float* pw     = (const float*)d_in[12];
  const float* Wo     = (const float*)d_in[13];
  const float* bo     = (const float*)d_in[14];
  float* out = (float*)d_out;

  const int M = B_ * N_;  // 2048

  // Workspace carve-up
  char* wsb = (char*)d_ws;
  size_t off = 0;
  auto alloc = [&](size_t bytes) { char* p = wsb + off; off += (bytes + 255) & ~(size_t)255; return p; };
  short* Atgt   = (short*)alloc((size_t)M * 512 * 2);
  short* Amem   = (short*)alloc((size_t)M * 512 * 2);
  short* Wt_tgt = (short*)alloc((size_t)640 * 512 * 2);
  short* Wt_mem = (short*)alloc((size_t)1280 * 512 * 2);
  short* Wot    = (short*)alloc((size_t)512 * 640 * 2);
  float* Ptgt   = (float*)alloc((size_t)M * 640 * 4);
  float* Pmem   = (float*)alloc((size_t)M * 1280 * 4);
  short* Qaug   = (short*)alloc((size_t)M * H_ * 96 * 2);
  short* Kaug   = (short*)alloc((size_t)M * H_ * 96 * 2);
  short* Vt     = (short*)alloc((size_t)M * H_ * 80 * 2);
  short* featsB = (short*)alloc((size_t)M * 640 * 2);
  float* rp     = (float*)alloc((size_t)M * 96 * 4);

  dim3 blk(256);

  // 1. inputs -> bf16
  convert_inputs_kernel<<<2 * (M * 512 / 8) / 256, blk, 0, stream>>>(tgt, memory, Atgt, Amem);
  // 2. pack weights (transposed bf16, SCALAR_SCALE folded into Wq_s)
  pack_weights_kernel<<<(640 * 64 + 1280 * 64 + 512 * 80) / 256, blk, 0, stream>>>(
      Wq_s, Wq_p, Wk_s, Wv_s, Wk_p, Wv_p, Wo, Wt_tgt, Wt_mem, Wot);
  // 3. fused projections
  gemm64_kernel<<<dim3(640 / 64, M / 64), blk, 0, stream>>>(Atgt, Wt_tgt, nullptr, Ptgt, 512, 640);
  gemm64_kernel<<<dim3(1280 / 64, M / 64), blk, 0, stream>>>(Amem, Wt_mem, nullptr, Pmem, 512, 1280);
  // 4. rotate all point sets in place
  rotate_all_kernel<<<3 * 65536 / 256, blk, 0, stream>>>(Ptgt, Pmem, q_vec, q_cent, k_vec, k_cent);
  // 5. build augmented Q/K and V^T
  build_qkaug_kernel<<<dim3(B_ * H_ * N_ * 96 / 256, 2), blk, 0, stream>>>(Ptgt, Pmem, pw, Qaug, Kaug);
  build_vt_kernel<<<dim3(N_ / 64, H_, B_), blk, 0, stream>>>(Pmem, Vt);
  // 6. flash attention
  flash_attn_kernel<<<dim3(N_ / 64, H_, B_), blk, 0, stream>>>(Qaug, Kaug, Vt, featsB, rp);
  // 7. rotate back + norm + feats tail
  post_kernel<<<(M * H_ * PD_) / 256, blk, 0, stream>>>(rp, q_vec, q_cent, featsB, M * H_ * PD_);
  // 8. output projection
  gemm64_kernel<<<dim3(512 / 64, M / 64), blk, 0, stream>>>(featsB, Wot, bo, out, 640, 512);
}

// Round 4
// 102.635 us; speedup vs baseline: 23.4559x; 1.1157x over previous
//
#include <hip/hip_runtime.h>
#include <math.h>

#define B_   2
#define N_   1024
#define DIM_ 512
#define H_   8
#define DH_  64
#define PD_  4

static constexpr float SCALAR_SCALE = 0.08838834764831845f; // (2*64)^-0.5
static constexpr float POINT_SCALE  = 0.16666666666666666f; // (2*4*4.5)^-0.5
static constexpr float EPS_         = 1e-8f;

typedef __attribute__((ext_vector_type(8))) short short8;
typedef __attribute__((ext_vector_type(4))) float f32x4;

__device__ __forceinline__ short f2bf(float x) {
  union { float f; unsigned u; } c; c.f = x;
  unsigned r = c.u + 0x7FFFu + ((c.u >> 16) & 1u);
  return (short)(r >> 16);
}

// ---------------------------------------------------------------------------
// Prep: convert tgt/memory to bf16 + pack all weights (transposed bf16).
//   Wt_tgt[640][512]: Wq_s*SS | Wq_p | 0 ; Wt_mem[1280][512]: Wk_s|Wv_s|Wk_p|Wv_p
//   Wot[512][640]: Wo^T
// ---------------------------------------------------------------------------
__global__ __launch_bounds__(256) void prep_kernel(
    const float* __restrict__ tgt, const float* __restrict__ memory,
    const float* __restrict__ Wq_s, const float* __restrict__ Wq_p,
    const float* __restrict__ Wk_s, const float* __restrict__ Wv_s,
    const float* __restrict__ Wk_p, const float* __restrict__ Wv_p,
    const float* __restrict__ Wo,
    short* __restrict__ Atgt, short* __restrict__ Amem,
    short* __restrict__ Wt_tgt, short* __restrict__ Wt_mem,
    short* __restrict__ Wot) {
  const int CONV = 2048 * 512 / 8;  // 131072 per input
  const int SA = 640 * 64, SB = 1280 * 64, SC = 512 * 80;
  int idx = blockIdx.x * 256 + threadIdx.x;
  if (idx < 2 * CONV) {
    const float* src = (idx < CONV) ? tgt : memory;
    short* dst = (idx < CONV) ? Atgt : Amem;
    int o = (idx < CONV) ? idx : idx - CONV;
    float4 lo = ((const float4*)src)[o * 2];
    float4 hi = ((const float4*)src)[o * 2 + 1];
    short8 v;
    v[0] = f2bf(lo.x); v[1] = f2bf(lo.y); v[2] = f2bf(lo.z); v[3] = f2bf(lo.w);
    v[4] = f2bf(hi.x); v[5] = f2bf(hi.y); v[6] = f2bf(hi.z); v[7] = f2bf(hi.w);
    ((short8*)dst)[o] = v;
    return;
  }
  idx -= 2 * CONV;
  float v[8];
  if (idx < SA) {
    int n = idx / 64, k0 = (idx % 64) * 8;
#pragma unroll
    for (int e = 0; e < 8; ++e) {
      int k = k0 + e;
      if (n < 512)      v[e] = Wq_s[(size_t)k * 512 + n] * SCALAR_SCALE;
      else if (n < 608) v[e] = Wq_p[(size_t)k * 96 + (n - 512)];
      else              v[e] = 0.0f;
    }
    short8 o;
#pragma unroll
    for (int e = 0; e < 8; ++e) o[e] = f2bf(v[e]);
    *(short8*)(Wt_tgt + (size_t)n * 512 + k0) = o;
  } else if (idx < SA + SB) {
    int j = idx - SA;
    int n = j / 64, k0 = (j % 64) * 8;
#pragma unroll
    for (int e = 0; e < 8; ++e) {
      int k = k0 + e;
      if (n < 512)       v[e] = Wk_s[(size_t)k * 512 + n];
      else if (n < 1024) v[e] = Wv_s[(size_t)k * 512 + (n - 512)];
      else if (n < 1120) v[e] = Wk_p[(size_t)k * 96 + (n - 1024)];
      else if (n < 1216) v[e] = Wv_p[(size_t)k * 96 + (n - 1120)];
      else               v[e] = 0.0f;
    }
    short8 o;
#pragma unroll
    for (int e = 0; e < 8; ++e) o[e] = f2bf(v[e]);
    *(short8*)(Wt_mem + (size_t)n * 512 + k0) = o;
  } else if (idx < SA + SB + SC) {
    int j = idx - SA - SB;
    int n = j / 80, k0 = (j % 80) * 8;
#pragma unroll
    for (int e = 0; e < 8; ++e) v[e] = Wo[(size_t)(k0 + e) * 512 + n];
    short8 o;
#pragma unroll
    for (int e = 0; e < 8; ++e) o[e] = f2bf(v[e]);
    *(short8*)(Wot + (size_t)n * 640 + k0) = o;
  }
}

// ---------------------------------------------------------------------------
// bf16 MFMA GEMM: C[M][ldc] fp32 = A[M][K] @ Bt[Npad][K]^T (+bias)
// ---------------------------------------------------------------------------
__global__ __launch_bounds__(256) void gemm64_kernel(
    const short* __restrict__ A, const short* __restrict__ Bt,
    const float* __restrict__ bias, float* __restrict__ C,
    int K, int ldc) {
  const int row0 = blockIdx.y * 64, col0 = blockIdx.x * 64;
  const int tid = threadIdx.x, wave = tid >> 6, lane = tid & 63;
  const int wr = wave >> 1, wc = wave & 1;
  const int lg = lane >> 4, lr = lane & 15;
  const int l8 = lane >> 3, l7 = lane & 7;

  __shared__ short Al[64][72];
  __shared__ short Bl[64][72];

  f32x4 acc[2][2];
#pragma unroll
  for (int m = 0; m < 2; ++m)
#pragma unroll
    for (int n = 0; n < 2; ++n)
#pragma unroll
      for (int r = 0; r < 4; ++r) acc[m][n][r] = 0.0f;

  for (int kt = 0; kt < K; kt += 64) {
    short8 areg[2], breg[2];
#pragma unroll
    for (int i = 0; i < 2; ++i) {
      int r = wave * 16 + i * 8 + l8;
      areg[i] = *(const short8*)(A + (size_t)(row0 + r) * K + kt + l7 * 8);
      breg[i] = *(const short8*)(Bt + (size_t)(col0 + r) * K + kt + l7 * 8);
    }
    __syncthreads();
#pragma unroll
    for (int i = 0; i < 2; ++i) {
      int r = wave * 16 + i * 8 + l8;
      *(short8*)(&Al[r][l7 * 8]) = areg[i];
      *(short8*)(&Bl[r][l7 * 8]) = breg[i];
    }
    __syncthreads();
#pragma unroll
    for (int ks = 0; ks < 2; ++ks) {
      short8 aA[2], bB[2];
#pragma unroll
      for (int m = 0; m < 2; ++m)
        aA[m] = *(const short8*)(&Al[wr * 32 + m * 16 + lr][ks * 32 + lg * 8]);
#pragma unroll
      for (int n = 0; n < 2; ++n)
        bB[n] = *(const short8*)(&Bl[wc * 32 + n * 16 + lr][ks * 32 + lg * 8]);
#pragma unroll
      for (int m = 0; m < 2; ++m)
#pragma unroll
        for (int n = 0; n < 2; ++n)
          acc[m][n] = __builtin_amdgcn_mfma_f32_16x16x32_bf16(aA[m], bB[n], acc[m][n], 0, 0, 0);
    }
  }

#pragma unroll
  for (int m = 0; m < 2; ++m)
#pragma unroll
    for (int n = 0; n < 2; ++n)
#pragma unroll
      for (int r = 0; r < 4; ++r) {
        int row = row0 + wr * 32 + m * 16 + lg * 4 + r;
        int col = col0 + wc * 32 + n * 16 + lr;
        C[(size_t)row * ldc + col] = acc[m][n][r] + (bias ? bias[col] : 0.0f);
      }
}

// ---------------------------------------------------------------------------
// Build augmented Q and K (bf16), rotating points on the fly.
// blockIdx.y: 0 = Q (Ptgt, q_vec/q_cent), 1 = K (Pmem, k_vec/k_cent)
// ---------------------------------------------------------------------------
__global__ __launch_bounds__(256) void build_qkaug_kernel(
    const float* __restrict__ Ptgt, const float* __restrict__ Pmem,
    const float* __restrict__ point_weights,
    const float* __restrict__ qv, const float* __restrict__ qc,
    const float* __restrict__ kv, const float* __restrict__ kc,
    short* __restrict__ Qaug, short* __restrict__ Kaug) {
  int idx = blockIdx.x * 256 + threadIdx.x;
  int d = idx % 96;
  int n = (idx / 96) % N_;
  int h = (idx / (96 * N_)) % H_;
  int b = idx / (96 * N_ * H_);
  int bn = b * N_ + n;
  float pwh = log1pf(expf(point_weights[h]));
  float coef = 0.5f * POINT_SCALE * pwh;
  float val;
  if (blockIdx.y == 0) {
    if (d < 64) {
      val = Ptgt[(size_t)bn * 640 + h * 64 + d];  // pre-scaled by SS
    } else if (d < 76) {
      int e = d - 64, pt = e / 3, c = e % 3;
      const float* P = Ptgt + (size_t)bn * 640 + 512 + h * 12 + pt * 3;
      const float* R = qv + (size_t)bn * 9;
      val = (R[c * 3] * P[0] + R[c * 3 + 1] * P[1] + R[c * 3 + 2] * P[2]
             + qc[(size_t)bn * 3 + c]) * (2.0f * coef);
    } else if (d == 76) val = 1.0f;
    else val = 0.0f;
    Qaug[idx] = f2bf(val);
  } else {
    if (d < 64) {
      val = Pmem[(size_t)bn * 1280 + h * 64 + d];
    } else if (d < 76) {
      int e = d - 64, pt = e / 3, c = e % 3;
      const float* P = Pmem + (size_t)bn * 1280 + 1024 + h * 12 + pt * 3;
      const float* R = kv + (size_t)bn * 9;
      val = R[c * 3] * P[0] + R[c * 3 + 1] * P[1] + R[c * 3 + 2] * P[2]
            + kc[(size_t)bn * 3 + c];
    } else if (d == 76) {
      const float* R = kv + (size_t)bn * 9;
      const float* tv = kc + (size_t)bn * 3;
      float s = 0.0f;
#pragma unroll
      for (int pt = 0; pt < 4; ++pt) {
        const float* P = Pmem + (size_t)bn * 1280 + 1024 + h * 12 + pt * 3;
#pragma unroll
        for (int c = 0; c < 3; ++c) {
          float g = R[c * 3] * P[0] + R[c * 3 + 1] * P[1] + R[c * 3 + 2] * P[2] + tv[c];
          s += g * g;
        }
      }
      val = -coef * s;
    } else val = 0.0f;
    Kaug[idx] = f2bf(val);
  }
}

// ---------------------------------------------------------------------------
// Build transposed augmented V (bf16): Vt[b][h][80][N], rotating vp on the fly.
// ---------------------------------------------------------------------------
__global__ __launch_bounds__(256) void build_vt_kernel(
    const float* __restrict__ Pmem,
    const float* __restrict__ kv, const float* __restrict__ kc,
    short* __restrict__ Vt) {
  const int n0 = blockIdx.x * 64, h = blockIdx.y, b = blockIdx.z;
  const int tid = threadIdx.x;
  __shared__ float buf[64][85];
#pragma unroll
  for (int i = 0; i < 16; ++i) {
    int nl = i * 4 + (tid >> 6), d = tid & 63;
    buf[nl][d] = Pmem[(size_t)(b * N_ + n0 + nl) * 1280 + 512 + h * 64 + d];
  }
  {
    int nl = tid >> 2, pt = tid & 3;
    int bn = b * N_ + n0 + nl;
    const float* P = Pmem + (size_t)bn * 1280 + 1120 + h * 12 + pt * 3;
    const float* R = kv + (size_t)bn * 9;
    const float* tv = kc + (size_t)bn * 3;
#pragma unroll
    for (int c = 0; c < 3; ++c)
      buf[nl][64 + pt * 3 + c] =
          R[c * 3] * P[0] + R[c * 3 + 1] * P[1] + R[c * 3 + 2] * P[2] + tv[c];
    buf[nl][76 + pt] = 0.0f;
  }
  __syncthreads();
#pragma unroll
  for (int i = 0; i < 20; ++i) {
    int d = i * 4 + (tid >> 6), nl = tid & 63;
    Vt[((size_t)(b * H_ + h) * 80 + d) * N_ + n0 + nl] = f2bf(buf[nl][d]);
  }
}

// ---------------------------------------------------------------------------
// Barrier-free split-j flash attention + fused rotate-back epilogue.
// Grid (N/16, H, B) = 1024 blocks, 256 thr = 4 waves.
// Block owns 16 q-rows; wave w owns j in [w*256, w*256+256), 4 tiles of 64.
// K/V fragments read directly from global (L2-resident). One barrier total.
// ---------------------------------------------------------------------------
__global__ __launch_bounds__(256) void flash_attn_kernel(
    const short* __restrict__ Qaug, const short* __restrict__ Kaug,
    const short* __restrict__ Vt,
    const float* __restrict__ qv, const float* __restrict__ qc,
    short* __restrict__ featsB) {
  const int it = blockIdx.x, h = blockIdx.y, b = blockIdx.z;
  const int bh = b * H_ + h;
  const int i0 = it * 16;
  const int tid = threadIdx.x;
  const int wave = tid >> 6, lane = tid & 63;
  const int lg = lane >> 4, lr = lane & 15;

  __shared__ short P_lds[4][16][72];
  __shared__ float Om[4][16][84];
  __shared__ float Mm[4][16], Ml[4][16];
  __shared__ float rpl[16][12];

  // persistent Q fragments (16 rows)
  short8 aQ[3];
  {
    const short* qrow = Qaug + ((size_t)bh * N_ + i0 + lr) * 96;
#pragma unroll
    for (int s = 0; s < 3; ++s)
      aQ[s] = *(const short8*)(qrow + s * 32 + lg * 8);
  }

  f32x4 O[5];
  float m_run[4], l_run[4];
#pragma unroll
  for (int v = 0; v < 5; ++v)
#pragma unroll
    for (int r = 0; r < 4; ++r) O[v][r] = 0.0f;
#pragma unroll
  for (int r = 0; r < 4; ++r) { m_run[r] = -3.0e38f; l_run[r] = 0.0f; }

  for (int t = 0; t < 4; ++t) {
    const int j0 = wave * 256 + t * 64;

    // S = Q @ K^T, fragments straight from global
    f32x4 S[4];
#pragma unroll
    for (int f = 0; f < 4; ++f)
#pragma unroll
      for (int r = 0; r < 4; ++r) S[f][r] = 0.0f;
#pragma unroll
    for (int s = 0; s < 3; ++s) {
#pragma unroll
      for (int f = 0; f < 4; ++f) {
        short8 bK = *(const short8*)(
            Kaug + ((size_t)bh * N_ + j0 + f * 16 + lr) * 96 + s * 32 + lg * 8);
        S[f] = __builtin_amdgcn_mfma_f32_16x16x32_bf16(aQ[s], bK, S[f], 0, 0, 0);
      }
    }

    // online softmax (rows = lg*4 + r)
    float tmax[4];
#pragma unroll
    for (int r = 0; r < 4; ++r)
      tmax[r] = fmaxf(fmaxf(S[0][r], S[1][r]), fmaxf(S[2][r], S[3][r]));
#pragma unroll
    for (int mask = 1; mask < 16; mask <<= 1)
#pragma unroll
      for (int r = 0; r < 4; ++r)
        tmax[r] = fmaxf(tmax[r], __shfl_xor(tmax[r], mask, 16));
    float alpha[4];
#pragma unroll
    for (int r = 0; r < 4; ++r) {
      float mnew = fmaxf(m_run[r], tmax[r]);
      alpha[r] = __expf(m_run[r] - mnew);
      m_run[r] = mnew;
    }
#pragma unroll
    for (int f = 0; f < 4; ++f)
#pragma unroll
      for (int r = 0; r < 4; ++r) S[f][r] = __expf(S[f][r] - m_run[r]);
    float rsum[4];
#pragma unroll
    for (int r = 0; r < 4; ++r) rsum[r] = S[0][r] + S[1][r] + S[2][r] + S[3][r];
#pragma unroll
    for (int mask = 1; mask < 16; mask <<= 1)
#pragma unroll
      for (int r = 0; r < 4; ++r) rsum[r] += __shfl_xor(rsum[r], mask, 16);
#pragma unroll
    for (int r = 0; r < 4; ++r) l_run[r] = l_run[r] * alpha[r] + rsum[r];
#pragma unroll
    for (int v = 0; v < 5; ++v)
#pragma unroll
      for (int r = 0; r < 4; ++r) O[v][r] *= alpha[r];

    // P C-layout -> A-layout via wave-local LDS (in-order DS, no barrier)
#pragma unroll
    for (int f = 0; f < 4; ++f)
#pragma unroll
      for (int r = 0; r < 4; ++r)
        P_lds[wave][lg * 4 + r][f * 16 + lr] = f2bf(S[f][r]);

    // O += P @ V, V fragments straight from global
#pragma unroll
    for (int s2 = 0; s2 < 2; ++s2) {
      short8 aP = *(const short8*)(&P_lds[wave][lr][s2 * 32 + lg * 8]);
#pragma unroll
      for (int v = 0; v < 5; ++v) {
        short8 bV = *(const short8*)(
            Vt + ((size_t)bh * 80 + v * 16 + lr) * N_ + j0 + s2 * 32 + lg * 8);
        O[v] = __builtin_amdgcn_mfma_f32_16x16x32_bf16(aP, bV, O[v], 0, 0, 0);
      }
    }
  }

  // publish per-wave partials
#pragma unroll
  for (int v = 0; v < 5; ++v)
#pragma unroll
    for (int r = 0; r < 4; ++r) Om[wave][lg * 4 + r][v * 16 + lr] = O[v][r];
  if (lr == 0) {
#pragma unroll
    for (int r = 0; r < 4; ++r) {
      Mm[wave][lg * 4 + r] = m_run[r];
      Ml[wave][lg * 4 + r] = l_run[r];
    }
  }
  __syncthreads();

  // merge 4 partials; thread = (row, 5-d chunk)
  {
    const int row = tid >> 4, q16 = tid & 15;
    float mw0 = Mm[0][row], mw1 = Mm[1][row], mw2 = Mm[2][row], mw3 = Mm[3][row];
    float mstar = fmaxf(fmaxf(mw0, mw1), fmaxf(mw2, mw3));
    float e0 = __expf(mw0 - mstar), e1 = __expf(mw1 - mstar),
          e2 = __expf(mw2 - mstar), e3 = __expf(mw3 - mstar);
    float denom = e0 * Ml[0][row] + e1 * Ml[1][row] + e2 * Ml[2][row] + e3 * Ml[3][row];
    float inv = 1.0f / denom;
    const int bn = b * N_ + i0 + row;
#pragma unroll
    for (int k = 0; k < 5; ++k) {
      int d = q16 * 5 + k;
      float val = (e0 * Om[0][row][d] + e1 * Om[1][row][d] +
                   e2 * Om[2][row][d] + e3 * Om[3][row][d]) * inv;
      if (d < 64)
        featsB[(size_t)bn * 640 + h * 64 + d] = f2bf(val);
      else if (d < 76)
        rpl[row][d - 64] = val;
    }
  }
  __syncthreads();

  // fused rotate-back + norm epilogue (64 point-tasks)
  if (tid < 64) {
    const int row = tid >> 2, pt = tid & 3;
    const int bn = b * N_ + i0 + row;
    const float* R = qv + (size_t)bn * 9;
    const float* tv = qc + (size_t)bn * 3;
    float p0 = rpl[row][pt * 3 + 0] - tv[0];
    float p1 = rpl[row][pt * 3 + 1] - tv[1];
    float p2 = rpl[row][pt * 3 + 2] - tv[2];
    float o0 = R[0] * p0 + R[3] * p1 + R[6] * p2;
    float o1 = R[1] * p0 + R[4] * p1 + R[7] * p2;
    float o2 = R[2] * p0 + R[5] * p1 + R[8] * p2;
    float nrm = sqrtf(o0 * o0 + o1 * o1 + o2 * o2 + EPS_);
    short* f = featsB + (size_t)bn * 640;
    f[512 + h * 12 + pt * 3 + 0] = f2bf(o0);
    f[512 + h * 12 + pt * 3 + 1] = f2bf(o1);
    f[512 + h * 12 + pt * 3 + 2] = f2bf(o2);
    f[608 + h * 4 + pt] = f2bf(nrm);
  }
}

// ---------------------------------------------------------------------------
extern "C" void kernel_launch(void* const* d_in, const int* in_sizes, int n_in,
                              void* d_out, int out_size, void* d_ws, size_t ws_size,
                              hipStream_t stream) {
  const float* tgt    = (const float*)d_in[0];
  const float* memory = (const float*)d_in[1];
  const float* q_cent = (const float*)d_in[2];
  const float* q_vec  = (const float*)d_in[3];
  const float* k_cent = (const float*)d_in[4];
  const float* k_vec  = (const float*)d_in[5];
  const float* Wq_s   = (const float*)d_in[6];
  const float* Wk_s   = (const float*)d_in[7];
  const float* Wv_s   = (const float*)d_in[8];
  const float* Wq_p   = (const float*)d_in[9];
  const float* Wk_p   = (const float*)d_in[10];
  const float* Wv_p   = (const float*)d_in[11];
  const float* pw     = (const float*)d_in[12];
  const float* Wo     = (const float*)d_in[13];
  const float* bo     = (const float*)d_in[14];
  float* out = (float*)d_out;

  const int M = B_ * N_;  // 2048

  char* wsb = (char*)d_ws;
  size_t off = 0;
  auto alloc = [&](size_t bytes) { char* p = wsb + off; off += (bytes + 255) & ~(size_t)255; return p; };
  short* Atgt   = (short*)alloc((size_t)M * 512 * 2);
  short* Amem   = (short*)alloc((size_t)M * 512 * 2);
  short* Wt_tgt = (short*)alloc((size_t)640 * 512 * 2);
  short* Wt_mem = (short*)alloc((size_t)1280 * 512 * 2);
  short* Wot    = (short*)alloc((size_t)512 * 640 * 2);
  float* Ptgt   = (float*)alloc((size_t)M * 640 * 4);
  float* Pmem   = (float*)alloc((size_t)M * 1280 * 4);
  short* Qaug   = (short*)alloc((size_t)M * H_ * 96 * 2);
  short* Kaug   = (short*)alloc((size_t)M * H_ * 96 * 2);
  short* Vt     = (short*)alloc((size_t)M * H_ * 80 * 2);
  short* featsB = (short*)alloc((size_t)M * 640 * 2);

  dim3 blk(256);

  // 1. convert inputs + pack weights
  prep_kernel<<<(2 * 131072 + 640 * 64 + 1280 * 64 + 512 * 80) / 256, blk, 0, stream>>>(
      tgt, memory, Wq_s, Wq_p, Wk_s, Wv_s, Wk_p, Wv_p, Wo,
      Atgt, Amem, Wt_tgt, Wt_mem, Wot);
  // 2. fused projections
  gemm64_kernel<<<dim3(640 / 64, M / 64), blk, 0, stream>>>(Atgt, Wt_tgt, nullptr, Ptgt, 512, 640);
  gemm64_kernel<<<dim3(1280 / 64, M / 64), blk, 0, stream>>>(Amem, Wt_mem, nullptr, Pmem, 512, 1280);
  // 3. build augmented Q/K (rotation fused) and V^T (rotation fused)
  build_qkaug_kernel<<<dim3(B_ * H_ * N_ * 96 / 256, 2), blk, 0, stream>>>(
      Ptgt, Pmem, pw, q_vec, q_cent, k_vec, k_cent, Qaug, Kaug);
  build_vt_kernel<<<dim3(N_ / 64, H_, B_), blk, 0, stream>>>(Pmem, k_vec, k_cent, Vt);
  // 4. flash attention (split-j, barrier-free) + fused rotate-back epilogue
  flash_attn_kernel<<<dim3(N_ / 16, H_, B_), blk, 0, stream>>>(
      Qaug, Kaug, Vt, q_vec, q_cent, featsB);
  // 5. output projection
  gemm64_kernel<<<dim3(512 / 64, M / 64), blk, 0, stream>>>(featsB, Wot, bo, out, 640, 512);
}

// Round 5
// 79.052 us; speedup vs baseline: 30.4535x; 1.2983x over previous
//
#include <hip/hip_runtime.h>
#include <math.h>

#define B_   2
#define N_   1024
#define DIM_ 512
#define H_   8
#define DH_  64
#define PD_  4

static constexpr float SCALAR_SCALE = 0.08838834764831845f; // (2*64)^-0.5
static constexpr float POINT_SCALE  = 0.16666666666666666f; // (2*4*4.5)^-0.5
static constexpr float EPS_         = 1e-8f;

typedef __attribute__((ext_vector_type(8))) short short8;
typedef __attribute__((ext_vector_type(4))) short short4_t;
typedef __attribute__((ext_vector_type(4))) float f32x4;

__device__ __forceinline__ short f2bf(float x) {
  union { float f; unsigned u; } c; c.f = x;
  unsigned r = c.u + 0x7FFFu + ((c.u >> 16) & 1u);
  return (short)(r >> 16);
}

// ---------------------------------------------------------------------------
// Prep: convert tgt/memory to bf16 + pack all weights (transposed bf16).
// ---------------------------------------------------------------------------
__global__ __launch_bounds__(256) void prep_kernel(
    const float* __restrict__ tgt, const float* __restrict__ memory,
    const float* __restrict__ Wq_s, const float* __restrict__ Wq_p,
    const float* __restrict__ Wk_s, const float* __restrict__ Wv_s,
    const float* __restrict__ Wk_p, const float* __restrict__ Wv_p,
    const float* __restrict__ Wo,
    short* __restrict__ Atgt, short* __restrict__ Amem,
    short* __restrict__ Wt_tgt, short* __restrict__ Wt_mem,
    short* __restrict__ Wot) {
  const int CONV = 2048 * 512 / 8;  // 131072 per input
  const int SA = 640 * 64, SB = 1280 * 64, SC = 512 * 80;
  int idx = blockIdx.x * 256 + threadIdx.x;
  if (idx < 2 * CONV) {
    const float* src = (idx < CONV) ? tgt : memory;
    short* dst = (idx < CONV) ? Atgt : Amem;
    int o = (idx < CONV) ? idx : idx - CONV;
    float4 lo = ((const float4*)src)[o * 2];
    float4 hi = ((const float4*)src)[o * 2 + 1];
    short8 v;
    v[0] = f2bf(lo.x); v[1] = f2bf(lo.y); v[2] = f2bf(lo.z); v[3] = f2bf(lo.w);
    v[4] = f2bf(hi.x); v[5] = f2bf(hi.y); v[6] = f2bf(hi.z); v[7] = f2bf(hi.w);
    ((short8*)dst)[o] = v;
    return;
  }
  idx -= 2 * CONV;
  float v[8];
  if (idx < SA) {
    int n = idx / 64, k0 = (idx % 64) * 8;
#pragma unroll
    for (int e = 0; e < 8; ++e) {
      int k = k0 + e;
      if (n < 512)      v[e] = Wq_s[(size_t)k * 512 + n] * SCALAR_SCALE;
      else if (n < 608) v[e] = Wq_p[(size_t)k * 96 + (n - 512)];
      else              v[e] = 0.0f;
    }
    short8 o;
#pragma unroll
    for (int e = 0; e < 8; ++e) o[e] = f2bf(v[e]);
    *(short8*)(Wt_tgt + (size_t)n * 512 + k0) = o;
  } else if (idx < SA + SB) {
    int j = idx - SA;
    int n = j / 64, k0 = (j % 64) * 8;
#pragma unroll
    for (int e = 0; e < 8; ++e) {
      int k = k0 + e;
      if (n < 512)       v[e] = Wk_s[(size_t)k * 512 + n];
      else if (n < 1024) v[e] = Wv_s[(size_t)k * 512 + (n - 512)];
      else if (n < 1120) v[e] = Wk_p[(size_t)k * 96 + (n - 1024)];
      else if (n < 1216) v[e] = Wv_p[(size_t)k * 96 + (n - 1120)];
      else               v[e] = 0.0f;
    }
    short8 o;
#pragma unroll
    for (int e = 0; e < 8; ++e) o[e] = f2bf(v[e]);
    *(short8*)(Wt_mem + (size_t)n * 512 + k0) = o;
  } else if (idx < SA + SB + SC) {
    int j = idx - SA - SB;
    int n = j / 80, k0 = (j % 80) * 8;
#pragma unroll
    for (int e = 0; e < 8; ++e) v[e] = Wo[(size_t)(k0 + e) * 512 + n];
    short8 o;
#pragma unroll
    for (int e = 0; e < 8; ++e) o[e] = f2bf(v[e]);
    *(short8*)(Wot + (size_t)n * 640 + k0) = o;
  }
}

// ---------------------------------------------------------------------------
// bf16 MFMA GEMM (single job): C[M][ldc] fp32 = A[M][K] @ Bt[Npad][K]^T (+bias)
// ---------------------------------------------------------------------------
__device__ __forceinline__ void gemm64_body(
    const short* __restrict__ A, const short* __restrict__ Bt,
    const float* __restrict__ bias, float* __restrict__ C,
    int K, int ldc, int row0, int col0) {
  const int tid = threadIdx.x, wave = tid >> 6, lane = tid & 63;
  const int wr = wave >> 1, wc = wave & 1;
  const int lg = lane >> 4, lr = lane & 15;
  const int l8 = lane >> 3, l7 = lane & 7;

  __shared__ short Al[64][72];
  __shared__ short Bl[64][72];

  f32x4 acc[2][2];
#pragma unroll
  for (int m = 0; m < 2; ++m)
#pragma unroll
    for (int n = 0; n < 2; ++n)
#pragma unroll
      for (int r = 0; r < 4; ++r) acc[m][n][r] = 0.0f;

  for (int kt = 0; kt < K; kt += 64) {
    short8 areg[2], breg[2];
#pragma unroll
    for (int i = 0; i < 2; ++i) {
      int r = wave * 16 + i * 8 + l8;
      areg[i] = *(const short8*)(A + (size_t)(row0 + r) * K + kt + l7 * 8);
      breg[i] = *(const short8*)(Bt + (size_t)(col0 + r) * K + kt + l7 * 8);
    }
    __syncthreads();
#pragma unroll
    for (int i = 0; i < 2; ++i) {
      int r = wave * 16 + i * 8 + l8;
      *(short8*)(&Al[r][l7 * 8]) = areg[i];
      *(short8*)(&Bl[r][l7 * 8]) = breg[i];
    }
    __syncthreads();
#pragma unroll
    for (int ks = 0; ks < 2; ++ks) {
      short8 aA[2], bB[2];
#pragma unroll
      for (int m = 0; m < 2; ++m)
        aA[m] = *(const short8*)(&Al[wr * 32 + m * 16 + lr][ks * 32 + lg * 8]);
#pragma unroll
      for (int n = 0; n < 2; ++n)
        bB[n] = *(const short8*)(&Bl[wc * 32 + n * 16 + lr][ks * 32 + lg * 8]);
#pragma unroll
      for (int m = 0; m < 2; ++m)
#pragma unroll
        for (int n = 0; n < 2; ++n)
          acc[m][n] = __builtin_amdgcn_mfma_f32_16x16x32_bf16(aA[m], bB[n], acc[m][n], 0, 0, 0);
    }
  }

#pragma unroll
  for (int m = 0; m < 2; ++m)
#pragma unroll
    for (int n = 0; n < 2; ++n)
#pragma unroll
      for (int r = 0; r < 4; ++r) {
        int row = row0 + wr * 32 + m * 16 + lg * 4 + r;
        int col = col0 + wc * 32 + n * 16 + lr;
        C[(size_t)row * ldc + col] = acc[m][n][r] + (bias ? bias[col] : 0.0f);
      }
}

__global__ __launch_bounds__(256) void gemm64_kernel(
    const short* __restrict__ A, const short* __restrict__ Bt,
    const float* __restrict__ bias, float* __restrict__ C, int K, int ldc) {
  gemm64_body(A, Bt, bias, C, K, ldc, blockIdx.y * 64, blockIdx.x * 64);
}

// Both projection GEMMs in one dispatch: x<10 -> tgt job (ldc 640), else mem job.
__global__ __launch_bounds__(256) void gemm64_dual_kernel(
    const short* __restrict__ Atgt, const short* __restrict__ Wt_tgt,
    const short* __restrict__ Amem, const short* __restrict__ Wt_mem,
    float* __restrict__ Ptgt, float* __restrict__ Pmem) {
  if (blockIdx.x < 10)
    gemm64_body(Atgt, Wt_tgt, nullptr, Ptgt, 512, 640, blockIdx.y * 64, blockIdx.x * 64);
  else
    gemm64_body(Amem, Wt_mem, nullptr, Pmem, 512, 1280, blockIdx.y * 64, (blockIdx.x - 10) * 64);
}

// ---------------------------------------------------------------------------
// Build augmented Q/K in FRAGMENT-NATIVE layout (rotation fused):
//   frag buffer: [bh][J:64][s:3][lane:64] x short8;  element (j,k):
//   J=j>>4, lr=j&15, s=k>>5, lg=(k>>3)&3, e=k&7, lane=lg*16+lr.
// One thread = one short8 (8 consecutive k for one n). grid (768, 2).
// ---------------------------------------------------------------------------
__global__ __launch_bounds__(256) void build_qkaug_kernel(
    const float* __restrict__ Ptgt, const float* __restrict__ Pmem,
    const float* __restrict__ point_weights,
    const float* __restrict__ qv, const float* __restrict__ qc,
    const float* __restrict__ kv, const float* __restrict__ kc,
    short8* __restrict__ Qf, short8* __restrict__ Kf) {
  int idx = blockIdx.x * 256 + threadIdx.x;
  int n = idx & 1023;
  int rest = idx >> 10;
  int k8 = rest % 12;
  int bh = rest / 12;
  int b = bh >> 3, h = bh & 7;
  int bn = b * N_ + n;
  int k0 = k8 * 8;
  float pwh = log1pf(expf(point_weights[h]));
  float coef = 0.5f * POINT_SCALE * pwh;
  float vals[8];
  if (blockIdx.y == 0) {
    const float* R = qv + (size_t)bn * 9;
    const float* tv = qc + (size_t)bn * 3;
#pragma unroll
    for (int e = 0; e < 8; ++e) {
      int d = k0 + e;
      float val;
      if (d < 64) {
        val = Ptgt[(size_t)bn * 640 + h * 64 + d];  // pre-scaled by SS
      } else if (d < 76) {
        int pd = d - 64, pt = pd / 3, c = pd % 3;
        const float* P = Ptgt + (size_t)bn * 640 + 512 + h * 12 + pt * 3;
        val = (R[c * 3] * P[0] + R[c * 3 + 1] * P[1] + R[c * 3 + 2] * P[2] + tv[c])
              * (2.0f * coef);
      } else if (d == 76) val = 1.0f;
      else val = 0.0f;
      vals[e] = val;
    }
  } else {
    const float* R = kv + (size_t)bn * 9;
    const float* tv = kc + (size_t)bn * 3;
#pragma unroll
    for (int e = 0; e < 8; ++e) {
      int d = k0 + e;
      float val;
      if (d < 64) {
        val = Pmem[(size_t)bn * 1280 + h * 64 + d];
      } else if (d < 76) {
        int pd = d - 64, pt = pd / 3, c = pd % 3;
        const float* P = Pmem + (size_t)bn * 1280 + 1024 + h * 12 + pt * 3;
        val = R[c * 3] * P[0] + R[c * 3 + 1] * P[1] + R[c * 3 + 2] * P[2] + tv[c];
      } else if (d == 76) {
        float s = 0.0f;
#pragma unroll
        for (int pt = 0; pt < 4; ++pt) {
          const float* P = Pmem + (size_t)bn * 1280 + 1024 + h * 12 + pt * 3;
#pragma unroll
          for (int c = 0; c < 3; ++c) {
            float g = R[c * 3] * P[0] + R[c * 3 + 1] * P[1] + R[c * 3 + 2] * P[2] + tv[c];
            s += g * g;
          }
        }
        val = -coef * s;
      } else val = 0.0f;
      vals[e] = val;
    }
  }
  short8 o;
#pragma unroll
  for (int e = 0; e < 8; ++e) o[e] = f2bf(vals[e]);
  int J = n >> 4, lr = n & 15, s = k8 >> 2, lg = k8 & 3;
  size_t fi = ((size_t)(bh * 64 + J) * 3 + s) * 64 + lg * 16 + lr;
  if (blockIdx.y == 0) Qf[fi] = o;
  else                 Kf[fi] = o;
}

// ---------------------------------------------------------------------------
// Build V in FRAGMENT-NATIVE layout (rotation fused):
//   frag buffer: [bh][t2:32][v:5][lane:64] x short8; element (d,j):
//   t2=j>>5, v=d>>4, lr=d&15, lg=(j>>3)&3, e=j&7, lane=lg*16+lr.
// Block = (64 j's, h, b); LDS-transposed gather.
// ---------------------------------------------------------------------------
__global__ __launch_bounds__(256) void build_vt_kernel(
    const float* __restrict__ Pmem,
    const float* __restrict__ kv, const float* __restrict__ kc,
    short8* __restrict__ Vf) {
  const int n0 = blockIdx.x * 64, h = blockIdx.y, b = blockIdx.z;
  const int bh = b * H_ + h;
  const int tid = threadIdx.x;
  __shared__ float buf[64][85];
#pragma unroll
  for (int i = 0; i < 16; ++i) {
    int nl = i * 4 + (tid >> 6), d = tid & 63;
    buf[nl][d] = Pmem[(size_t)(b * N_ + n0 + nl) * 1280 + 512 + h * 64 + d];
  }
  {
    int nl = tid >> 2, pt = tid & 3;
    int bn = b * N_ + n0 + nl;
    const float* P = Pmem + (size_t)bn * 1280 + 1120 + h * 12 + pt * 3;
    const float* R = kv + (size_t)bn * 9;
    const float* tv = kc + (size_t)bn * 3;
#pragma unroll
    for (int c = 0; c < 3; ++c)
      buf[nl][64 + pt * 3 + c] =
          R[c * 3] * P[0] + R[c * 3 + 1] * P[1] + R[c * 3 + 2] * P[2] + tv[c];
    buf[nl][76 + pt] = 0.0f;
  }
  __syncthreads();
  // 640 tasks: (t2l:2) x (v:5) x (lane:64); short8 per task, coalesced store.
  for (int task = tid; task < 640; task += 256) {
    int l6 = task & 63;
    int v = (task >> 6) % 5;
    int t2l = task / 320;
    int lr = l6 & 15, lg = l6 >> 4;
    int d = v * 16 + lr;
    short8 o;
#pragma unroll
    for (int e = 0; e < 8; ++e) o[e] = f2bf(buf[t2l * 32 + lg * 8 + e][d]);
    int t2 = (n0 >> 5) + t2l;
    Vf[((size_t)(bh * 32 + t2) * 5 + v) * 64 + l6] = o;
  }
}

// ---------------------------------------------------------------------------
// Split-j flash attention, fragment-native coalesced loads, swapped QK^T.
// 1D grid 1024 blocks (XCD-swizzled: all 64 i-tiles of a bh on one XCD),
// 256 thr = 4 waves; wave w owns j in [w*256, w*256+256), 2 passes of 128.
// S^T = mfma(K, Q): lane holds S^T[j][i=lr] -> row-local softmax, 2 shfls.
// PV as O^T = mfma(V^T, P^T). One barrier; fused merge + rotate-back.
// ---------------------------------------------------------------------------
__global__ __launch_bounds__(256) void flash_attn_kernel(
    const short8* __restrict__ Qf, const short8* __restrict__ Kf,
    const short8* __restrict__ Vf,
    const float* __restrict__ qv, const float* __restrict__ qc,
    short* __restrict__ featsB) {
  // XCD-aware remap: xcd = flat&7 gets bh pair {xcd*2, xcd*2+1}
  const int flat = blockIdx.x;
  const int local = flat >> 3;
  const int bh = (flat & 7) * 2 + (local >> 6);
  const int it = local & 63;
  const int b = bh >> 3, h = bh & 7;
  const int i0 = it * 16;
  const int tid = threadIdx.x;
  const int wave = tid >> 6, lane = tid & 63;
  const int lg = lane >> 4, lr = lane & 15;

  __shared__ __align__(16) char wblob[4][5376];  // P_l [16][136]s / Om [16][84]f
  __shared__ float Mm[4][16], Ml[4][16];
  __shared__ float rpl[16][12];
  short* P_l = (short*)wblob[wave];

  // persistent Q fragments (B-operand)
  short8 aQ[3];
#pragma unroll
  for (int s = 0; s < 3; ++s)
    aQ[s] = Qf[((size_t)(bh * 64 + it) * 3 + s) * 64 + lane];

  f32x4 O[5];
#pragma unroll
  for (int v = 0; v < 5; ++v)
#pragma unroll
    for (int r = 0; r < 4; ++r) O[v][r] = 0.0f;
  float m_run = -3.0e38f, l_run = 0.0f;

  for (int t = 0; t < 2; ++t) {
    const int J0 = wave * 16 + t * 8;  // 16-j block base

    // S^T = K @ Q^T : 8 j-frags x 3 k-steps, coalesced 1KB loads
    f32x4 S[8];
#pragma unroll
    for (int f = 0; f < 8; ++f)
#pragma unroll
      for (int r = 0; r < 4; ++r) S[f][r] = 0.0f;
#pragma unroll
    for (int s = 0; s < 3; ++s) {
      short8 aK[8];
#pragma unroll
      for (int f = 0; f < 8; ++f)
        aK[f] = Kf[((size_t)(bh * 64 + J0 + f) * 3 + s) * 64 + lane];
#pragma unroll
      for (int f = 0; f < 8; ++f)
        S[f] = __builtin_amdgcn_mfma_f32_16x16x32_bf16(aK[f], aQ[s], S[f], 0, 0, 0);
    }

    // online softmax for column i=lr (register-local over 32 j's + 2 shfls)
    float tm = S[0][0];
#pragma unroll
    for (int f = 0; f < 8; ++f)
#pragma unroll
      for (int r = 0; r < 4; ++r) tm = fmaxf(tm, S[f][r]);
    tm = fmaxf(tm, __shfl_xor(tm, 16));
    tm = fmaxf(tm, __shfl_xor(tm, 32));
    float mnew = fmaxf(m_run, tm);
    float alpha = __expf(m_run - mnew);
    m_run = mnew;
    float rs = 0.0f;
#pragma unroll
    for (int f = 0; f < 8; ++f)
#pragma unroll
      for (int r = 0; r < 4; ++r) {
        S[f][r] = __expf(S[f][r] - mnew);
        rs += S[f][r];
      }
    rs += __shfl_xor(rs, 16);
    rs += __shfl_xor(rs, 32);
    l_run = l_run * alpha + rs;
#pragma unroll
    for (int v = 0; v < 5; ++v)
#pragma unroll
      for (int r = 0; r < 4; ++r) O[v][r] *= alpha;

    // P^T -> LDS: packed b64 writes (4 consecutive j per frag)
#pragma unroll
    for (int f = 0; f < 8; ++f) {
      short4_t pk;
#pragma unroll
      for (int r = 0; r < 4; ++r) pk[r] = f2bf(S[f][r]);
      *(short4_t*)&P_l[lr * 136 + f * 16 + lg * 4] = pk;
    }

    // O^T += V^T @ P^T : 4 k-steps of 32 j, 5 d-frags, coalesced V loads
#pragma unroll
    for (int s2 = 0; s2 < 4; ++s2) {
      const int t2 = wave * 8 + t * 4 + s2;
      short8 bP = *(const short8*)&P_l[lr * 136 + s2 * 32 + lg * 8];
      short8 aV[5];
#pragma unroll
      for (int v = 0; v < 5; ++v)
        aV[v] = Vf[((size_t)(bh * 32 + t2) * 5 + v) * 64 + lane];
#pragma unroll
      for (int v = 0; v < 5; ++v)
        O[v] = __builtin_amdgcn_mfma_f32_16x16x32_bf16(aV[v], bP, O[v], 0, 0, 0);
    }
  }

  // publish per-wave partials (Om aliases P_l -- safe after last bP read)
  float* Om_w = (float*)wblob[wave];  // [16][84]
#pragma unroll
  for (int v = 0; v < 5; ++v)
#pragma unroll
    for (int r = 0; r < 4; ++r)
      Om_w[lr * 84 + v * 16 + lg * 4 + r] = O[v][r];
  if (lg == 0) { Mm[wave][lr] = m_run; Ml[wave][lr] = l_run; }
  __syncthreads();

  // merge 4 partials; thread = (row, 5-d chunk)
  {
    const int row = tid >> 4, q16 = tid & 15;
    float mw0 = Mm[0][row], mw1 = Mm[1][row], mw2 = Mm[2][row], mw3 = Mm[3][row];
    float mstar = fmaxf(fmaxf(mw0, mw1), fmaxf(mw2, mw3));
    float e0 = __expf(mw0 - mstar), e1 = __expf(mw1 - mstar),
          e2 = __expf(mw2 - mstar), e3 = __expf(mw3 - mstar);
    float denom = e0 * Ml[0][row] + e1 * Ml[1][row] + e2 * Ml[2][row] + e3 * Ml[3][row];
    float inv = 1.0f / denom;
    const int bn = b * N_ + i0 + row;
    const float* O0 = (const float*)wblob[0];
    const float* O1 = (const float*)wblob[1];
    const float* O2 = (const float*)wblob[2];
    const float* O3 = (const float*)wblob[3];
#pragma unroll
    for (int k = 0; k < 5; ++k) {
      int d = q16 * 5 + k;
      float val = (e0 * O0[row * 84 + d] + e1 * O1[row * 84 + d] +
                   e2 * O2[row * 84 + d] + e3 * O3[row * 84 + d]) * inv;
      if (d < 64)
        featsB[(size_t)bn * 640 + h * 64 + d] = f2bf(val);
      else if (d < 76)
        rpl[row][d - 64] = val;
    }
  }
  __syncthreads();

  // fused rotate-back + norm epilogue
  if (tid < 64) {
    const int row = tid >> 2, pt = tid & 3;
    const int bn = b * N_ + i0 + row;
    const float* R = qv + (size_t)bn * 9;
    const float* tv = qc + (size_t)bn * 3;
    float p0 = rpl[row][pt * 3 + 0] - tv[0];
    float p1 = rpl[row][pt * 3 + 1] - tv[1];
    float p2 = rpl[row][pt * 3 + 2] - tv[2];
    float o0 = R[0] * p0 + R[3] * p1 + R[6] * p2;
    float o1 = R[1] * p0 + R[4] * p1 + R[7] * p2;
    float o2 = R[2] * p0 + R[5] * p1 + R[8] * p2;
    float nrm = sqrtf(o0 * o0 + o1 * o1 + o2 * o2 + EPS_);
    short* f = featsB + (size_t)bn * 640;
    f[512 + h * 12 + pt * 3 + 0] = f2bf(o0);
    f[512 + h * 12 + pt * 3 + 1] = f2bf(o1);
    f[512 + h * 12 + pt * 3 + 2] = f2bf(o2);
    f[608 + h * 4 + pt] = f2bf(nrm);
  }
}

// ---------------------------------------------------------------------------
extern "C" void kernel_launch(void* const* d_in, const int* in_sizes, int n_in,
                              void* d_out, int out_size, void* d_ws, size_t ws_size,
                              hipStream_t stream) {
  const float* tgt    = (const float*)d_in[0];
  const float* memory = (const float*)d_in[1];
  const float* q_cent = (const float*)d_in[2];
  const float* q_vec  = (const float*)d_in[3];
  const float* k_cent = (const float*)d_in[4];
  const float* k_vec  = (const float*)d_in[5];
  const float* Wq_s   = (const float*)d_in[6];
  const float* Wk_s   = (const float*)d_in[7];
  const float* Wv_s   = (const float*)d_in[8];
  const float* Wq_p   = (const float*)d_in[9];
  const float* Wk_p   = (const float*)d_in[10];
  const float* Wv_p   = (const float*)d_in[11];
  const float* pw     = (const float*)d_in[12];
  const float* Wo     = (const float*)d_in[13];
  const float* bo     = (const float*)d_in[14];
  float* out = (float*)d_out;

  const int M = B_ * N_;  // 2048

  char* wsb = (char*)d_ws;
  size_t off = 0;
  auto alloc = [&](size_t bytes) { char* p = wsb + off; off += (bytes + 255) & ~(size_t)255; return p; };
  short* Atgt   = (short*)alloc((size_t)M * 512 * 2);
  short* Amem   = (short*)alloc((size_t)M * 512 * 2);
  short* Wt_tgt = (short*)alloc((size_t)640 * 512 * 2);
  short* Wt_mem = (short*)alloc((size_t)1280 * 512 * 2);
  short* Wot    = (short*)alloc((size_t)512 * 640 * 2);
  float* Ptgt   = (float*)alloc((size_t)M * 640 * 4);
  float* Pmem   = (float*)alloc((size_t)M * 1280 * 4);
  short8* Qf    = (short8*)alloc((size_t)16 * 64 * 3 * 64 * 16);
  short8* Kf    = (short8*)alloc((size_t)16 * 64 * 3 * 64 * 16);
  short8* Vf    = (short8*)alloc((size_t)16 * 32 * 5 * 64 * 16);
  short* featsB = (short*)alloc((size_t)M * 640 * 2);

  dim3 blk(256);

  // 1. convert inputs + pack weights
  prep_kernel<<<(2 * 131072 + 640 * 64 + 1280 * 64 + 512 * 80) / 256, blk, 0, stream>>>(
      tgt, memory, Wq_s, Wq_p, Wk_s, Wv_s, Wk_p, Wv_p, Wo,
      Atgt, Amem, Wt_tgt, Wt_mem, Wot);
  // 2. fused projections (both in one dispatch)
  gemm64_dual_kernel<<<dim3(30, M / 64), blk, 0, stream>>>(
      Atgt, Wt_tgt, Amem, Wt_mem, Ptgt, Pmem);
  // 3. build fragment-native augmented Q/K and V (rotation fused)
  build_qkaug_kernel<<<dim3(768, 2), blk, 0, stream>>>(
      Ptgt, Pmem, pw, q_vec, q_cent, k_vec, k_cent, Qf, Kf);
  build_vt_kernel<<<dim3(N_ / 64, H_, B_), blk, 0, stream>>>(Pmem, k_vec, k_cent, Vf);
  // 4. flash attention (split-j, coalesced frags) + fused rotate-back epilogue
  flash_attn_kernel<<<1024, blk, 0, stream>>>(Qf, Kf, Vf, q_vec, q_cent, featsB);
  // 5. output projection
  gemm64_kernel<<<dim3(512 / 64, M / 64), blk, 0, stream>>>(featsB, Wot, bo, out, 640, 512);
}

// Round 6
// 67.331 us; speedup vs baseline: 35.7544x; 1.1741x over previous
//
#include <hip/hip_runtime.h>
#include <math.h>

#define B_   2
#define N_   1024
#define DIM_ 512
#define H_   8
#define DH_  64
#define PD_  4

static constexpr float SCALAR_SCALE = 0.08838834764831845f; // (2*64)^-0.5
static constexpr float POINT_SCALE  = 0.16666666666666666f; // (2*4*4.5)^-0.5
static constexpr float EPS_         = 1e-8f;

typedef __attribute__((ext_vector_type(8))) short short8;
typedef __attribute__((ext_vector_type(4))) short short4_t;
typedef __attribute__((ext_vector_type(4))) float f32x4;

__device__ __forceinline__ short f2bf(float x) {
  union { float f; unsigned u; } c; c.f = x;
  unsigned r = c.u + 0x7FFFu + ((c.u >> 16) & 1u);
  return (short)(r >> 16);
}

// ---------------------------------------------------------------------------
// Prep: convert tgt/memory to bf16 + pack all weights (transposed bf16).
// ---------------------------------------------------------------------------
__global__ __launch_bounds__(256) void prep_kernel(
    const float* __restrict__ tgt, const float* __restrict__ memory,
    const float* __restrict__ Wq_s, const float* __restrict__ Wq_p,
    const float* __restrict__ Wk_s, const float* __restrict__ Wv_s,
    const float* __restrict__ Wk_p, const float* __restrict__ Wv_p,
    const float* __restrict__ Wo,
    short* __restrict__ Atgt, short* __restrict__ Amem,
    short* __restrict__ Wt_tgt, short* __restrict__ Wt_mem,
    short* __restrict__ Wot) {
  const int CONV = 2048 * 512 / 8;  // 131072 per input
  const int SA = 640 * 64, SB = 1280 * 64, SC = 512 * 80;
  int idx = blockIdx.x * 256 + threadIdx.x;
  if (idx < 2 * CONV) {
    const float* src = (idx < CONV) ? tgt : memory;
    short* dst = (idx < CONV) ? Atgt : Amem;
    int o = (idx < CONV) ? idx : idx - CONV;
    float4 lo = ((const float4*)src)[o * 2];
    float4 hi = ((const float4*)src)[o * 2 + 1];
    short8 v;
    v[0] = f2bf(lo.x); v[1] = f2bf(lo.y); v[2] = f2bf(lo.z); v[3] = f2bf(lo.w);
    v[4] = f2bf(hi.x); v[5] = f2bf(hi.y); v[6] = f2bf(hi.z); v[7] = f2bf(hi.w);
    ((short8*)dst)[o] = v;
    return;
  }
  idx -= 2 * CONV;
  float v[8];
  if (idx < SA) {
    int n = idx / 64, k0 = (idx % 64) * 8;
#pragma unroll
    for (int e = 0; e < 8; ++e) {
      int k = k0 + e;
      if (n < 512)      v[e] = Wq_s[(size_t)k * 512 + n] * SCALAR_SCALE;
      else if (n < 608) v[e] = Wq_p[(size_t)k * 96 + (n - 512)];
      else              v[e] = 0.0f;
    }
    short8 o;
#pragma unroll
    for (int e = 0; e < 8; ++e) o[e] = f2bf(v[e]);
    *(short8*)(Wt_tgt + (size_t)n * 512 + k0) = o;
  } else if (idx < SA + SB) {
    int j = idx - SA;
    int n = j / 64, k0 = (j % 64) * 8;
#pragma unroll
    for (int e = 0; e < 8; ++e) {
      int k = k0 + e;
      if (n < 512)       v[e] = Wk_s[(size_t)k * 512 + n];
      else if (n < 1024) v[e] = Wv_s[(size_t)k * 512 + (n - 512)];
      else if (n < 1120) v[e] = Wk_p[(size_t)k * 96 + (n - 1024)];
      else if (n < 1216) v[e] = Wv_p[(size_t)k * 96 + (n - 1120)];
      else               v[e] = 0.0f;
    }
    short8 o;
#pragma unroll
    for (int e = 0; e < 8; ++e) o[e] = f2bf(v[e]);
    *(short8*)(Wt_mem + (size_t)n * 512 + k0) = o;
  } else if (idx < SA + SB + SC) {
    int j = idx - SA - SB;
    int n = j / 80, k0 = (j % 80) * 8;
#pragma unroll
    for (int e = 0; e < 8; ++e) v[e] = Wo[(size_t)(k0 + e) * 512 + n];
    short8 o;
#pragma unroll
    for (int e = 0; e < 8; ++e) o[e] = f2bf(v[e]);
    *(short8*)(Wot + (size_t)n * 640 + k0) = o;
  }
}

// ---------------------------------------------------------------------------
// bf16 MFMA GEMM body (64x64 tile): C[.][ldc] fp32 = A[.][K] @ Bt[.][K]^T
// ---------------------------------------------------------------------------
__device__ __forceinline__ void gemm64_body(
    const short* __restrict__ A, const short* __restrict__ Bt,
    float* __restrict__ C, int K, int ldc, int row0, int col0) {
  const int tid = threadIdx.x, wave = tid >> 6, lane = tid & 63;
  const int wr = wave >> 1, wc = wave & 1;
  const int lg = lane >> 4, lr = lane & 15;
  const int l8 = lane >> 3, l7 = lane & 7;

  __shared__ short Al[64][72];
  __shared__ short Bl[64][72];

  f32x4 acc[2][2];
#pragma unroll
  for (int m = 0; m < 2; ++m)
#pragma unroll
    for (int n = 0; n < 2; ++n)
#pragma unroll
      for (int r = 0; r < 4; ++r) acc[m][n][r] = 0.0f;

  for (int kt = 0; kt < K; kt += 64) {
    short8 areg[2], breg[2];
#pragma unroll
    for (int i = 0; i < 2; ++i) {
      int r = wave * 16 + i * 8 + l8;
      areg[i] = *(const short8*)(A + (size_t)(row0 + r) * K + kt + l7 * 8);
      breg[i] = *(const short8*)(Bt + (size_t)(col0 + r) * K + kt + l7 * 8);
    }
    __syncthreads();
#pragma unroll
    for (int i = 0; i < 2; ++i) {
      int r = wave * 16 + i * 8 + l8;
      *(short8*)(&Al[r][l7 * 8]) = areg[i];
      *(short8*)(&Bl[r][l7 * 8]) = breg[i];
    }
    __syncthreads();
#pragma unroll
    for (int ks = 0; ks < 2; ++ks) {
      short8 aA[2], bB[2];
#pragma unroll
      for (int m = 0; m < 2; ++m)
        aA[m] = *(const short8*)(&Al[wr * 32 + m * 16 + lr][ks * 32 + lg * 8]);
#pragma unroll
      for (int n = 0; n < 2; ++n)
        bB[n] = *(const short8*)(&Bl[wc * 32 + n * 16 + lr][ks * 32 + lg * 8]);
#pragma unroll
      for (int m = 0; m < 2; ++m)
#pragma unroll
        for (int n = 0; n < 2; ++n)
          acc[m][n] = __builtin_amdgcn_mfma_f32_16x16x32_bf16(aA[m], bB[n], acc[m][n], 0, 0, 0);
    }
  }

#pragma unroll
  for (int m = 0; m < 2; ++m)
#pragma unroll
    for (int n = 0; n < 2; ++n)
#pragma unroll
      for (int r = 0; r < 4; ++r) {
        int row = row0 + wr * 32 + m * 16 + lg * 4 + r;
        int col = col0 + wc * 32 + n * 16 + lr;
        C[(size_t)row * ldc + col] = acc[m][n][r];
      }
}

// Both projection GEMMs in one dispatch: x<10 -> tgt (ldc 640), else mem (19 tiles).
__global__ __launch_bounds__(256) void gemm64_dual_kernel(
    const short* __restrict__ Atgt, const short* __restrict__ Wt_tgt,
    const short* __restrict__ Amem, const short* __restrict__ Wt_mem,
    float* __restrict__ Ptgt, float* __restrict__ Pmem) {
  if (blockIdx.x < 10)
    gemm64_body(Atgt, Wt_tgt, Ptgt, 512, 640, blockIdx.y * 64, blockIdx.x * 64);
  else
    gemm64_body(Amem, Wt_mem, Pmem, 512, 1280, blockIdx.y * 64, (blockIdx.x - 10) * 64);
}

// ---------------------------------------------------------------------------
// Output GEMM, 64x32 tiles (grid 16x32 = 512 blocks, 2/CU):
//   out[2048][512] = featsB[2048][640] @ Wot[512][640]^T + bo
// ---------------------------------------------------------------------------
__global__ __launch_bounds__(256) void gemm_out_kernel(
    const short* __restrict__ A, const short* __restrict__ Bt,
    const float* __restrict__ bias, float* __restrict__ C) {
  const int row0 = blockIdx.y * 64, col0 = blockIdx.x * 32;
  const int tid = threadIdx.x, wave = tid >> 6, lane = tid & 63;
  const int wr = wave >> 1, wc = wave & 1;
  const int lg = lane >> 4, lr = lane & 15;
  const int l8 = lane >> 3, l7 = lane & 7;

  __shared__ short Al[64][72];
  __shared__ short Bl[32][72];

  f32x4 acc[2];
#pragma unroll
  for (int m = 0; m < 2; ++m)
#pragma unroll
    for (int r = 0; r < 4; ++r) acc[m][r] = 0.0f;

  for (int kt = 0; kt < 640; kt += 64) {
    short8 areg[2], breg;
#pragma unroll
    for (int i = 0; i < 2; ++i) {
      int r = wave * 16 + i * 8 + l8;
      areg[i] = *(const short8*)(A + (size_t)(row0 + r) * 640 + kt + l7 * 8);
    }
    {
      int r = wave * 8 + l8;
      breg = *(const short8*)(Bt + (size_t)(col0 + r) * 640 + kt + l7 * 8);
    }
    __syncthreads();
#pragma unroll
    for (int i = 0; i < 2; ++i) {
      int r = wave * 16 + i * 8 + l8;
      *(short8*)(&Al[r][l7 * 8]) = areg[i];
    }
    { int r = wave * 8 + l8; *(short8*)(&Bl[r][l7 * 8]) = breg; }
    __syncthreads();
#pragma unroll
    for (int ks = 0; ks < 2; ++ks) {
      short8 aA[2], bB;
#pragma unroll
      for (int m = 0; m < 2; ++m)
        aA[m] = *(const short8*)(&Al[wr * 32 + m * 16 + lr][ks * 32 + lg * 8]);
      bB = *(const short8*)(&Bl[wc * 16 + lr][ks * 32 + lg * 8]);
#pragma unroll
      for (int m = 0; m < 2; ++m)
        acc[m] = __builtin_amdgcn_mfma_f32_16x16x32_bf16(aA[m], bB, acc[m], 0, 0, 0);
    }
  }

#pragma unroll
  for (int m = 0; m < 2; ++m)
#pragma unroll
    for (int r = 0; r < 4; ++r) {
      int row = row0 + wr * 32 + m * 16 + lg * 4 + r;
      int col = col0 + wc * 16 + lr;
      C[(size_t)row * 512 + col] = acc[m][r] + bias[col];
    }
}

// ---------------------------------------------------------------------------
// Merged build kernel. Grid 1792:
//   [0,768)    : Qf job (fragment-native augmented Q, rotation fused)
//   [768,1536) : Kf job
//   [1536,1792): Vf job (LDS transpose, rotation fused)
// Fragment layouts (unchanged from R4):
//   Qf/Kf: [bh][J:64][s:3][lane:64] short8 ; lane=lg*16+lr, lr=n&15, lg=k-chunk
//   Vf:    [bh][t2:32][v:5][lane:64] short8 ; lr=d&15, lg=j-chunk
// ---------------------------------------------------------------------------
__global__ __launch_bounds__(256) void build_all_kernel(
    const float* __restrict__ Ptgt, const float* __restrict__ Pmem,
    const float* __restrict__ point_weights,
    const float* __restrict__ qv, const float* __restrict__ qc,
    const float* __restrict__ kv, const float* __restrict__ kc,
    short8* __restrict__ Qf, short8* __restrict__ Kf,
    short8* __restrict__ Vf) {
  __shared__ float buf[64][85];
  const int blk = blockIdx.x;
  if (blk < 1536) {
    const bool isQ = blk < 768;
    int idx = (isQ ? blk : blk - 768) * 256 + threadIdx.x;
    int n = idx & 1023;
    int rest = idx >> 10;
    int k8 = rest % 12;
    int bh = rest / 12;
    int b = bh >> 3, h = bh & 7;
    int bn = b * N_ + n;
    int k0 = k8 * 8;
    float pwh = log1pf(expf(point_weights[h]));
    float coef = 0.5f * POINT_SCALE * pwh;
    float vals[8];
    if (isQ) {
      const float* R = qv + (size_t)bn * 9;
      const float* tv = qc + (size_t)bn * 3;
#pragma unroll
      for (int e = 0; e < 8; ++e) {
        int d = k0 + e;
        float val;
        if (d < 64) {
          val = Ptgt[(size_t)bn * 640 + h * 64 + d];  // pre-scaled by SS
        } else if (d < 76) {
          int pd = d - 64, pt = pd / 3, c = pd % 3;
          const float* P = Ptgt + (size_t)bn * 640 + 512 + h * 12 + pt * 3;
          val = (R[c * 3] * P[0] + R[c * 3 + 1] * P[1] + R[c * 3 + 2] * P[2] + tv[c])
                * (2.0f * coef);
        } else if (d == 76) val = 1.0f;
        else val = 0.0f;
        vals[e] = val;
      }
    } else {
      const float* R = kv + (size_t)bn * 9;
      const float* tv = kc + (size_t)bn * 3;
#pragma unroll
      for (int e = 0; e < 8; ++e) {
        int d = k0 + e;
        float val;
        if (d < 64) {
          val = Pmem[(size_t)bn * 1280 + h * 64 + d];
        } else if (d < 76) {
          int pd = d - 64, pt = pd / 3, c = pd % 3;
          const float* P = Pmem + (size_t)bn * 1280 + 1024 + h * 12 + pt * 3;
          val = R[c * 3] * P[0] + R[c * 3 + 1] * P[1] + R[c * 3 + 2] * P[2] + tv[c];
        } else if (d == 76) {
          float s = 0.0f;
#pragma unroll
          for (int pt = 0; pt < 4; ++pt) {
            const float* P = Pmem + (size_t)bn * 1280 + 1024 + h * 12 + pt * 3;
#pragma unroll
            for (int c = 0; c < 3; ++c) {
              float g = R[c * 3] * P[0] + R[c * 3 + 1] * P[1] + R[c * 3 + 2] * P[2] + tv[c];
              s += g * g;
            }
          }
          val = -coef * s;
        } else val = 0.0f;
        vals[e] = val;
      }
    }
    short8 o;
#pragma unroll
    for (int e = 0; e < 8; ++e) o[e] = f2bf(vals[e]);
    int J = n >> 4, lr = n & 15, s = k8 >> 2, lg = k8 & 3;
    size_t fi = ((size_t)(bh * 64 + J) * 3 + s) * 64 + lg * 16 + lr;
    if (isQ) Qf[fi] = o;
    else     Kf[fi] = o;
    return;
  }
  // ---- Vf job ----
  {
    const int vtb = blk - 1536;            // (16, 8, 2) flattened
    const int n0 = (vtb & 15) * 64;
    const int h = (vtb >> 4) & 7;
    const int b = vtb >> 7;
    const int bh = b * H_ + h;
    const int tid = threadIdx.x;
#pragma unroll
    for (int i = 0; i < 16; ++i) {
      int nl = i * 4 + (tid >> 6), d = tid & 63;
      buf[nl][d] = Pmem[(size_t)(b * N_ + n0 + nl) * 1280 + 512 + h * 64 + d];
    }
    {
      int nl = tid >> 2, pt = tid & 3;
      int bn = b * N_ + n0 + nl;
      const float* P = Pmem + (size_t)bn * 1280 + 1120 + h * 12 + pt * 3;
      const float* R = kv + (size_t)bn * 9;
      const float* tv = kc + (size_t)bn * 3;
#pragma unroll
      for (int c = 0; c < 3; ++c)
        buf[nl][64 + pt * 3 + c] =
            R[c * 3] * P[0] + R[c * 3 + 1] * P[1] + R[c * 3 + 2] * P[2] + tv[c];
      buf[nl][76 + pt] = 0.0f;
    }
    __syncthreads();
    for (int task = tid; task < 640; task += 256) {
      int l6 = task & 63;
      int v = (task >> 6) % 5;
      int t2l = task / 320;
      int lr = l6 & 15, lg = l6 >> 4;
      int d = v * 16 + lr;
      short8 o;
#pragma unroll
      for (int e = 0; e < 8; ++e) o[e] = f2bf(buf[t2l * 32 + lg * 8 + e][d]);
      int t2 = (n0 >> 5) + t2l;
      Vf[((size_t)(bh * 32 + t2) * 5 + v) * 64 + l6] = o;
    }
  }
}

// ---------------------------------------------------------------------------
// Split-j flash attention, 32 q-rows per block (K/V frags reused for 2 i-tiles).
// Grid 512 (XCD-swizzled: 2 bh per XCD slot), 256 thr = 4 waves, 2 blocks/CU.
// Wave w owns j in [w*256,+256): 2 passes x 128 j. One barrier; fused merge +
// rotate-back epilogue.
// ---------------------------------------------------------------------------
__global__ __launch_bounds__(256, 2) void flash_attn_kernel(
    const short8* __restrict__ Qf, const short8* __restrict__ Kf,
    const short8* __restrict__ Vf,
    const float* __restrict__ qv, const float* __restrict__ qc,
    short* __restrict__ featsB) {
  const int flat = blockIdx.x;          // 512
  const int local = flat >> 3;          // 0..63
  const int bh = (flat & 7) * 2 + (local >> 5);
  const int it = local & 31;
  const int b = bh >> 3, h = bh & 7;
  const int i0 = it * 32;
  const int tid = threadIdx.x;
  const int wave = tid >> 6, lane = tid & 63;
  const int lg = lane >> 4, lr = lane & 15;

  // P_l: 2 i-tiles x 16 x 136 shorts = 8704 B ; Om: 32 x 85 f32 = 10880 B
  __shared__ __align__(16) char wblob[4][10880];
  __shared__ float Mm[4][32], Ml[4][32];
  __shared__ float rpl[32][12];
  short* P_l = (short*)wblob[wave];

  // persistent Q fragments for both i-tiles
  short8 aQ[2][3];
#pragma unroll
  for (int i = 0; i < 2; ++i)
#pragma unroll
    for (int s = 0; s < 3; ++s)
      aQ[i][s] = Qf[((size_t)(bh * 64 + it * 2 + i) * 3 + s) * 64 + lane];

  f32x4 O[2][5];
#pragma unroll
  for (int i = 0; i < 2; ++i)
#pragma unroll
    for (int v = 0; v < 5; ++v)
#pragma unroll
      for (int r = 0; r < 4; ++r) O[i][v][r] = 0.0f;
  float m_run[2] = {-3.0e38f, -3.0e38f}, l_run[2] = {0.0f, 0.0f};

  for (int t = 0; t < 2; ++t) {
    const int J0 = wave * 16 + t * 8;

    // S^T for both i-tiles; aK loaded once per k-step, reused for i0 and i1
    f32x4 S0[8], S1[8];
#pragma unroll
    for (int f = 0; f < 8; ++f)
#pragma unroll
      for (int r = 0; r < 4; ++r) { S0[f][r] = 0.0f; S1[f][r] = 0.0f; }
#pragma unroll
    for (int s = 0; s < 3; ++s) {
      short8 aK[8];
#pragma unroll
      for (int f = 0; f < 8; ++f)
        aK[f] = Kf[((size_t)(bh * 64 + J0 + f) * 3 + s) * 64 + lane];
#pragma unroll
      for (int f = 0; f < 8; ++f) {
        S0[f] = __builtin_amdgcn_mfma_f32_16x16x32_bf16(aK[f], aQ[0][s], S0[f], 0, 0, 0);
        S1[f] = __builtin_amdgcn_mfma_f32_16x16x32_bf16(aK[f], aQ[1][s], S1[f], 0, 0, 0);
      }
    }

    // online softmax + P write, per i-tile (column i = lr, register-local)
#pragma unroll
    for (int i = 0; i < 2; ++i) {
      f32x4* S = (i == 0) ? S0 : S1;
      float tm = S[0][0];
#pragma unroll
      for (int f = 0; f < 8; ++f)
#pragma unroll
        for (int r = 0; r < 4; ++r) tm = fmaxf(tm, S[f][r]);
      tm = fmaxf(tm, __shfl_xor(tm, 16));
      tm = fmaxf(tm, __shfl_xor(tm, 32));
      float mnew = fmaxf(m_run[i], tm);
      float alpha = __expf(m_run[i] - mnew);
      m_run[i] = mnew;
      float rs = 0.0f;
#pragma unroll
      for (int f = 0; f < 8; ++f)
#pragma unroll
        for (int r = 0; r < 4; ++r) {
          S[f][r] = __expf(S[f][r] - mnew);
          rs += S[f][r];
        }
      rs += __shfl_xor(rs, 16);
      rs += __shfl_xor(rs, 32);
      l_run[i] = l_run[i] * alpha + rs;
#pragma unroll
      for (int v = 0; v < 5; ++v)
#pragma unroll
        for (int r = 0; r < 4; ++r) O[i][v][r] *= alpha;
#pragma unroll
      for (int f = 0; f < 8; ++f) {
        short4_t pk;
#pragma unroll
        for (int r = 0; r < 4; ++r) pk[r] = f2bf(S[f][r]);
        *(short4_t*)&P_l[i * 2176 + lr * 136 + f * 16 + lg * 4] = pk;
      }
    }

    // O^T += V^T @ P^T ; aV loaded once per k-step, reused for both i-tiles
#pragma unroll
    for (int s2 = 0; s2 < 4; ++s2) {
      const int t2 = wave * 8 + t * 4 + s2;
      short8 bP0 = *(const short8*)&P_l[0 * 2176 + lr * 136 + s2 * 32 + lg * 8];
      short8 bP1 = *(const short8*)&P_l[1 * 2176 + lr * 136 + s2 * 32 + lg * 8];
      short8 aV[5];
#pragma unroll
      for (int v = 0; v < 5; ++v)
        aV[v] = Vf[((size_t)(bh * 32 + t2) * 5 + v) * 64 + lane];
#pragma unroll
      for (int v = 0; v < 5; ++v) {
        O[0][v] = __builtin_amdgcn_mfma_f32_16x16x32_bf16(aV[v], bP0, O[0][v], 0, 0, 0);
        O[1][v] = __builtin_amdgcn_mfma_f32_16x16x32_bf16(aV[v], bP1, O[1][v], 0, 0, 0);
      }
    }
  }

  // publish per-wave partials (Om aliases P_l -- safe after last bP read)
  float* Om_w = (float*)wblob[wave];  // [32][85]
#pragma unroll
  for (int i = 0; i < 2; ++i)
#pragma unroll
    for (int v = 0; v < 5; ++v)
#pragma unroll
      for (int r = 0; r < 4; ++r)
        Om_w[(i * 16 + lr) * 85 + v * 16 + lg * 4 + r] = O[i][v][r];
  if (lg == 0) {
#pragma unroll
    for (int i = 0; i < 2; ++i) {
      Mm[wave][i * 16 + lr] = m_run[i];
      Ml[wave][i * 16 + lr] = l_run[i];
    }
  }
  __syncthreads();

  // merge 4 partials; thread = (row:32, 10-d chunk:8)
  {
    const int row = tid >> 3, q8 = tid & 7;
    float mw0 = Mm[0][row], mw1 = Mm[1][row], mw2 = Mm[2][row], mw3 = Mm[3][row];
    float mstar = fmaxf(fmaxf(mw0, mw1), fmaxf(mw2, mw3));
    float e0 = __expf(mw0 - mstar), e1 = __expf(mw1 - mstar),
          e2 = __expf(mw2 - mstar), e3 = __expf(mw3 - mstar);
    float denom = e0 * Ml[0][row] + e1 * Ml[1][row] + e2 * Ml[2][row] + e3 * Ml[3][row];
    float inv = 1.0f / denom;
    const int bn = b * N_ + i0 + row;
    const float* O0 = (const float*)wblob[0];
    const float* O1 = (const float*)wblob[1];
    const float* O2 = (const float*)wblob[2];
    const float* O3 = (const float*)wblob[3];
#pragma unroll
    for (int k = 0; k < 10; ++k) {
      int d = q8 * 10 + k;
      if (d < 76) {
        float val = (e0 * O0[row * 85 + d] + e1 * O1[row * 85 + d] +
                     e2 * O2[row * 85 + d] + e3 * O3[row * 85 + d]) * inv;
        if (d < 64)
          featsB[(size_t)bn * 640 + h * 64 + d] = f2bf(val);
        else
          rpl[row][d - 64] = val;
      }
    }
  }
  __syncthreads();

  // fused rotate-back + norm epilogue (128 point-tasks)
  if (tid < 128) {
    const int row = tid >> 2, pt = tid & 3;
    const int bn = b * N_ + i0 + row;
    const float* R = qv + (size_t)bn * 9;
    const float* tv = qc + (size_t)bn * 3;
    float p0 = rpl[row][pt * 3 + 0] - tv[0];
    float p1 = rpl[row][pt * 3 + 1] - tv[1];
    float p2 = rpl[row][pt * 3 + 2] - tv[2];
    float o0 = R[0] * p0 + R[3] * p1 + R[6] * p2;
    float o1 = R[1] * p0 + R[4] * p1 + R[7] * p2;
    float o2 = R[2] * p0 + R[5] * p1 + R[8] * p2;
    float nrm = sqrtf(o0 * o0 + o1 * o1 + o2 * o2 + EPS_);
    short* f = featsB + (size_t)bn * 640;
    f[512 + h * 12 + pt * 3 + 0] = f2bf(o0);
    f[512 + h * 12 + pt * 3 + 1] = f2bf(o1);
    f[512 + h * 12 + pt * 3 + 2] = f2bf(o2);
    f[608 + h * 4 + pt] = f2bf(nrm);
  }
}

// ---------------------------------------------------------------------------
extern "C" void kernel_launch(void* const* d_in, const int* in_sizes, int n_in,
                              void* d_out, int out_size, void* d_ws, size_t ws_size,
                              hipStream_t stream) {
  const float* tgt    = (const float*)d_in[0];
  const float* memory = (const float*)d_in[1];
  const float* q_cent = (const float*)d_in[2];
  const float* q_vec  = (const float*)d_in[3];
  const float* k_cent = (const float*)d_in[4];
  const float* k_vec  = (const float*)d_in[5];
  const float* Wq_s   = (const float*)d_in[6];
  const float* Wk_s   = (const float*)d_in[7];
  const float* Wv_s   = (const float*)d_in[8];
  const float* Wq_p   = (const float*)d_in[9];
  const float* Wk_p   = (const float*)d_in[10];
  const float* Wv_p   = (const float*)d_in[11];
  const float* pw     = (const float*)d_in[12];
  const float* Wo     = (const float*)d_in[13];
  const float* bo     = (const float*)d_in[14];
  float* out = (float*)d_out;

  const int M = B_ * N_;  // 2048

  char* wsb = (char*)d_ws;
  size_t off = 0;
  auto alloc = [&](size_t bytes) { char* p = wsb + off; off += (bytes + 255) & ~(size_t)255; return p; };
  short* Atgt   = (short*)alloc((size_t)M * 512 * 2);
  short* Amem   = (short*)alloc((size_t)M * 512 * 2);
  short* Wt_tgt = (short*)alloc((size_t)640 * 512 * 2);
  short* Wt_mem = (short*)alloc((size_t)1280 * 512 * 2);
  short* Wot    = (short*)alloc((size_t)512 * 640 * 2);
  float* Ptgt   = (float*)alloc((size_t)M * 640 * 4);
  float* Pmem   = (float*)alloc((size_t)M * 1280 * 4);
  short8* Qf    = (short8*)alloc((size_t)16 * 64 * 3 * 64 * 16);
  short8* Kf    = (short8*)alloc((size_t)16 * 64 * 3 * 64 * 16);
  short8* Vf    = (short8*)alloc((size_t)16 * 32 * 5 * 64 * 16);
  short* featsB = (short*)alloc((size_t)M * 640 * 2);

  dim3 blk(256);

  // 1. convert inputs + pack weights
  prep_kernel<<<(2 * 131072 + 640 * 64 + 1280 * 64 + 512 * 80) / 256, blk, 0, stream>>>(
      tgt, memory, Wq_s, Wq_p, Wk_s, Wv_s, Wk_p, Wv_p, Wo,
      Atgt, Amem, Wt_tgt, Wt_mem, Wot);
  // 2. fused projections (both in one dispatch; 19 mem tiles -- pad tile dropped)
  gemm64_dual_kernel<<<dim3(29, M / 64), blk, 0, stream>>>(
      Atgt, Wt_tgt, Amem, Wt_mem, Ptgt, Pmem);
  // 3. build fragment-native Q/K/V (one dispatch, rotations fused)
  build_all_kernel<<<1792, blk, 0, stream>>>(
      Ptgt, Pmem, pw, q_vec, q_cent, k_vec, k_cent, Qf, Kf, Vf);
  // 4. flash attention (split-j, 32 rows/block) + fused rotate-back epilogue
  flash_attn_kernel<<<512, blk, 0, stream>>>(Qf, Kf, Vf, q_vec, q_cent, featsB);
  // 5. output projection (64x32 tiles, 512 blocks)
  gemm_out_kernel<<<dim3(16, 32), blk, 0, stream>>>(featsB, Wot, bo, out);
}

// Round 7
// 61.965 us; speedup vs baseline: 38.8506x; 1.0866x over previous
//
#include <hip/hip_runtime.h>
#include <math.h>

#define B_   2
#define N_   1024
#define DIM_ 512
#define H_   8
#define DH_  64
#define PD_  4

static constexpr float SCALAR_SCALE = 0.08838834764831845f; // (2*64)^-0.5
static constexpr float POINT_SCALE  = 0.16666666666666666f; // (2*4*4.5)^-0.5
static constexpr float EPS_         = 1e-8f;

typedef __attribute__((ext_vector_type(8))) short short8;
typedef __attribute__((ext_vector_type(4))) short short4_t;
typedef __attribute__((ext_vector_type(4))) float f32x4;

__device__ __forceinline__ short f2bf(float x) {
  union { float f; unsigned u; } c; c.f = x;
  unsigned r = c.u + 0x7FFFu + ((c.u >> 16) & 1u);
  return (short)(r >> 16);
}

// ---------------------------------------------------------------------------
// Prep: convert tgt/memory to bf16 + pack weights per-head 80-col transposed:
//   Wq80[h][80][512]: c<64 Wq_s[.][h*64+c]*SS | c<76 Wq_p[.][h*12+c-64] | 0
//   Wk80 same from Wk_s/Wk_p (no scale); Wv80 from Wv_s/Wv_p.
//   Wot[512][640] = Wo^T.
// ---------------------------------------------------------------------------
__global__ __launch_bounds__(256) void prep_kernel(
    const float* __restrict__ tgt, const float* __restrict__ memory,
    const float* __restrict__ Wq_s, const float* __restrict__ Wq_p,
    const float* __restrict__ Wk_s, const float* __restrict__ Wv_s,
    const float* __restrict__ Wk_p, const float* __restrict__ Wv_p,
    const float* __restrict__ Wo,
    short* __restrict__ Atgt, short* __restrict__ Amem,
    short* __restrict__ Wq80, short* __restrict__ Wk80,
    short* __restrict__ Wv80, short* __restrict__ Wot) {
  const int CONV = 2048 * 512 / 8;   // 131072 per input
  const int WP = 8 * 80 * 64;        // 40960 per 80-col matrix
  int idx = blockIdx.x * 256 + threadIdx.x;
  if (idx < 2 * CONV) {
    const float* src = (idx < CONV) ? tgt : memory;
    short* dst = (idx < CONV) ? Atgt : Amem;
    int o = (idx < CONV) ? idx : idx - CONV;
    float4 lo = ((const float4*)src)[o * 2];
    float4 hi = ((const float4*)src)[o * 2 + 1];
    short8 v;
    v[0] = f2bf(lo.x); v[1] = f2bf(lo.y); v[2] = f2bf(lo.z); v[3] = f2bf(lo.w);
    v[4] = f2bf(hi.x); v[5] = f2bf(hi.y); v[6] = f2bf(hi.z); v[7] = f2bf(hi.w);
    ((short8*)dst)[o] = v;
    return;
  }
  idx -= 2 * CONV;
  float v[8];
  if (idx < 3 * WP) {
    int mat = idx / WP;
    int j = idx % WP;
    int h = j / (80 * 64);
    int c = (j / 64) % 80;
    int k0 = (j % 64) * 8;
    const float* Ws = (mat == 0) ? Wq_s : (mat == 1 ? Wk_s : Wv_s);
    const float* Wp = (mat == 0) ? Wq_p : (mat == 1 ? Wk_p : Wv_p);
    float scale = (mat == 0 && true) ? 1.0f : 1.0f;
#pragma unroll
    for (int e = 0; e < 8; ++e) {
      int k = k0 + e;
      float val;
      if (c < 64)      val = Ws[(size_t)k * 512 + h * 64 + c];
      else if (c < 76) val = Wp[(size_t)k * 96 + h * 12 + (c - 64)];
      else             val = 0.0f;
      v[e] = val;
    }
    if (mat == 0 && c < 64) {
#pragma unroll
      for (int e = 0; e < 8; ++e) v[e] *= SCALAR_SCALE;
    }
    short8 o;
#pragma unroll
    for (int e = 0; e < 8; ++e) o[e] = f2bf(v[e]);
    short* dst = (mat == 0) ? Wq80 : (mat == 1 ? Wk80 : Wv80);
    *(short8*)(dst + ((size_t)(h * 80 + c)) * 512 + k0) = o;
  } else {
    int j = idx - 3 * WP;          // 40960 tasks for Wot
    int n = j / 80, k0 = (j % 80) * 8;
#pragma unroll
    for (int e = 0; e < 8; ++e) v[e] = Wo[(size_t)(k0 + e) * 512 + n];
    short8 o;
#pragma unroll
    for (int e = 0; e < 8; ++e) o[e] = f2bf(v[e]);
    *(short8*)(Wot + (size_t)n * 640 + k0) = o;
  }
}

// ---------------------------------------------------------------------------
// Fused projection GEMM + augmented-fragment build.
// Grid 768: job = blk>>8 (0=Q from Atgt/Wq80, 1=K from Amem/Wk80, 2=V from
// Amem/Wv80); sub = blk&255: rowblk(32) x h(8). Block computes P[64][80] fp32
// = A[64 rows][512] @ Wh[80 cols][512]^T, then in epilogue rotates points,
// builds k2/const cols, and writes fragment-native Qf/Kf/Vf (bf16).
// Fragment layouts (same as flash expects):
//   Qf/Kf: [bh][J:64][s:3][lane:64] short8 ; k=(s*4+lg)*8+e, row lr of J
//   Vf:    [bh][t2:32][v:5][lane:64] short8 ; d=v*16+lr, j=t2*32+lg*8+e
// ---------------------------------------------------------------------------
__global__ __launch_bounds__(256) void projbuild_kernel(
    const short* __restrict__ Atgt, const short* __restrict__ Amem,
    const short* __restrict__ Wq80, const short* __restrict__ Wk80,
    const short* __restrict__ Wv80,
    const float* __restrict__ point_weights,
    const float* __restrict__ qv, const float* __restrict__ qc,
    const float* __restrict__ kv, const float* __restrict__ kc,
    short8* __restrict__ Qf, short8* __restrict__ Kf,
    short8* __restrict__ Vf) {
  const int blk = blockIdx.x;
  const int job = blk >> 8;
  const int sub = blk & 255;
  const int rowblk = sub >> 3, h = sub & 7;
  const int row0 = rowblk * 64;           // global bn base
  const int b = row0 >> 10;
  const int n0 = row0 & 1023;
  const int bh = b * H_ + h;
  const int tid = threadIdx.x;
  const int wave = tid >> 6, lane = tid & 63;
  const int lg = lane >> 4, lr = lane & 15;

  const short* A = (job == 0) ? Atgt : Amem;
  const short* W = (job == 0) ? Wq80 : (job == 1 ? Wk80 : Wv80);
  const short* Wh = W + (size_t)h * 80 * 512;

  // LDS: staging (Al 64x72 + Wl 80x72 shorts = 20736B) aliased with
  // epilogue Pb[64][84] f32 (21504B) + ks4[64][4] (1024B)
  __shared__ __align__(16) char smem[22784];
  short (*Al)[72] = (short(*)[72])smem;
  short (*Wl)[72] = (short(*)[72])(smem + 9216);
  float (*Pb)[84] = (float(*)[84])smem;
  float (*ks4)[4] = (float(*)[4])(smem + 21504);

  f32x4 acc[5];
#pragma unroll
  for (int f = 0; f < 5; ++f)
#pragma unroll
    for (int r = 0; r < 4; ++r) acc[f][r] = 0.0f;

  for (int kt = 0; kt < 512; kt += 64) {
    for (int i = tid; i < 1152; i += 256) {
      if (i < 512) {
        int row = i >> 3, k8 = i & 7;
        *(short8*)&Al[row][k8 * 8] =
            *(const short8*)(A + (size_t)(row0 + row) * 512 + kt + k8 * 8);
      } else {
        int j = i - 512;
        int col = j >> 3, k8 = j & 7;
        *(short8*)&Wl[col][k8 * 8] =
            *(const short8*)(Wh + (size_t)col * 512 + kt + k8 * 8);
      }
    }
    __syncthreads();
#pragma unroll
    for (int ks = 0; ks < 2; ++ks) {
      short8 aA = *(const short8*)&Al[wave * 16 + lr][ks * 32 + lg * 8];
      short8 bW[5];
#pragma unroll
      for (int f = 0; f < 5; ++f)
        bW[f] = *(const short8*)&Wl[f * 16 + lr][ks * 32 + lg * 8];
#pragma unroll
      for (int f = 0; f < 5; ++f)
        acc[f] = __builtin_amdgcn_mfma_f32_16x16x32_bf16(aA, bW[f], acc[f], 0, 0, 0);
    }
    __syncthreads();
  }

  // ---- epilogue: acc -> Pb (LDS aliases staging; last barrier passed) ----
#pragma unroll
  for (int f = 0; f < 5; ++f)
#pragma unroll
    for (int r = 0; r < 4; ++r)
      Pb[wave * 16 + lg * 4 + r][f * 16 + lr] = acc[f][r];
  __syncthreads();

  const float pwh = log1pf(expf(point_weights[h]));
  const float coef = 0.5f * POINT_SCALE * pwh;

  // rotate the 4 points of each row (one thread per (row, pt))
  {
    const int nl = tid >> 2, pt = tid & 3;
    const int bn = row0 + nl;
    const float* R  = (job == 0) ? (qv + (size_t)bn * 9) : (kv + (size_t)bn * 9);
    const float* tv = (job == 0) ? (qc + (size_t)bn * 3) : (kc + (size_t)bn * 3);
    float p0 = Pb[nl][64 + pt * 3 + 0];
    float p1 = Pb[nl][64 + pt * 3 + 1];
    float p2 = Pb[nl][64 + pt * 3 + 2];
    float g0 = R[0] * p0 + R[1] * p1 + R[2] * p2 + tv[0];
    float g1 = R[3] * p0 + R[4] * p1 + R[5] * p2 + tv[1];
    float g2 = R[6] * p0 + R[7] * p1 + R[8] * p2 + tv[2];
    float sc = (job == 0) ? (2.0f * coef) : 1.0f;
    Pb[nl][64 + pt * 3 + 0] = g0 * sc;
    Pb[nl][64 + pt * 3 + 1] = g1 * sc;
    Pb[nl][64 + pt * 3 + 2] = g2 * sc;
    if (job == 1) ks4[nl][pt] = g0 * g0 + g1 * g1 + g2 * g2;
  }
  __syncthreads();

  // aug columns 76..79 per row
  if (tid < 64) {
    if (job == 0) {
      Pb[tid][76] = 1.0f;
      Pb[tid][77] = 0.0f; Pb[tid][78] = 0.0f; Pb[tid][79] = 0.0f;
    } else if (job == 1) {
      Pb[tid][76] = -coef * (ks4[tid][0] + ks4[tid][1] + ks4[tid][2] + ks4[tid][3]);
      Pb[tid][77] = 0.0f; Pb[tid][78] = 0.0f; Pb[tid][79] = 0.0f;
    } else {
      Pb[tid][76] = 0.0f; Pb[tid][77] = 0.0f;
      Pb[tid][78] = 0.0f; Pb[tid][79] = 0.0f;
    }
  }
  __syncthreads();

  // fragment pack
  if (job < 2) {
    // 768 tasks: (Jl:4) x (k8:12) x (lr16:16)
    for (int t = tid; t < 768; t += 256) {
      int plr = t & 15;
      int k8 = (t >> 4) % 12;
      int Jl = t / 192;
      int k0 = k8 * 8;
      short8 o;
      if (k0 < 80) {
#pragma unroll
        for (int e = 0; e < 8; ++e) o[e] = f2bf(Pb[Jl * 16 + plr][k0 + e]);
      } else {
#pragma unroll
        for (int e = 0; e < 8; ++e) o[e] = 0;
      }
      int J = (n0 >> 4) + Jl;
      size_t fi = ((size_t)(bh * 64 + J) * 3 + (k8 >> 2)) * 64 + (k8 & 3) * 16 + plr;
      if (job == 0) Qf[fi] = o;
      else          Kf[fi] = o;
    }
  } else {
    // 640 tasks: (t2l:2) x (v:5) x (lane:64)
    for (int t = tid; t < 640; t += 256) {
      int l6 = t & 63;
      int v = (t >> 6) % 5;
      int t2l = t / 320;
      int plr = l6 & 15, plg = l6 >> 4;
      int d = v * 16 + plr;
      short8 o;
#pragma unroll
      for (int e = 0; e < 8; ++e) o[e] = f2bf(Pb[t2l * 32 + plg * 8 + e][d]);
      int t2 = (n0 >> 5) + t2l;
      Vf[((size_t)(bh * 32 + t2) * 5 + v) * 64 + l6] = o;
    }
  }
}

// ---------------------------------------------------------------------------
// Split-j flash attention, 32 q-rows per block (K/V frags reused for 2 i-tiles).
// Grid 512 (XCD-swizzled), 256 thr = 4 waves, 2 blocks/CU. One barrier;
// fused merge + rotate-back epilogue.  (unchanged from R5)
// ---------------------------------------------------------------------------
__global__ __launch_bounds__(256, 2) void flash_attn_kernel(
    const short8* __restrict__ Qf, const short8* __restrict__ Kf,
    const short8* __restrict__ Vf,
    const float* __restrict__ qv, const float* __restrict__ qc,
    short* __restrict__ featsB) {
  const int flat = blockIdx.x;          // 512
  const int local = flat >> 3;          // 0..63
  const int bh = (flat & 7) * 2 + (local >> 5);
  const int it = local & 31;
  const int b = bh >> 3, h = bh & 7;
  const int i0 = it * 32;
  const int tid = threadIdx.x;
  const int wave = tid >> 6, lane = tid & 63;
  const int lg = lane >> 4, lr = lane & 15;

  __shared__ __align__(16) char wblob[4][10880];
  __shared__ float Mm[4][32], Ml[4][32];
  __shared__ float rpl[32][12];
  short* P_l = (short*)wblob[wave];

  short8 aQ[2][3];
#pragma unroll
  for (int i = 0; i < 2; ++i)
#pragma unroll
    for (int s = 0; s < 3; ++s)
      aQ[i][s] = Qf[((size_t)(bh * 64 + it * 2 + i) * 3 + s) * 64 + lane];

  f32x4 O[2][5];
#pragma unroll
  for (int i = 0; i < 2; ++i)
#pragma unroll
    for (int v = 0; v < 5; ++v)
#pragma unroll
      for (int r = 0; r < 4; ++r) O[i][v][r] = 0.0f;
  float m_run[2] = {-3.0e38f, -3.0e38f}, l_run[2] = {0.0f, 0.0f};

  for (int t = 0; t < 2; ++t) {
    const int J0 = wave * 16 + t * 8;

    f32x4 S0[8], S1[8];
#pragma unroll
    for (int f = 0; f < 8; ++f)
#pragma unroll
      for (int r = 0; r < 4; ++r) { S0[f][r] = 0.0f; S1[f][r] = 0.0f; }
#pragma unroll
    for (int s = 0; s < 3; ++s) {
      short8 aK[8];
#pragma unroll
      for (int f = 0; f < 8; ++f)
        aK[f] = Kf[((size_t)(bh * 64 + J0 + f) * 3 + s) * 64 + lane];
#pragma unroll
      for (int f = 0; f < 8; ++f) {
        S0[f] = __builtin_amdgcn_mfma_f32_16x16x32_bf16(aK[f], aQ[0][s], S0[f], 0, 0, 0);
        S1[f] = __builtin_amdgcn_mfma_f32_16x16x32_bf16(aK[f], aQ[1][s], S1[f], 0, 0, 0);
      }
    }

#pragma unroll
    for (int i = 0; i < 2; ++i) {
      f32x4* S = (i == 0) ? S0 : S1;
      float tm = S[0][0];
#pragma unroll
      for (int f = 0; f < 8; ++f)
#pragma unroll
        for (int r = 0; r < 4; ++r) tm = fmaxf(tm, S[f][r]);
      tm = fmaxf(tm, __shfl_xor(tm, 16));
      tm = fmaxf(tm, __shfl_xor(tm, 32));
      float mnew = fmaxf(m_run[i], tm);
      float alpha = __expf(m_run[i] - mnew);
      m_run[i] = mnew;
      float rs = 0.0f;
#pragma unroll
      for (int f = 0; f < 8; ++f)
#pragma unroll
        for (int r = 0; r < 4; ++r) {
          S[f][r] = __expf(S[f][r] - mnew);
          rs += S[f][r];
        }
      rs += __shfl_xor(rs, 16);
      rs += __shfl_xor(rs, 32);
      l_run[i] = l_run[i] * alpha + rs;
#pragma unroll
      for (int v = 0; v < 5; ++v)
#pragma unroll
        for (int r = 0; r < 4; ++r) O[i][v][r] *= alpha;
#pragma unroll
      for (int f = 0; f < 8; ++f) {
        short4_t pk;
#pragma unroll
        for (int r = 0; r < 4; ++r) pk[r] = f2bf(S[f][r]);
        *(short4_t*)&P_l[i * 2176 + lr * 136 + f * 16 + lg * 4] = pk;
      }
    }

#pragma unroll
    for (int s2 = 0; s2 < 4; ++s2) {
      const int t2 = wave * 8 + t * 4 + s2;
      short8 bP0 = *(const short8*)&P_l[0 * 2176 + lr * 136 + s2 * 32 + lg * 8];
      short8 bP1 = *(const short8*)&P_l[1 * 2176 + lr * 136 + s2 * 32 + lg * 8];
      short8 aV[5];
#pragma unroll
      for (int v = 0; v < 5; ++v)
        aV[v] = Vf[((size_t)(bh * 32 + t2) * 5 + v) * 64 + lane];
#pragma unroll
      for (int v = 0; v < 5; ++v) {
        O[0][v] = __builtin_amdgcn_mfma_f32_16x16x32_bf16(aV[v], bP0, O[0][v], 0, 0, 0);
        O[1][v] = __builtin_amdgcn_mfma_f32_16x16x32_bf16(aV[v], bP1, O[1][v], 0, 0, 0);
      }
    }
  }

  float* Om_w = (float*)wblob[wave];  // [32][85]
#pragma unroll
  for (int i = 0; i < 2; ++i)
#pragma unroll
    for (int v = 0; v < 5; ++v)
#pragma unroll
      for (int r = 0; r < 4; ++r)
        Om_w[(i * 16 + lr) * 85 + v * 16 + lg * 4 + r] = O[i][v][r];
  if (lg == 0) {
#pragma unroll
    for (int i = 0; i < 2; ++i) {
      Mm[wave][i * 16 + lr] = m_run[i];
      Ml[wave][i * 16 + lr] = l_run[i];
    }
  }
  __syncthreads();

  {
    const int row = tid >> 3, q8 = tid & 7;
    float mw0 = Mm[0][row], mw1 = Mm[1][row], mw2 = Mm[2][row], mw3 = Mm[3][row];
    float mstar = fmaxf(fmaxf(mw0, mw1), fmaxf(mw2, mw3));
    float e0 = __expf(mw0 - mstar), e1 = __expf(mw1 - mstar),
          e2 = __expf(mw2 - mstar), e3 = __expf(mw3 - mstar);
    float denom = e0 * Ml[0][row] + e1 * Ml[1][row] + e2 * Ml[2][row] + e3 * Ml[3][row];
    float inv = 1.0f / denom;
    const int bn = b * N_ + i0 + row;
    const float* O0 = (const float*)wblob[0];
    const float* O1 = (const float*)wblob[1];
    const float* O2 = (const float*)wblob[2];
    const float* O3 = (const float*)wblob[3];
#pragma unroll
    for (int k = 0; k < 10; ++k) {
      int d = q8 * 10 + k;
      if (d < 76) {
        float val = (e0 * O0[row * 85 + d] + e1 * O1[row * 85 + d] +
                     e2 * O2[row * 85 + d] + e3 * O3[row * 85 + d]) * inv;
        if (d < 64)
          featsB[(size_t)bn * 640 + h * 64 + d] = f2bf(val);
        else
          rpl[row][d - 64] = val;
      }
    }
  }
  __syncthreads();

  if (tid < 128) {
    const int row = tid >> 2, pt = tid & 3;
    const int bn = b * N_ + i0 + row;
    const float* R = qv + (size_t)bn * 9;
    const float* tv = qc + (size_t)bn * 3;
    float p0 = rpl[row][pt * 3 + 0] - tv[0];
    float p1 = rpl[row][pt * 3 + 1] - tv[1];
    float p2 = rpl[row][pt * 3 + 2] - tv[2];
    float o0 = R[0] * p0 + R[3] * p1 + R[6] * p2;
    float o1 = R[1] * p0 + R[4] * p1 + R[7] * p2;
    float o2 = R[2] * p0 + R[5] * p1 + R[8] * p2;
    float nrm = sqrtf(o0 * o0 + o1 * o1 + o2 * o2 + EPS_);
    short* f = featsB + (size_t)bn * 640;
    f[512 + h * 12 + pt * 3 + 0] = f2bf(o0);
    f[512 + h * 12 + pt * 3 + 1] = f2bf(o1);
    f[512 + h * 12 + pt * 3 + 2] = f2bf(o2);
    f[608 + h * 4 + pt] = f2bf(nrm);
  }
}

// ---------------------------------------------------------------------------
// Output GEMM, 64x32 tiles (512 blocks): out = featsB @ Wot^T + bo
// ---------------------------------------------------------------------------
__global__ __launch_bounds__(256) void gemm_out_kernel(
    const short* __restrict__ A, const short* __restrict__ Bt,
    const float* __restrict__ bias, float* __restrict__ C) {
  const int row0 = blockIdx.y * 64, col0 = blockIdx.x * 32;
  const int tid = threadIdx.x, wave = tid >> 6, lane = tid & 63;
  const int wr = wave >> 1, wc = wave & 1;
  const int lg = lane >> 4, lr = lane & 15;
  const int l8 = lane >> 3, l7 = lane & 7;

  __shared__ short Al[64][72];
  __shared__ short Bl[32][72];

  f32x4 acc[2];
#pragma unroll
  for (int m = 0; m < 2; ++m)
#pragma unroll
    for (int r = 0; r < 4; ++r) acc[m][r] = 0.0f;

  for (int kt = 0; kt < 640; kt += 64) {
    short8 areg[2], breg;
#pragma unroll
    for (int i = 0; i < 2; ++i) {
      int r = wave * 16 + i * 8 + l8;
      areg[i] = *(const short8*)(A + (size_t)(row0 + r) * 640 + kt + l7 * 8);
    }
    {
      int r = wave * 8 + l8;
      breg = *(const short8*)(Bt + (size_t)(col0 + r) * 640 + kt + l7 * 8);
    }
    __syncthreads();
#pragma unroll
    for (int i = 0; i < 2; ++i) {
      int r = wave * 16 + i * 8 + l8;
      *(short8*)(&Al[r][l7 * 8]) = areg[i];
    }
    { int r = wave * 8 + l8; *(short8*)(&Bl[r][l7 * 8]) = breg; }
    __syncthreads();
#pragma unroll
    for (int ks = 0; ks < 2; ++ks) {
      short8 aA[2], bB;
#pragma unroll
      for (int m = 0; m < 2; ++m)
        aA[m] = *(const short8*)(&Al[wr * 32 + m * 16 + lr][ks * 32 + lg * 8]);
      bB = *(const short8*)(&Bl[wc * 16 + lr][ks * 32 + lg * 8]);
#pragma unroll
      for (int m = 0; m < 2; ++m)
        acc[m] = __builtin_amdgcn_mfma_f32_16x16x32_bf16(aA[m], bB, acc[m], 0, 0, 0);
    }
  }

#pragma unroll
  for (int m = 0; m < 2; ++m)
#pragma unroll
    for (int r = 0; r < 4; ++r) {
      int row = row0 + wr * 32 + m * 16 + lg * 4 + r;
      int col = col0 + wc * 16 + lr;
      C[(size_t)row * 512 + col] = acc[m][r] + bias[col];
    }
}

// ---------------------------------------------------------------------------
extern "C" void kernel_launch(void* const* d_in, const int* in_sizes, int n_in,
                              void* d_out, int out_size, void* d_ws, size_t ws_size,
                              hipStream_t stream) {
  const float* tgt    = (const float*)d_in[0];
  const float* memory = (const float*)d_in[1];
  const float* q_cent = (const float*)d_in[2];
  const float* q_vec  = (const float*)d_in[3];
  const float* k_cent = (const float*)d_in[4];
  const float* k_vec  = (const float*)d_in[5];
  const float* Wq_s   = (const float*)d_in[6];
  const float* Wk_s   = (const float*)d_in[7];
  const float* Wv_s   = (const float*)d_in[8];
  const float* Wq_p   = (const float*)d_in[9];
  const float* Wk_p   = (const float*)d_in[10];
  const float* Wv_p   = (const float*)d_in[11];
  const float* pw     = (const float*)d_in[12];
  const float* Wo     = (const float*)d_in[13];
  const float* bo     = (const float*)d_in[14];
  float* out = (float*)d_out;

  const int M = B_ * N_;  // 2048

  char* wsb = (char*)d_ws;
  size_t off = 0;
  auto alloc = [&](size_t bytes) { char* p = wsb + off; off += (bytes + 255) & ~(size_t)255; return p; };
  short* Atgt   = (short*)alloc((size_t)M * 512 * 2);
  short* Amem   = (short*)alloc((size_t)M * 512 * 2);
  short* Wq80   = (short*)alloc((size_t)8 * 80 * 512 * 2);
  short* Wk80   = (short*)alloc((size_t)8 * 80 * 512 * 2);
  short* Wv80   = (short*)alloc((size_t)8 * 80 * 512 * 2);
  short* Wot    = (short*)alloc((size_t)512 * 640 * 2);
  short8* Qf    = (short8*)alloc((size_t)16 * 64 * 3 * 64 * 16);
  short8* Kf    = (short8*)alloc((size_t)16 * 64 * 3 * 64 * 16);
  short8* Vf    = (short8*)alloc((size_t)16 * 32 * 5 * 64 * 16);
  short* featsB = (short*)alloc((size_t)M * 640 * 2);

  dim3 blk(256);

  // 1. convert inputs + pack weights (per-head 80-col layout)
  prep_kernel<<<(2 * 131072 + 4 * 40960) / 256, blk, 0, stream>>>(
      tgt, memory, Wq_s, Wq_p, Wk_s, Wv_s, Wk_p, Wv_p, Wo,
      Atgt, Amem, Wq80, Wk80, Wv80, Wot);
  // 2. fused projection GEMM + rotation + fragment build (Q,K,V in one dispatch)
  projbuild_kernel<<<768, blk, 0, stream>>>(
      Atgt, Amem, Wq80, Wk80, Wv80, pw, q_vec, q_cent, k_vec, k_cent,
      Qf, Kf, Vf);
  // 3. flash attention (split-j, 32 rows/block) + fused rotate-back epilogue
  flash_attn_kernel<<<512, blk, 0, stream>>>(Qf, Kf, Vf, q_vec, q_cent, featsB);
  // 4. output projection (64x32 tiles, 512 blocks)
  gemm_out_kernel<<<dim3(16, 32), blk, 0, stream>>>(featsB, Wot, bo, out);
}

// Round 8
// 56.669 us; speedup vs baseline: 42.4820x; 1.0935x over previous
//
#include <hip/hip_runtime.h>
#include <math.h>

#define B_   2
#define N_   1024
#define DIM_ 512
#define H_   8
#define DH_  64
#define PD_  4

static constexpr float SCALAR_SCALE = 0.08838834764831845f; // (2*64)^-0.5
static constexpr float POINT_SCALE  = 0.16666666666666666f; // (2*4*4.5)^-0.5
static constexpr float EPS_         = 1e-8f;

typedef __attribute__((ext_vector_type(8))) short short8;
typedef __attribute__((ext_vector_type(4))) short short4_t;
typedef __attribute__((ext_vector_type(4))) float f32x4;

__device__ __forceinline__ short f2bf(float x) {
  union { float f; unsigned u; } c; c.f = x;
  unsigned r = c.u + 0x7FFFu + ((c.u >> 16) & 1u);
  return (short)(r >> 16);
}

// ---------------------------------------------------------------------------
// Prep: convert tgt/memory to bf16 + pack weights per-head 80-col transposed:
//   Wq80[h][80][512]: c<64 Wq_s[.][h*64+c]*SS | c<76 Wq_p[.][h*12+c-64] | 0
//   Wk80 / Wv80 same (no scale); Wot[512][640] = Wo^T.
// ---------------------------------------------------------------------------
__global__ __launch_bounds__(256) void prep_kernel(
    const float* __restrict__ tgt, const float* __restrict__ memory,
    const float* __restrict__ Wq_s, const float* __restrict__ Wq_p,
    const float* __restrict__ Wk_s, const float* __restrict__ Wv_s,
    const float* __restrict__ Wk_p, const float* __restrict__ Wv_p,
    const float* __restrict__ Wo,
    short* __restrict__ Atgt, short* __restrict__ Amem,
    short* __restrict__ Wq80, short* __restrict__ Wk80,
    short* __restrict__ Wv80, short* __restrict__ Wot) {
  const int CONV = 2048 * 512 / 8;   // 131072 per input
  const int WP = 8 * 80 * 64;        // 40960 per 80-col matrix
  int idx = blockIdx.x * 256 + threadIdx.x;
  if (idx < 2 * CONV) {
    const float* src = (idx < CONV) ? tgt : memory;
    short* dst = (idx < CONV) ? Atgt : Amem;
    int o = (idx < CONV) ? idx : idx - CONV;
    float4 lo = ((const float4*)src)[o * 2];
    float4 hi = ((const float4*)src)[o * 2 + 1];
    short8 v;
    v[0] = f2bf(lo.x); v[1] = f2bf(lo.y); v[2] = f2bf(lo.z); v[3] = f2bf(lo.w);
    v[4] = f2bf(hi.x); v[5] = f2bf(hi.y); v[6] = f2bf(hi.z); v[7] = f2bf(hi.w);
    ((short8*)dst)[o] = v;
    return;
  }
  idx -= 2 * CONV;
  float v[8];
  if (idx < 3 * WP) {
    int mat = idx / WP;
    int j = idx % WP;
    int h = j / (80 * 64);
    int c = (j / 64) % 80;
    int k0 = (j % 64) * 8;
    const float* Ws = (mat == 0) ? Wq_s : (mat == 1 ? Wk_s : Wv_s);
    const float* Wp = (mat == 0) ? Wq_p : (mat == 1 ? Wk_p : Wv_p);
#pragma unroll
    for (int e = 0; e < 8; ++e) {
      int k = k0 + e;
      float val;
      if (c < 64)      val = Ws[(size_t)k * 512 + h * 64 + c];
      else if (c < 76) val = Wp[(size_t)k * 96 + h * 12 + (c - 64)];
      else             val = 0.0f;
      v[e] = val;
    }
    if (mat == 0 && c < 64) {
#pragma unroll
      for (int e = 0; e < 8; ++e) v[e] *= SCALAR_SCALE;
    }
    short8 o;
#pragma unroll
    for (int e = 0; e < 8; ++e) o[e] = f2bf(v[e]);
    short* dst = (mat == 0) ? Wq80 : (mat == 1 ? Wk80 : Wv80);
    *(short8*)(dst + ((size_t)(h * 80 + c)) * 512 + k0) = o;
  } else {
    int j = idx - 3 * WP;          // 40960 tasks for Wot
    int n = j / 80, k0 = (j % 80) * 8;
#pragma unroll
    for (int e = 0; e < 8; ++e) v[e] = Wo[(size_t)(k0 + e) * 512 + n];
    short8 o;
#pragma unroll
    for (int e = 0; e < 8; ++e) o[e] = f2bf(v[e]);
    *(short8*)(Wot + (size_t)n * 640 + k0) = o;
  }
}

// ---------------------------------------------------------------------------
// Fused projection GEMM + augmented-fragment build. BK=128 (4 k-iters).
// Grid 768: job = blk>>8 (0=Q, 1=K, 2=V); sub = blk&255: rowblk(32) x h(8).
// Block computes P[64][80] fp32 = A[64][512] @ Wh[80][512]^T, then rotates
// points, builds k2/const cols, writes fragment-native Qf/Kf/Vf (bf16).
//   Qf/Kf: [bh][J:64][s:3][lane:64] short8 ; Vf: [bh][t2:32][v:5][lane:64]
// ---------------------------------------------------------------------------
__global__ __launch_bounds__(256) void projbuild_kernel(
    const short* __restrict__ Atgt, const short* __restrict__ Amem,
    const short* __restrict__ Wq80, const short* __restrict__ Wk80,
    const short* __restrict__ Wv80,
    const float* __restrict__ point_weights,
    const float* __restrict__ qv, const float* __restrict__ qc,
    const float* __restrict__ kv, const float* __restrict__ kc,
    short8* __restrict__ Qf, short8* __restrict__ Kf,
    short8* __restrict__ Vf) {
  const int blk = blockIdx.x;
  const int job = blk >> 8;
  const int sub = blk & 255;
  const int rowblk = sub >> 3, h = sub & 7;
  const int row0 = rowblk * 64;           // global bn base
  const int b = row0 >> 10;
  const int n0 = row0 & 1023;
  const int bh = b * H_ + h;
  const int tid = threadIdx.x;
  const int wave = tid >> 6, lane = tid & 63;
  const int lg = lane >> 4, lr = lane & 15;

  const short* A = (job == 0) ? Atgt : Amem;
  const short* W = (job == 0) ? Wq80 : (job == 1 ? Wk80 : Wv80);
  const short* Wh = W + (size_t)h * 80 * 512;

  // LDS: staging Al[64][136] (17408B) + Wl[80][136] (21760B) = 39168B,
  // aliased with epilogue Pb[64][84] f32 (21504B) + ks4[64][4] (1024B).
  __shared__ __align__(16) char smem[39168];
  short (*Al)[136] = (short(*)[136])smem;
  short (*Wl)[136] = (short(*)[136])(smem + 17408);
  float (*Pb)[84] = (float(*)[84])smem;
  float (*ks4)[4] = (float(*)[4])(smem + 21504);

  f32x4 acc[5];
#pragma unroll
  for (int f = 0; f < 5; ++f)
#pragma unroll
    for (int r = 0; r < 4; ++r) acc[f][r] = 0.0f;

  for (int kt = 0; kt < 512; kt += 128) {
#pragma unroll
    for (int ii = 0; ii < 9; ++ii) {
      int i = ii * 256 + tid;
      if (i < 1024) {
        int row = i >> 4, k8 = i & 15;
        *(short8*)&Al[row][k8 * 8] =
            *(const short8*)(A + (size_t)(row0 + row) * 512 + kt + k8 * 8);
      } else {
        int j = i - 1024;
        int col = j >> 4, k8 = j & 15;
        *(short8*)&Wl[col][k8 * 8] =
            *(const short8*)(Wh + (size_t)col * 512 + kt + k8 * 8);
      }
    }
    __syncthreads();
#pragma unroll
    for (int ks = 0; ks < 4; ++ks) {
      short8 aA = *(const short8*)&Al[wave * 16 + lr][ks * 32 + lg * 8];
      short8 bW[5];
#pragma unroll
      for (int f = 0; f < 5; ++f)
        bW[f] = *(const short8*)&Wl[f * 16 + lr][ks * 32 + lg * 8];
#pragma unroll
      for (int f = 0; f < 5; ++f)
        acc[f] = __builtin_amdgcn_mfma_f32_16x16x32_bf16(aA, bW[f], acc[f], 0, 0, 0);
    }
    __syncthreads();
  }

  // ---- epilogue: acc -> Pb (aliases staging; last barrier passed) ----
#pragma unroll
  for (int f = 0; f < 5; ++f)
#pragma unroll
    for (int r = 0; r < 4; ++r)
      Pb[wave * 16 + lg * 4 + r][f * 16 + lr] = acc[f][r];
  __syncthreads();

  const float pwh = log1pf(expf(point_weights[h]));
  const float coef = 0.5f * POINT_SCALE * pwh;

  // rotate the 4 points of each row (one thread per (row, pt))
  {
    const int nl = tid >> 2, pt = tid & 3;
    const int bn = row0 + nl;
    const float* R  = (job == 0) ? (qv + (size_t)bn * 9) : (kv + (size_t)bn * 9);
    const float* tv = (job == 0) ? (qc + (size_t)bn * 3) : (kc + (size_t)bn * 3);
    float p0 = Pb[nl][64 + pt * 3 + 0];
    float p1 = Pb[nl][64 + pt * 3 + 1];
    float p2 = Pb[nl][64 + pt * 3 + 2];
    float g0 = R[0] * p0 + R[1] * p1 + R[2] * p2 + tv[0];
    float g1 = R[3] * p0 + R[4] * p1 + R[5] * p2 + tv[1];
    float g2 = R[6] * p0 + R[7] * p1 + R[8] * p2 + tv[2];
    float sc = (job == 0) ? (2.0f * coef) : 1.0f;
    Pb[nl][64 + pt * 3 + 0] = g0 * sc;
    Pb[nl][64 + pt * 3 + 1] = g1 * sc;
    Pb[nl][64 + pt * 3 + 2] = g2 * sc;
    if (job == 1) ks4[nl][pt] = g0 * g0 + g1 * g1 + g2 * g2;
  }
  __syncthreads();

  // aug columns 76..79 per row
  if (tid < 64) {
    if (job == 0) {
      Pb[tid][76] = 1.0f;
      Pb[tid][77] = 0.0f; Pb[tid][78] = 0.0f; Pb[tid][79] = 0.0f;
    } else if (job == 1) {
      Pb[tid][76] = -coef * (ks4[tid][0] + ks4[tid][1] + ks4[tid][2] + ks4[tid][3]);
      Pb[tid][77] = 0.0f; Pb[tid][78] = 0.0f; Pb[tid][79] = 0.0f;
    } else {
      Pb[tid][76] = 0.0f; Pb[tid][77] = 0.0f;
      Pb[tid][78] = 0.0f; Pb[tid][79] = 0.0f;
    }
  }
  __syncthreads();

  // fragment pack
  if (job < 2) {
    // 768 tasks: (Jl:4) x (k8:12) x (lr16:16)
    for (int t = tid; t < 768; t += 256) {
      int plr = t & 15;
      int k8 = (t >> 4) % 12;
      int Jl = t / 192;
      int k0 = k8 * 8;
      short8 o;
      if (k0 < 80) {
#pragma unroll
        for (int e = 0; e < 8; ++e) o[e] = f2bf(Pb[Jl * 16 + plr][k0 + e]);
      } else {
#pragma unroll
        for (int e = 0; e < 8; ++e) o[e] = 0;
      }
      int J = (n0 >> 4) + Jl;
      size_t fi = ((size_t)(bh * 64 + J) * 3 + (k8 >> 2)) * 64 + (k8 & 3) * 16 + plr;
      if (job == 0) Qf[fi] = o;
      else          Kf[fi] = o;
    }
  } else {
    // 640 tasks: (t2l:2) x (v:5) x (lane:64)
    for (int t = tid; t < 640; t += 256) {
      int l6 = t & 63;
      int v = (t >> 6) % 5;
      int t2l = t / 320;
      int plr = l6 & 15, plg = l6 >> 4;
      int d = v * 16 + plr;
      short8 o;
#pragma unroll
      for (int e = 0; e < 8; ++e) o[e] = f2bf(Pb[t2l * 32 + plg * 8 + e][d]);
      int t2 = (n0 >> 5) + t2l;
      Vf[((size_t)(bh * 32 + t2) * 5 + v) * 64 + l6] = o;
    }
  }
}

// ---------------------------------------------------------------------------
// Split-j flash attention, 32 q-rows per block (K/V frags reused for 2 i-tiles).
// Grid 512 (XCD-swizzled), 256 thr = 4 waves, 2 blocks/CU. One barrier;
// fused merge + rotate-back epilogue. s_setprio around MFMA clusters.
// ---------------------------------------------------------------------------
__global__ __launch_bounds__(256, 2) void flash_attn_kernel(
    const short8* __restrict__ Qf, const short8* __restrict__ Kf,
    const short8* __restrict__ Vf,
    const float* __restrict__ qv, const float* __restrict__ qc,
    short* __restrict__ featsB) {
  const int flat = blockIdx.x;          // 512
  const int local = flat >> 3;          // 0..63
  const int bh = (flat & 7) * 2 + (local >> 5);
  const int it = local & 31;
  const int b = bh >> 3, h = bh & 7;
  const int i0 = it * 32;
  const int tid = threadIdx.x;
  const int wave = tid >> 6, lane = tid & 63;
  const int lg = lane >> 4, lr = lane & 15;

  __shared__ __align__(16) char wblob[4][10880];
  __shared__ float Mm[4][32], Ml[4][32];
  __shared__ float rpl[32][12];
  short* P_l = (short*)wblob[wave];

  short8 aQ[2][3];
#pragma unroll
  for (int i = 0; i < 2; ++i)
#pragma unroll
    for (int s = 0; s < 3; ++s)
      aQ[i][s] = Qf[((size_t)(bh * 64 + it * 2 + i) * 3 + s) * 64 + lane];

  f32x4 O[2][5];
#pragma unroll
  for (int i = 0; i < 2; ++i)
#pragma unroll
    for (int v = 0; v < 5; ++v)
#pragma unroll
      for (int r = 0; r < 4; ++r) O[i][v][r] = 0.0f;
  float m_run[2] = {-3.0e38f, -3.0e38f}, l_run[2] = {0.0f, 0.0f};

  for (int t = 0; t < 2; ++t) {
    const int J0 = wave * 16 + t * 8;

    f32x4 S0[8], S1[8];
#pragma unroll
    for (int f = 0; f < 8; ++f)
#pragma unroll
      for (int r = 0; r < 4; ++r) { S0[f][r] = 0.0f; S1[f][r] = 0.0f; }
#pragma unroll
    for (int s = 0; s < 3; ++s) {
      short8 aK[8];
#pragma unroll
      for (int f = 0; f < 8; ++f)
        aK[f] = Kf[((size_t)(bh * 64 + J0 + f) * 3 + s) * 64 + lane];
      __builtin_amdgcn_s_setprio(1);
#pragma unroll
      for (int f = 0; f < 8; ++f) {
        S0[f] = __builtin_amdgcn_mfma_f32_16x16x32_bf16(aK[f], aQ[0][s], S0[f], 0, 0, 0);
        S1[f] = __builtin_amdgcn_mfma_f32_16x16x32_bf16(aK[f], aQ[1][s], S1[f], 0, 0, 0);
      }
      __builtin_amdgcn_s_setprio(0);
    }

#pragma unroll
    for (int i = 0; i < 2; ++i) {
      f32x4* S = (i == 0) ? S0 : S1;
      float tm = S[0][0];
#pragma unroll
      for (int f = 0; f < 8; ++f)
#pragma unroll
        for (int r = 0; r < 4; ++r) tm = fmaxf(tm, S[f][r]);
      tm = fmaxf(tm, __shfl_xor(tm, 16));
      tm = fmaxf(tm, __shfl_xor(tm, 32));
      float mnew = fmaxf(m_run[i], tm);
      float alpha = __expf(m_run[i] - mnew);
      m_run[i] = mnew;
      float rs = 0.0f;
#pragma unroll
      for (int f = 0; f < 8; ++f)
#pragma unroll
        for (int r = 0; r < 4; ++r) {
          S[f][r] = __expf(S[f][r] - mnew);
          rs += S[f][r];
        }
      rs += __shfl_xor(rs, 16);
      rs += __shfl_xor(rs, 32);
      l_run[i] = l_run[i] * alpha + rs;
#pragma unroll
      for (int v = 0; v < 5; ++v)
#pragma unroll
        for (int r = 0; r < 4; ++r) O[i][v][r] *= alpha;
#pragma unroll
      for (int f = 0; f < 8; ++f) {
        short4_t pk;
#pragma unroll
        for (int r = 0; r < 4; ++r) pk[r] = f2bf(S[f][r]);
        *(short4_t*)&P_l[i * 2176 + lr * 136 + f * 16 + lg * 4] = pk;
      }
    }

#pragma unroll
    for (int s2 = 0; s2 < 4; ++s2) {
      const int t2 = wave * 8 + t * 4 + s2;
      short8 bP0 = *(const short8*)&P_l[0 * 2176 + lr * 136 + s2 * 32 + lg * 8];
      short8 bP1 = *(const short8*)&P_l[1 * 2176 + lr * 136 + s2 * 32 + lg * 8];
      short8 aV[5];
#pragma unroll
      for (int v = 0; v < 5; ++v)
        aV[v] = Vf[((size_t)(bh * 32 + t2) * 5 + v) * 64 + lane];
      __builtin_amdgcn_s_setprio(1);
#pragma unroll
      for (int v = 0; v < 5; ++v) {
        O[0][v] = __builtin_amdgcn_mfma_f32_16x16x32_bf16(aV[v], bP0, O[0][v], 0, 0, 0);
        O[1][v] = __builtin_amdgcn_mfma_f32_16x16x32_bf16(aV[v], bP1, O[1][v], 0, 0, 0);
      }
      __builtin_amdgcn_s_setprio(0);
    }
  }

  float* Om_w = (float*)wblob[wave];  // [32][85]
#pragma unroll
  for (int i = 0; i < 2; ++i)
#pragma unroll
    for (int v = 0; v < 5; ++v)
#pragma unroll
      for (int r = 0; r < 4; ++r)
        Om_w[(i * 16 + lr) * 85 + v * 16 + lg * 4 + r] = O[i][v][r];
  if (lg == 0) {
#pragma unroll
    for (int i = 0; i < 2; ++i) {
      Mm[wave][i * 16 + lr] = m_run[i];
      Ml[wave][i * 16 + lr] = l_run[i];
    }
  }
  __syncthreads();

  {
    const int row = tid >> 3, q8 = tid & 7;
    float mw0 = Mm[0][row], mw1 = Mm[1][row], mw2 = Mm[2][row], mw3 = Mm[3][row];
    float mstar = fmaxf(fmaxf(mw0, mw1), fmaxf(mw2, mw3));
    float e0 = __expf(mw0 - mstar), e1 = __expf(mw1 - mstar),
          e2 = __expf(mw2 - mstar), e3 = __expf(mw3 - mstar);
    float denom = e0 * Ml[0][row] + e1 * Ml[1][row] + e2 * Ml[2][row] + e3 * Ml[3][row];
    float inv = 1.0f / denom;
    const int bn = b * N_ + i0 + row;
    const float* O0 = (const float*)wblob[0];
    const float* O1 = (const float*)wblob[1];
    const float* O2 = (const float*)wblob[2];
    const float* O3 = (const float*)wblob[3];
#pragma unroll
    for (int k = 0; k < 10; ++k) {
      int d = q8 * 10 + k;
      if (d < 76) {
        float val = (e0 * O0[row * 85 + d] + e1 * O1[row * 85 + d] +
                     e2 * O2[row * 85 + d] + e3 * O3[row * 85 + d]) * inv;
        if (d < 64)
          featsB[(size_t)bn * 640 + h * 64 + d] = f2bf(val);
        else
          rpl[row][d - 64] = val;
      }
    }
  }
  __syncthreads();

  if (tid < 128) {
    const int row = tid >> 2, pt = tid & 3;
    const int bn = b * N_ + i0 + row;
    const float* R = qv + (size_t)bn * 9;
    const float* tv = qc + (size_t)bn * 3;
    float p0 = rpl[row][pt * 3 + 0] - tv[0];
    float p1 = rpl[row][pt * 3 + 1] - tv[1];
    float p2 = rpl[row][pt * 3 + 2] - tv[2];
    float o0 = R[0] * p0 + R[3] * p1 + R[6] * p2;
    float o1 = R[1] * p0 + R[4] * p1 + R[7] * p2;
    float o2 = R[2] * p0 + R[5] * p1 + R[8] * p2;
    float nrm = sqrtf(o0 * o0 + o1 * o1 + o2 * o2 + EPS_);
    short* f = featsB + (size_t)bn * 640;
    f[512 + h * 12 + pt * 3 + 0] = f2bf(o0);
    f[512 + h * 12 + pt * 3 + 1] = f2bf(o1);
    f[512 + h * 12 + pt * 3 + 2] = f2bf(o2);
    f[608 + h * 4 + pt] = f2bf(nrm);
  }
}

// ---------------------------------------------------------------------------
// Output GEMM, 64x32 tiles (512 blocks), BK=128 (5 k-iters):
//   out[2048][512] = featsB[2048][640] @ Wot[512][640]^T + bo
// ---------------------------------------------------------------------------
__global__ __launch_bounds__(256) void gemm_out_kernel(
    const short* __restrict__ A, const short* __restrict__ Bt,
    const float* __restrict__ bias, float* __restrict__ C) {
  const int row0 = blockIdx.y * 64, col0 = blockIdx.x * 32;
  const int tid = threadIdx.x, wave = tid >> 6, lane = tid & 63;
  const int wr = wave >> 1, wc = wave & 1;
  const int lg = lane >> 4, lr = lane & 15;

  __shared__ short Al[64][136];
  __shared__ short Bl[32][136];

  f32x4 acc[2];
#pragma unroll
  for (int m = 0; m < 2; ++m)
#pragma unroll
    for (int r = 0; r < 4; ++r) acc[m][r] = 0.0f;

  for (int kt = 0; kt < 640; kt += 128) {
#pragma unroll
    for (int ii = 0; ii < 6; ++ii) {
      int i = ii * 256 + tid;
      if (i < 1024) {
        int row = i >> 4, k8 = i & 15;
        *(short8*)&Al[row][k8 * 8] =
            *(const short8*)(A + (size_t)(row0 + row) * 640 + kt + k8 * 8);
      } else {
        int j = i - 1024;
        int col = j >> 4, k8 = j & 15;
        *(short8*)&Bl[col][k8 * 8] =
            *(const short8*)(Bt + (size_t)(col0 + col) * 640 + kt + k8 * 8);
      }
    }
    __syncthreads();
#pragma unroll
    for (int ks = 0; ks < 4; ++ks) {
      short8 aA[2], bB;
#pragma unroll
      for (int m = 0; m < 2; ++m)
        aA[m] = *(const short8*)(&Al[wr * 32 + m * 16 + lr][ks * 32 + lg * 8]);
      bB = *(const short8*)(&Bl[wc * 16 + lr][ks * 32 + lg * 8]);
#pragma unroll
      for (int m = 0; m < 2; ++m)
        acc[m] = __builtin_amdgcn_mfma_f32_16x16x32_bf16(aA[m], bB, acc[m], 0, 0, 0);
    }
    __syncthreads();
  }

#pragma unroll
  for (int m = 0; m < 2; ++m)
#pragma unroll
    for (int r = 0; r < 4; ++r) {
      int row = row0 + wr * 32 + m * 16 + lg * 4 + r;
      int col = col0 + wc * 16 + lr;
      C[(size_t)row * 512 + col] = acc[m][r] + bias[col];
    }
}

// ---------------------------------------------------------------------------
extern "C" void kernel_launch(void* const* d_in, const int* in_sizes, int n_in,
                              void* d_out, int out_size, void* d_ws, size_t ws_size,
                              hipStream_t stream) {
  const float* tgt    = (const float*)d_in[0];
  const float* memory = (const float*)d_in[1];
  const float* q_cent = (const float*)d_in[2];
  const float* q_vec  = (const float*)d_in[3];
  const float* k_cent = (const float*)d_in[4];
  const float* k_vec  = (const float*)d_in[5];
  const float* Wq_s   = (const float*)d_in[6];
  const float* Wk_s   = (const float*)d_in[7];
  const float* Wv_s   = (const float*)d_in[8];
  const float* Wq_p   = (const float*)d_in[9];
  const float* Wk_p   = (const float*)d_in[10];
  const float* Wv_p   = (const float*)d_in[11];
  const float* pw     = (const float*)d_in[12];
  const float* Wo     = (const float*)d_in[13];
  const float* bo     = (const float*)d_in[14];
  float* out = (float*)d_out;

  const int M = B_ * N_;  // 2048

  char* wsb = (char*)d_ws;
  size_t off = 0;
  auto alloc = [&](size_t bytes) { char* p = wsb + off; off += (bytes + 255) & ~(size_t)255; return p; };
  short* Atgt   = (short*)alloc((size_t)M * 512 * 2);
  short* Amem   = (short*)alloc((size_t)M * 512 * 2);
  short* Wq80   = (short*)alloc((size_t)8 * 80 * 512 * 2);
  short* Wk80   = (short*)alloc((size_t)8 * 80 * 512 * 2);
  short* Wv80   = (short*)alloc((size_t)8 * 80 * 512 * 2);
  short* Wot    = (short*)alloc((size_t)512 * 640 * 2);
  short8* Qf    = (short8*)alloc((size_t)16 * 64 * 3 * 64 * 16);
  short8* Kf    = (short8*)alloc((size_t)16 * 64 * 3 * 64 * 16);
  short8* Vf    = (short8*)alloc((size_t)16 * 32 * 5 * 64 * 16);
  short* featsB = (short*)alloc((size_t)M * 640 * 2);

  dim3 blk(256);

  // 1. convert inputs + pack weights (per-head 80-col layout)
  prep_kernel<<<(2 * 131072 + 4 * 40960) / 256, blk, 0, stream>>>(
      tgt, memory, Wq_s, Wq_p, Wk_s, Wv_s, Wk_p, Wv_p, Wo,
      Atgt, Amem, Wq80, Wk80, Wv80, Wot);
  // 2. fused projection GEMM + rotation + fragment build (BK=128)
  projbuild_kernel<<<768, blk, 0, stream>>>(
      Atgt, Amem, Wq80, Wk80, Wv80, pw, q_vec, q_cent, k_vec, k_cent,
      Qf, Kf, Vf);
  // 3. flash attention (split-j, 32 rows/block) + fused rotate-back epilogue
  flash_attn_kernel<<<512, blk, 0, stream>>>(Qf, Kf, Vf, q_vec, q_cent, featsB);
  // 4. output projection (64x32 tiles, BK=128)
  gemm_out_kernel<<<dim3(16, 32), blk, 0, stream>>>(featsB, Wot, bo, out);
}

// Round 9
// 52.530 us; speedup vs baseline: 45.8288x; 1.0788x over previous
//
#include <hip/hip_runtime.h>
#include <math.h>

#define B_   2
#define N_   1024
#define DIM_ 512
#define H_   8
#define DH_  64
#define PD_  4

static constexpr float SCALAR_SCALE = 0.08838834764831845f; // (2*64)^-0.5
static constexpr float POINT_SCALE  = 0.16666666666666666f; // (2*4*4.5)^-0.5
static constexpr float EPS_         = 1e-8f;

typedef __attribute__((ext_vector_type(8))) short short8;
typedef __attribute__((ext_vector_type(4))) short short4_t;
typedef __attribute__((ext_vector_type(4))) float f32x4;

__device__ __forceinline__ short f2bf(float x) {
  union { float f; unsigned u; } c; c.f = x;
  unsigned r = c.u + 0x7FFFu + ((c.u >> 16) & 1u);
  return (short)(r >> 16);
}

// ---------------------------------------------------------------------------
// Prep: convert tgt/memory to bf16 + pack weights per-head 80-col transposed.
// ---------------------------------------------------------------------------
__global__ __launch_bounds__(256) void prep_kernel(
    const float* __restrict__ tgt, const float* __restrict__ memory,
    const float* __restrict__ Wq_s, const float* __restrict__ Wq_p,
    const float* __restrict__ Wk_s, const float* __restrict__ Wv_s,
    const float* __restrict__ Wk_p, const float* __restrict__ Wv_p,
    const float* __restrict__ Wo,
    short* __restrict__ Atgt, short* __restrict__ Amem,
    short* __restrict__ Wq80, short* __restrict__ Wk80,
    short* __restrict__ Wv80, short* __restrict__ Wot) {
  const int CONV = 2048 * 512 / 8;   // 131072 per input
  const int WP = 8 * 80 * 64;        // 40960 per 80-col matrix
  int idx = blockIdx.x * 256 + threadIdx.x;
  if (idx < 2 * CONV) {
    const float* src = (idx < CONV) ? tgt : memory;
    short* dst = (idx < CONV) ? Atgt : Amem;
    int o = (idx < CONV) ? idx : idx - CONV;
    float4 lo = ((const float4*)src)[o * 2];
    float4 hi = ((const float4*)src)[o * 2 + 1];
    short8 v;
    v[0] = f2bf(lo.x); v[1] = f2bf(lo.y); v[2] = f2bf(lo.z); v[3] = f2bf(lo.w);
    v[4] = f2bf(hi.x); v[5] = f2bf(hi.y); v[6] = f2bf(hi.z); v[7] = f2bf(hi.w);
    ((short8*)dst)[o] = v;
    return;
  }
  idx -= 2 * CONV;
  float v[8];
  if (idx < 3 * WP) {
    int mat = idx / WP;
    int j = idx % WP;
    int h = j / (80 * 64);
    int c = (j / 64) % 80;
    int k0 = (j % 64) * 8;
    const float* Ws = (mat == 0) ? Wq_s : (mat == 1 ? Wk_s : Wv_s);
    const float* Wp = (mat == 0) ? Wq_p : (mat == 1 ? Wk_p : Wv_p);
#pragma unroll
    for (int e = 0; e < 8; ++e) {
      int k = k0 + e;
      float val;
      if (c < 64)      val = Ws[(size_t)k * 512 + h * 64 + c];
      else if (c < 76) val = Wp[(size_t)k * 96 + h * 12 + (c - 64)];
      else             val = 0.0f;
      v[e] = val;
    }
    if (mat == 0 && c < 64) {
#pragma unroll
      for (int e = 0; e < 8; ++e) v[e] *= SCALAR_SCALE;
    }
    short8 o;
#pragma unroll
    for (int e = 0; e < 8; ++e) o[e] = f2bf(v[e]);
    short* dst = (mat == 0) ? Wq80 : (mat == 1 ? Wk80 : Wv80);
    *(short8*)(dst + ((size_t)(h * 80 + c)) * 512 + k0) = o;
  } else {
    int j = idx - 3 * WP;          // 40960 tasks for Wot
    int n = j / 80, k0 = (j % 80) * 8;
#pragma unroll
    for (int e = 0; e < 8; ++e) v[e] = Wo[(size_t)(k0 + e) * 512 + n];
    short8 o;
#pragma unroll
    for (int e = 0; e < 8; ++e) o[e] = f2bf(v[e]);
    *(short8*)(Wot + (size_t)n * 640 + k0) = o;
  }
}

// ---------------------------------------------------------------------------
// Fused projection GEMM + augmented-fragment build. BK=128, reg double-buffer.
// Grid 768: job = blk>>8 (0=Q, 1=K, 2=V); sub = blk&255: rowblk(32) x h(8).
// ---------------------------------------------------------------------------
__global__ __launch_bounds__(256) void projbuild_kernel(
    const short* __restrict__ Atgt, const short* __restrict__ Amem,
    const short* __restrict__ Wq80, const short* __restrict__ Wk80,
    const short* __restrict__ Wv80,
    const float* __restrict__ point_weights,
    const float* __restrict__ qv, const float* __restrict__ qc,
    const float* __restrict__ kv, const float* __restrict__ kc,
    short8* __restrict__ Qf, short8* __restrict__ Kf,
    short8* __restrict__ Vf) {
  const int blk = blockIdx.x;
  const int job = blk >> 8;
  const int sub = blk & 255;
  const int rowblk = sub >> 3, h = sub & 7;
  const int row0 = rowblk * 64;           // global bn base
  const int b = row0 >> 10;
  const int n0 = row0 & 1023;
  const int bh = b * H_ + h;
  const int tid = threadIdx.x;
  const int wave = tid >> 6, lane = tid & 63;
  const int lg = lane >> 4, lr = lane & 15;

  const short* A = (job == 0) ? Atgt : Amem;
  const short* W = (job == 0) ? Wq80 : (job == 1 ? Wk80 : Wv80);
  const short* Wh = W + (size_t)h * 80 * 512;

  // LDS: staging Al[64][136] + Wl[80][136] = 39168B, aliased with epilogue
  // Pb[64][84] f32 (21504B) + ks4[64][4] (1024B).
  __shared__ __align__(16) char smem[39168];
  short (*Al)[136] = (short(*)[136])smem;
  short (*Wl)[136] = (short(*)[136])(smem + 17408);
  float (*Pb)[84] = (float(*)[84])smem;
  float (*ks4)[4] = (float(*)[4])(smem + 21504);

  f32x4 acc[5];
#pragma unroll
  for (int f = 0; f < 5; ++f)
#pragma unroll
    for (int r = 0; r < 4; ++r) acc[f][r] = 0.0f;

  // per-thread staging task (constant across iters)
  const int i_lo = tid;            // covers 0..255 of 2304 tasks, ii*256+tid
  short8 st[9];
  // preload kt=0
#pragma unroll
  for (int ii = 0; ii < 9; ++ii) {
    int i = ii * 256 + i_lo;
    if (i < 1024) {
      int row = i >> 4, k8 = i & 15;
      st[ii] = *(const short8*)(A + (size_t)(row0 + row) * 512 + 0 + k8 * 8);
    } else {
      int j = i - 1024;
      int col = j >> 4, k8 = j & 15;
      st[ii] = *(const short8*)(Wh + (size_t)col * 512 + 0 + k8 * 8);
    }
  }

  for (int kt = 0; kt < 512; kt += 128) {
    // write staged regs -> LDS
#pragma unroll
    for (int ii = 0; ii < 9; ++ii) {
      int i = ii * 256 + i_lo;
      if (i < 1024) {
        int row = i >> 4, k8 = i & 15;
        *(short8*)&Al[row][k8 * 8] = st[ii];
      } else {
        int j = i - 1024;
        int col = j >> 4, k8 = j & 15;
        *(short8*)&Wl[col][k8 * 8] = st[ii];
      }
    }
    __syncthreads();
    // prefetch next k-tile into regs (overlaps MFMA below)
    if (kt + 128 < 512) {
#pragma unroll
      for (int ii = 0; ii < 9; ++ii) {
        int i = ii * 256 + i_lo;
        if (i < 1024) {
          int row = i >> 4, k8 = i & 15;
          st[ii] = *(const short8*)(A + (size_t)(row0 + row) * 512 + (kt + 128) + k8 * 8);
        } else {
          int j = i - 1024;
          int col = j >> 4, k8 = j & 15;
          st[ii] = *(const short8*)(Wh + (size_t)col * 512 + (kt + 128) + k8 * 8);
        }
      }
    }
#pragma unroll
    for (int ks = 0; ks < 4; ++ks) {
      short8 aA = *(const short8*)&Al[wave * 16 + lr][ks * 32 + lg * 8];
      short8 bW[5];
#pragma unroll
      for (int f = 0; f < 5; ++f)
        bW[f] = *(const short8*)&Wl[f * 16 + lr][ks * 32 + lg * 8];
#pragma unroll
      for (int f = 0; f < 5; ++f)
        acc[f] = __builtin_amdgcn_mfma_f32_16x16x32_bf16(aA, bW[f], acc[f], 0, 0, 0);
    }
    __syncthreads();
  }

  // ---- epilogue: acc -> Pb (aliases staging; last barrier passed) ----
#pragma unroll
  for (int f = 0; f < 5; ++f)
#pragma unroll
    for (int r = 0; r < 4; ++r)
      Pb[wave * 16 + lg * 4 + r][f * 16 + lr] = acc[f][r];
  __syncthreads();

  const float pwh = log1pf(expf(point_weights[h]));
  const float coef = 0.5f * POINT_SCALE * pwh;

  // rotate the 4 points of each row (one thread per (row, pt))
  {
    const int nl = tid >> 2, pt = tid & 3;
    const int bn = row0 + nl;
    const float* R  = (job == 0) ? (qv + (size_t)bn * 9) : (kv + (size_t)bn * 9);
    const float* tv = (job == 0) ? (qc + (size_t)bn * 3) : (kc + (size_t)bn * 3);
    float p0 = Pb[nl][64 + pt * 3 + 0];
    float p1 = Pb[nl][64 + pt * 3 + 1];
    float p2 = Pb[nl][64 + pt * 3 + 2];
    float g0 = R[0] * p0 + R[1] * p1 + R[2] * p2 + tv[0];
    float g1 = R[3] * p0 + R[4] * p1 + R[5] * p2 + tv[1];
    float g2 = R[6] * p0 + R[7] * p1 + R[8] * p2 + tv[2];
    float sc = (job == 0) ? (2.0f * coef) : 1.0f;
    Pb[nl][64 + pt * 3 + 0] = g0 * sc;
    Pb[nl][64 + pt * 3 + 1] = g1 * sc;
    Pb[nl][64 + pt * 3 + 2] = g2 * sc;
    if (job == 1) ks4[nl][pt] = g0 * g0 + g1 * g1 + g2 * g2;
  }
  __syncthreads();

  // aug columns 76..79 per row
  if (tid < 64) {
    if (job == 0) {
      Pb[tid][76] = 1.0f;
      Pb[tid][77] = 0.0f; Pb[tid][78] = 0.0f; Pb[tid][79] = 0.0f;
    } else if (job == 1) {
      Pb[tid][76] = -coef * (ks4[tid][0] + ks4[tid][1] + ks4[tid][2] + ks4[tid][3]);
      Pb[tid][77] = 0.0f; Pb[tid][78] = 0.0f; Pb[tid][79] = 0.0f;
    } else {
      Pb[tid][76] = 0.0f; Pb[tid][77] = 0.0f;
      Pb[tid][78] = 0.0f; Pb[tid][79] = 0.0f;
    }
  }
  __syncthreads();

  // fragment pack
  if (job < 2) {
    // 768 tasks: (Jl:4) x (k8:12) x (lr16:16)
    for (int t = tid; t < 768; t += 256) {
      int plr = t & 15;
      int k8 = (t >> 4) % 12;
      int Jl = t / 192;
      int k0 = k8 * 8;
      short8 o;
      if (k0 < 80) {
#pragma unroll
        for (int e = 0; e < 8; ++e) o[e] = f2bf(Pb[Jl * 16 + plr][k0 + e]);
      } else {
#pragma unroll
        for (int e = 0; e < 8; ++e) o[e] = 0;
      }
      int J = (n0 >> 4) + Jl;
      size_t fi = ((size_t)(bh * 64 + J) * 3 + (k8 >> 2)) * 64 + (k8 & 3) * 16 + plr;
      if (job == 0) Qf[fi] = o;
      else          Kf[fi] = o;
    }
  } else {
    // 640 tasks: (t2l:2) x (v:5) x (lane:64)
    for (int t = tid; t < 640; t += 256) {
      int l6 = t & 63;
      int v = (t >> 6) % 5;
      int t2l = t / 320;
      int plr = l6 & 15, plg = l6 >> 4;
      int d = v * 16 + plr;
      short8 o;
#pragma unroll
      for (int e = 0; e < 8; ++e) o[e] = f2bf(Pb[t2l * 32 + plg * 8 + e][d]);
      int t2 = (n0 >> 5) + t2l;
      Vf[((size_t)(bh * 32 + t2) * 5 + v) * 64 + l6] = o;
    }
  }
}

// ---------------------------------------------------------------------------
// Split-j flash attention, 32 q-rows per block; V prefetched before softmax.
// Grid 512 (XCD-swizzled), 256 thr = 4 waves, 2 blocks/CU.
// ---------------------------------------------------------------------------
__global__ __launch_bounds__(256, 2) void flash_attn_kernel(
    const short8* __restrict__ Qf, const short8* __restrict__ Kf,
    const short8* __restrict__ Vf,
    const float* __restrict__ qv, const float* __restrict__ qc,
    short* __restrict__ featsB) {
  const int flat = blockIdx.x;          // 512
  const int local = flat >> 3;          // 0..63
  const int bh = (flat & 7) * 2 + (local >> 5);
  const int it = local & 31;
  const int b = bh >> 3, h = bh & 7;
  const int i0 = it * 32;
  const int tid = threadIdx.x;
  const int wave = tid >> 6, lane = tid & 63;
  const int lg = lane >> 4, lr = lane & 15;

  __shared__ __align__(16) char wblob[4][10880];
  __shared__ float Mm[4][32], Ml[4][32];
  __shared__ float rpl[32][12];
  short* P_l = (short*)wblob[wave];

  short8 aQ[2][3];
#pragma unroll
  for (int i = 0; i < 2; ++i)
#pragma unroll
    for (int s = 0; s < 3; ++s)
      aQ[i][s] = Qf[((size_t)(bh * 64 + it * 2 + i) * 3 + s) * 64 + lane];

  f32x4 O[2][5];
#pragma unroll
  for (int i = 0; i < 2; ++i)
#pragma unroll
    for (int v = 0; v < 5; ++v)
#pragma unroll
      for (int r = 0; r < 4; ++r) O[i][v][r] = 0.0f;
  float m_run[2] = {-3.0e38f, -3.0e38f}, l_run[2] = {0.0f, 0.0f};

  for (int t = 0; t < 2; ++t) {
    const int J0 = wave * 16 + t * 8;

    f32x4 S0[8], S1[8];
#pragma unroll
    for (int f = 0; f < 8; ++f)
#pragma unroll
      for (int r = 0; r < 4; ++r) { S0[f][r] = 0.0f; S1[f][r] = 0.0f; }
#pragma unroll
    for (int s = 0; s < 3; ++s) {
      short8 aK[8];
#pragma unroll
      for (int f = 0; f < 8; ++f)
        aK[f] = Kf[((size_t)(bh * 64 + J0 + f) * 3 + s) * 64 + lane];
      __builtin_amdgcn_s_setprio(1);
#pragma unroll
      for (int f = 0; f < 8; ++f) {
        S0[f] = __builtin_amdgcn_mfma_f32_16x16x32_bf16(aK[f], aQ[0][s], S0[f], 0, 0, 0);
        S1[f] = __builtin_amdgcn_mfma_f32_16x16x32_bf16(aK[f], aQ[1][s], S1[f], 0, 0, 0);
      }
      __builtin_amdgcn_s_setprio(0);
    }

    // prefetch ALL V fragments for this t -- latency hides under softmax
    short8 aVp[4][5];
#pragma unroll
    for (int s2 = 0; s2 < 4; ++s2) {
      const int t2 = wave * 8 + t * 4 + s2;
#pragma unroll
      for (int v = 0; v < 5; ++v)
        aVp[s2][v] = Vf[((size_t)(bh * 32 + t2) * 5 + v) * 64 + lane];
    }

#pragma unroll
    for (int i = 0; i < 2; ++i) {
      f32x4* S = (i == 0) ? S0 : S1;
      float tm = S[0][0];
#pragma unroll
      for (int f = 0; f < 8; ++f)
#pragma unroll
        for (int r = 0; r < 4; ++r) tm = fmaxf(tm, S[f][r]);
      tm = fmaxf(tm, __shfl_xor(tm, 16));
      tm = fmaxf(tm, __shfl_xor(tm, 32));
      float mnew = fmaxf(m_run[i], tm);
      float alpha = __expf(m_run[i] - mnew);
      m_run[i] = mnew;
      float rs = 0.0f;
#pragma unroll
      for (int f = 0; f < 8; ++f)
#pragma unroll
        for (int r = 0; r < 4; ++r) {
          S[f][r] = __expf(S[f][r] - mnew);
          rs += S[f][r];
        }
      rs += __shfl_xor(rs, 16);
      rs += __shfl_xor(rs, 32);
      l_run[i] = l_run[i] * alpha + rs;
#pragma unroll
      for (int v = 0; v < 5; ++v)
#pragma unroll
        for (int r = 0; r < 4; ++r) O[i][v][r] *= alpha;
#pragma unroll
      for (int f = 0; f < 8; ++f) {
        short4_t pk;
#pragma unroll
        for (int r = 0; r < 4; ++r) pk[r] = f2bf(S[f][r]);
        *(short4_t*)&P_l[i * 2176 + lr * 136 + f * 16 + lg * 4] = pk;
      }
    }

#pragma unroll
    for (int s2 = 0; s2 < 4; ++s2) {
      short8 bP0 = *(const short8*)&P_l[0 * 2176 + lr * 136 + s2 * 32 + lg * 8];
      short8 bP1 = *(const short8*)&P_l[1 * 2176 + lr * 136 + s2 * 32 + lg * 8];
      __builtin_amdgcn_s_setprio(1);
#pragma unroll
      for (int v = 0; v < 5; ++v) {
        O[0][v] = __builtin_amdgcn_mfma_f32_16x16x32_bf16(aVp[s2][v], bP0, O[0][v], 0, 0, 0);
        O[1][v] = __builtin_amdgcn_mfma_f32_16x16x32_bf16(aVp[s2][v], bP1, O[1][v], 0, 0, 0);
      }
      __builtin_amdgcn_s_setprio(0);
    }
  }

  float* Om_w = (float*)wblob[wave];  // [32][85]
#pragma unroll
  for (int i = 0; i < 2; ++i)
#pragma unroll
    for (int v = 0; v < 5; ++v)
#pragma unroll
      for (int r = 0; r < 4; ++r)
        Om_w[(i * 16 + lr) * 85 + v * 16 + lg * 4 + r] = O[i][v][r];
  if (lg == 0) {
#pragma unroll
    for (int i = 0; i < 2; ++i) {
      Mm[wave][i * 16 + lr] = m_run[i];
      Ml[wave][i * 16 + lr] = l_run[i];
    }
  }
  __syncthreads();

  {
    const int row = tid >> 3, q8 = tid & 7;
    float mw0 = Mm[0][row], mw1 = Mm[1][row], mw2 = Mm[2][row], mw3 = Mm[3][row];
    float mstar = fmaxf(fmaxf(mw0, mw1), fmaxf(mw2, mw3));
    float e0 = __expf(mw0 - mstar), e1 = __expf(mw1 - mstar),
          e2 = __expf(mw2 - mstar), e3 = __expf(mw3 - mstar);
    float denom = e0 * Ml[0][row] + e1 * Ml[1][row] + e2 * Ml[2][row] + e3 * Ml[3][row];
    float inv = 1.0f / denom;
    const int bn = b * N_ + i0 + row;
    const float* O0 = (const float*)wblob[0];
    const float* O1 = (const float*)wblob[1];
    const float* O2 = (const float*)wblob[2];
    const float* O3 = (const float*)wblob[3];
#pragma unroll
    for (int k = 0; k < 10; ++k) {
      int d = q8 * 10 + k;
      if (d < 76) {
        float val = (e0 * O0[row * 85 + d] + e1 * O1[row * 85 + d] +
                     e2 * O2[row * 85 + d] + e3 * O3[row * 85 + d]) * inv;
        if (d < 64)
          featsB[(size_t)bn * 640 + h * 64 + d] = f2bf(val);
        else
          rpl[row][d - 64] = val;
      }
    }
  }
  __syncthreads();

  if (tid < 128) {
    const int row = tid >> 2, pt = tid & 3;
    const int bn = b * N_ + i0 + row;
    const float* R = qv + (size_t)bn * 9;
    const float* tv = qc + (size_t)bn * 3;
    float p0 = rpl[row][pt * 3 + 0] - tv[0];
    float p1 = rpl[row][pt * 3 + 1] - tv[1];
    float p2 = rpl[row][pt * 3 + 2] - tv[2];
    float o0 = R[0] * p0 + R[3] * p1 + R[6] * p2;
    float o1 = R[1] * p0 + R[4] * p1 + R[7] * p2;
    float o2 = R[2] * p0 + R[5] * p1 + R[8] * p2;
    float nrm = sqrtf(o0 * o0 + o1 * o1 + o2 * o2 + EPS_);
    short* f = featsB + (size_t)bn * 640;
    f[512 + h * 12 + pt * 3 + 0] = f2bf(o0);
    f[512 + h * 12 + pt * 3 + 1] = f2bf(o1);
    f[512 + h * 12 + pt * 3 + 2] = f2bf(o2);
    f[608 + h * 4 + pt] = f2bf(nrm);
  }
}

// ---------------------------------------------------------------------------
// Output GEMM, 64x32 tiles (512 blocks), BK=128, reg double-buffer:
//   out[2048][512] = featsB[2048][640] @ Wot[512][640]^T + bo
// ---------------------------------------------------------------------------
__global__ __launch_bounds__(256) void gemm_out_kernel(
    const short* __restrict__ A, const short* __restrict__ Bt,
    const float* __restrict__ bias, float* __restrict__ C) {
  const int row0 = blockIdx.y * 64, col0 = blockIdx.x * 32;
  const int tid = threadIdx.x, wave = tid >> 6, lane = tid & 63;
  const int wr = wave >> 1, wc = wave & 1;
  const int lg = lane >> 4, lr = lane & 15;

  __shared__ short Al[64][136];
  __shared__ short Bl[32][136];

  f32x4 acc[2];
#pragma unroll
  for (int m = 0; m < 2; ++m)
#pragma unroll
    for (int r = 0; r < 4; ++r) acc[m][r] = 0.0f;

  short8 st[6];
#pragma unroll
  for (int ii = 0; ii < 6; ++ii) {
    int i = ii * 256 + tid;
    if (i < 1024) {
      int row = i >> 4, k8 = i & 15;
      st[ii] = *(const short8*)(A + (size_t)(row0 + row) * 640 + 0 + k8 * 8);
    } else {
      int j = i - 1024;
      int col = j >> 4, k8 = j & 15;
      st[ii] = *(const short8*)(Bt + (size_t)(col0 + col) * 640 + 0 + k8 * 8);
    }
  }

  for (int kt = 0; kt < 640; kt += 128) {
#pragma unroll
    for (int ii = 0; ii < 6; ++ii) {
      int i = ii * 256 + tid;
      if (i < 1024) {
        int row = i >> 4, k8 = i & 15;
        *(short8*)&Al[row][k8 * 8] = st[ii];
      } else {
        int j = i - 1024;
        int col = j >> 4, k8 = j & 15;
        *(short8*)&Bl[col][k8 * 8] = st[ii];
      }
    }
    __syncthreads();
    if (kt + 128 < 640) {
#pragma unroll
      for (int ii = 0; ii < 6; ++ii) {
        int i = ii * 256 + tid;
        if (i < 1024) {
          int row = i >> 4, k8 = i & 15;
          st[ii] = *(const short8*)(A + (size_t)(row0 + row) * 640 + (kt + 128) + k8 * 8);
        } else {
          int j = i - 1024;
          int col = j >> 4, k8 = j & 15;
          st[ii] = *(const short8*)(Bt + (size_t)(col0 + col) * 640 + (kt + 128) + k8 * 8);
        }
      }
    }
#pragma unroll
    for (int ks = 0; ks < 4; ++ks) {
      short8 aA[2], bB;
#pragma unroll
      for (int m = 0; m < 2; ++m)
        aA[m] = *(const short8*)(&Al[wr * 32 + m * 16 + lr][ks * 32 + lg * 8]);
      bB = *(const short8*)(&Bl[wc * 16 + lr][ks * 32 + lg * 8]);
#pragma unroll
      for (int m = 0; m < 2; ++m)
        acc[m] = __builtin_amdgcn_mfma_f32_16x16x32_bf16(aA[m], bB, acc[m], 0, 0, 0);
    }
    __syncthreads();
  }

#pragma unroll
  for (int m = 0; m < 2; ++m)
#pragma unroll
    for (int r = 0; r < 4; ++r) {
      int row = row0 + wr * 32 + m * 16 + lg * 4 + r;
      int col = col0 + wc * 16 + lr;
      C[(size_t)row * 512 + col] = acc[m][r] + bias[col];
    }
}

// ---------------------------------------------------------------------------
extern "C" void kernel_launch(void* const* d_in, const int* in_sizes, int n_in,
                              void* d_out, int out_size, void* d_ws, size_t ws_size,
                              hipStream_t stream) {
  const float* tgt    = (const float*)d_in[0];
  const float* memory = (const float*)d_in[1];
  const float* q_cent = (const float*)d_in[2];
  const float* q_vec  = (const float*)d_in[3];
  const float* k_cent = (const float*)d_in[4];
  const float* k_vec  = (const float*)d_in[5];
  const float* Wq_s   = (const float*)d_in[6];
  const float* Wk_s   = (const float*)d_in[7];
  const float* Wv_s   = (const float*)d_in[8];
  const float* Wq_p   = (const float*)d_in[9];
  const float* Wk_p   = (const float*)d_in[10];
  const float* Wv_p   = (const float*)d_in[11];
  const float* pw     = (const float*)d_in[12];
  const float* Wo     = (const float*)d_in[13];
  const float* bo     = (const float*)d_in[14];
  float* out = (float*)d_out;

  const int M = B_ * N_;  // 2048

  char* wsb = (char*)d_ws;
  size_t off = 0;
  auto alloc = [&](size_t bytes) { char* p = wsb + off; off += (bytes + 255) & ~(size_t)255; return p; };
  short* Atgt   = (short*)alloc((size_t)M * 512 * 2);
  short* Amem   = (short*)alloc((size_t)M * 512 * 2);
  short* Wq80   = (short*)alloc((size_t)8 * 80 * 512 * 2);
  short* Wk80   = (short*)alloc((size_t)8 * 80 * 512 * 2);
  short* Wv80   = (short*)alloc((size_t)8 * 80 * 512 * 2);
  short* Wot    = (short*)alloc((size_t)512 * 640 * 2);
  short8* Qf    = (short8*)alloc((size_t)16 * 64 * 3 * 64 * 16);
  short8* Kf    = (short8*)alloc((size_t)16 * 64 * 3 * 64 * 16);
  short8* Vf    = (short8*)alloc((size_t)16 * 32 * 5 * 64 * 16);
  short* featsB = (short*)alloc((size_t)M * 640 * 2);

  dim3 blk(256);

  // 1. convert inputs + pack weights (per-head 80-col layout)
  prep_kernel<<<(2 * 131072 + 4 * 40960) / 256, blk, 0, stream>>>(
      tgt, memory, Wq_s, Wq_p, Wk_s, Wv_s, Wk_p, Wv_p, Wo,
      Atgt, Amem, Wq80, Wk80, Wv80, Wot);
  // 2. fused projection GEMM + rotation + fragment build (BK=128, reg dbuf)
  projbuild_kernel<<<768, blk, 0, stream>>>(
      Atgt, Amem, Wq80, Wk80, Wv80, pw, q_vec, q_cent, k_vec, k_cent,
      Qf, Kf, Vf);
  // 3. flash attention (split-j, V prefetch) + fused rotate-back epilogue
  flash_attn_kernel<<<512, blk, 0, stream>>>(Qf, Kf, Vf, q_vec, q_cent, featsB);
  // 4. output projection (64x32 tiles, BK=128, reg dbuf)
  gemm_out_kernel<<<dim3(16, 32), blk, 0, stream>>>(featsB, Wot, bo, out);
}